// Round 13
// baseline (128.949 us; speedup 1.0000x reference)
//
#include <hip/hip_runtime.h>

#define NN 10000
#define NE 160000
#define IND 56          // 32 + 3*8
#define WN 1600
#define EPB 128         // fallback: edges per block (4 waves x 32)
#define NBLK (NE / EPB)
#define EPB2 256        // main: edges per block (4 waves x 64)
#define NBLK2 (NE / EPB2)
#define DCAP 64         // max edges per source node bucket

typedef __attribute__((ext_vector_type(8))) short bf16x8;
typedef __attribute__((ext_vector_type(4))) float f32x4;

static constexpr float PATH_NORM_C = 0.15811388300841897f; // 1/sqrt(40)
static constexpr float CG_C        = 0.57735026918962576f; // 1/sqrt(3)

__device__ __forceinline__ uint32_t f2bf(float f) {
    uint32_t x = __float_as_uint(f);
    return (x + 0x7fffu + ((x >> 16) & 1u)) >> 16;   // RNE
}
__device__ __forceinline__ uint32_t pack2(float a, float b) {
    return f2bf(a) | (f2bf(b) << 16);
}
__device__ __forceinline__ f32x4 ld_cf4(const ushort* p) {
    uint2 w = *reinterpret_cast<const uint2*>(p);
    f32x4 v;
    v[0] = __uint_as_float(w.x << 16);
    v[1] = __uint_as_float(w.x & 0xffff0000u);
    v[2] = __uint_as_float(w.y << 16);
    v[3] = __uint_as_float(w.y & 0xffff0000u);
    return v;
}

// ---- pre-pass: W1T + W2F (fragment order) + bucket fill --------------------
__global__ __launch_bounds__(256) void prep_kernel(
    const float* __restrict__ fc_w1, const float* __restrict__ fc_w2,
    const int* __restrict__ edge_index,
    ushort* __restrict__ W1T, ushort* __restrict__ W2F,
    int* __restrict__ cursor, int* __restrict__ elist, int do_fill)
{
    int i = blockIdx.x * 256 + threadIdx.x;
    if (i < 64 * 64) {
        int k = i >> 6, j = i & 63;
        W1T[k * 64 + j] = (ushort)f2bf(fc_w1[j * 64 + k]);
    }
    int i2 = i - 64 * 64;
    if (i2 >= 0 && i2 < 100 * 1024) {
        int t  = i2 >> 10, r = i2 & 1023;
        int kh = r >> 9,  rr = r & 511;
        int l  = rr >> 3, ii = rr & 7;
        int j  = t * 16 + (l & 15);
        int k  = kh * 32 + ((l >> 4) << 3) + ii;
        W2F[i2] = (ushort)f2bf(fc_w2[k * WN + j]);
    }
    int i3 = i2 - 100 * 1024;
    if (i3 >= 0 && i3 < NE && do_fill) {
        int s = edge_index[i3];
        int pos = atomicAdd(&cursor[s], 1);
        if (pos < DCAP) elist[s * DCAP + pos] = i3;
    }
}

// == edge kernel: 4 waves x 64 edges (ms=0..3), 4-deep pipeline, EPB2=256 ====
// __launch_bounds__(256,1): allocator ceiling 512 VGPR -> no spill (R12 fix)
__global__ __launch_bounds__(256, 1) void edge_kernel(
    const float* __restrict__ node_attr,
    const float* __restrict__ edge_attr,
    const float* __restrict__ edge_sh,
    const float* __restrict__ fc_b1,
    const float* __restrict__ fc_b2,
    const int*   __restrict__ edge_index,
    const ushort* __restrict__ W1T,
    const ushort* __restrict__ W2F,
    float* __restrict__ tpbuf)
{
    __shared__ ushort cfh[64][EPB2];                              // 32 KB
    __shared__ float  shS[4][EPB2];                               //  4 KB
    __shared__ __attribute__((aligned(16))) ushort pool[16384];   // 32 KB relay

    const int tid  = threadIdx.x;
    const int wave = tid >> 6;
    const int lane = tid & 63;
    const int g    = lane >> 4;
    const int q    = lane & 15;
    const int E0   = blockIdx.x * EPB2;

    // ---------------- preamble: per-edge coefficient table (e = tid) ---------
    {
        const int e    = tid;
        const int dstn = edge_index[NE + E0 + e];
        const float4 sh = reinterpret_cast<const float4*>(edge_sh)[E0 + e];
        const float4* xp = reinterpret_cast<const float4*>(node_attr + (size_t)dstn * IND);
        float xr[56];
        #pragma unroll
        for (int i = 0; i < 14; ++i) {
            float4 v = xp[i];
            xr[4*i] = v.x; xr[4*i+1] = v.y; xr[4*i+2] = v.z; xr[4*i+3] = v.w;
        }
        #pragma unroll
        for (int u = 0; u < 32; ++u) cfh[u][e] = (ushort)f2bf(xr[u]);
        #pragma unroll
        for (int u = 0; u < 8; ++u) {
            cfh[32 + 3*u + 0][e] = (ushort)f2bf(sh.x * xr[32 + 3*u + 0]);
            cfh[32 + 3*u + 1][e] = (ushort)f2bf(sh.x * xr[32 + 3*u + 1]);
            cfh[32 + 3*u + 2][e] = (ushort)f2bf(sh.x * xr[32 + 3*u + 2]);
            cfh[56 + u][e] = (ushort)f2bf(
                CG_C * (xr[32+3*u]*sh.y + xr[32+3*u+1]*sh.z + xr[32+3*u+2]*sh.w));
        }
        shS[0][e] = sh.x;
        shS[1][e] = sh.y;  shS[2][e] = sh.z;  shS[3][e] = sh.w;
    }

    // ---------------- GEMM1: h for 64 edges/wave (ms = 0..3) -----------------
    f32x4 d1[4][4];   // [ms][mt]
    #pragma unroll
    for (int mt = 0; mt < 4; ++mt) {
        const float4 b1v = *reinterpret_cast<const float4*>(fc_b1 + mt*16 + 4*g);
        #pragma unroll
        for (int ms = 0; ms < 4; ++ms)
            d1[ms][mt] = (f32x4){b1v.x, b1v.y, b1v.z, b1v.w};
    }

    #pragma unroll
    for (int kh = 0; kh < 2; ++kh) {
        bf16x8 bfr[4];
        #pragma unroll
        for (int ms = 0; ms < 4; ++ms) {
            const int e = E0 + wave*64 + ms*16 + q;
            const float* ap = edge_attr + (size_t)e * 64 + kh*32 + g*8;
            float4 f0 = *reinterpret_cast<const float4*>(ap);
            float4 f1 = *reinterpret_cast<const float4*>(ap + 4);
            union { uint32_t u[4]; bf16x8 v; } cv;
            cv.u[0] = pack2(f0.x, f0.y); cv.u[1] = pack2(f0.z, f0.w);
            cv.u[2] = pack2(f1.x, f1.y); cv.u[3] = pack2(f1.z, f1.w);
            bfr[ms] = cv.v;
        }
        #pragma unroll
        for (int mt = 0; mt < 4; ++mt) {
            bf16x8 afr = *reinterpret_cast<const bf16x8*>(W1T + (mt*16 + q)*64 + kh*32 + g*8);
            #pragma unroll
            for (int ms = 0; ms < 4; ++ms)
                d1[ms][mt] = __builtin_amdgcn_mfma_f32_16x16x32_bf16(afr, bfr[ms], d1[ms][mt], 0, 0, 0);
        }
    }
    #pragma unroll
    for (int mt = 0; mt < 4; ++mt) {
        const int kg = 2*mt + (g >> 1);
        #pragma unroll
        for (int ms = 0; ms < 4; ++ms) {
            float v0 = fmaxf(d1[ms][mt][0], 0.f);
            float v1 = fmaxf(d1[ms][mt][1], 0.f);
            float v2 = fmaxf(d1[ms][mt][2], 0.f);
            float v3 = fmaxf(d1[ms][mt][3], 0.f);
            uint32_t* wp = reinterpret_cast<uint32_t*>(
                &pool[wave*4096 + ms*1024 + (kg*16 + q)*8 + 4*(g & 1)]);
            wp[0] = pack2(v0, v1);
            wp[1] = pack2(v2, v3);
        }
    }

    bf16x8 af[4][2];
    #pragma unroll
    for (int ms = 0; ms < 4; ++ms)
        #pragma unroll
        for (int kh = 0; kh < 2; ++kh)
            af[ms][kh] = *reinterpret_cast<const bf16x8*>(
                &pool[wave*4096 + ms*1024 + ((kh*4 + g)*16 + q)*8]);

    // 4-deep named-slot prefetch pipeline for the W2F tile stream
    bf16x8 A0, A1, B0, B1, C0, C1, D0, D1;
    float  Ab, Bb, Cb, Db;
    auto load_slot = [&](int t, bf16x8& b0, bf16x8& b1, float& bb) {
        const ushort* p = W2F + (size_t)t * 1024 + lane * 8;
        b0 = *reinterpret_cast<const bf16x8*>(p);
        b1 = *reinterpret_cast<const bf16x8*>(p + 512);
        bb = fc_b2[t * 16 + q];
    };
    load_slot(0, A0, A1, Ab);
    load_slot(1, B0, B1, Bb);
    load_slot(2, C0, C1, Cb);
    load_slot(3, D0, D1, Db);

    __syncthreads();

    const int ebase = wave*64 + 4*g;
    f32x4 s0v[4];
    #pragma unroll
    for (int ms = 0; ms < 4; ++ms)
        s0v[ms] = *reinterpret_cast<const f32x4*>(&shS[0][ebase + ms*16]);

    float o0[4][2][4];
    float ttv[4][4];
    float o1v[4][4][3];
    #pragma unroll
    for (int ms = 0; ms < 4; ++ms) {
        #pragma unroll
        for (int r = 0; r < 4; ++r) {
            o0[ms][0][r] = 0.f; o0[ms][1][r] = 0.f; ttv[ms][r] = 0.f;
            o1v[ms][r][0] = 0.f; o1v[ms][r][1] = 0.f; o1v[ms][r][2] = 0.f;
        }
    }

    auto mfma2 = [&](const bf16x8& b0, const bf16x8& b1, float b2v, f32x4* accv) {
        #pragma unroll
        for (int ms = 0; ms < 4; ++ms) {
            f32x4 a = (f32x4){b2v, b2v, b2v, b2v};
            a = __builtin_amdgcn_mfma_f32_16x16x32_bf16(af[ms][0], b0, a, 0, 0, 0);
            a = __builtin_amdgcn_mfma_f32_16x16x32_bf16(af[ms][1], b1, a, 0, 0, 0);
            accv[ms] = a;
        }
    };

    const int qh = q >> 3;

    // ---- region 1: tiles 0..63, coef s0*x0[u], out0 -------------------------
    #pragma unroll 1
    for (int c = 0; c < 16; ++c) {
        const int t4 = 4*c;
        {   // u0 = 2c : tiles t4, t4+1 (slots A, B)
            const int u0 = 2*c;
            f32x4 cu[4];
            #pragma unroll
            for (int ms = 0; ms < 4; ++ms) cu[ms] = ld_cf4(&cfh[u0][ebase + ms*16]);
            {
                f32x4 w2[4];
                mfma2(A0, A1, Ab, w2);  load_slot(t4 + 4, A0, A1, Ab);
                #pragma unroll
                for (int ms = 0; ms < 4; ++ms)
                    #pragma unroll
                    for (int r = 0; r < 4; ++r)
                        o0[ms][0][r] = fmaf(s0v[ms][r]*cu[ms][r], w2[ms][r], o0[ms][0][r]);
            }
            {
                f32x4 w2[4];
                mfma2(B0, B1, Bb, w2);  load_slot(t4 + 5, B0, B1, Bb);
                #pragma unroll
                for (int ms = 0; ms < 4; ++ms)
                    #pragma unroll
                    for (int r = 0; r < 4; ++r)
                        o0[ms][1][r] = fmaf(s0v[ms][r]*cu[ms][r], w2[ms][r], o0[ms][1][r]);
            }
        }
        {   // u1 = 2c+1 : tiles t4+2, t4+3 (slots C, D)
            const int u1 = 2*c + 1;
            f32x4 cu[4];
            #pragma unroll
            for (int ms = 0; ms < 4; ++ms) cu[ms] = ld_cf4(&cfh[u1][ebase + ms*16]);
            {
                f32x4 w2[4];
                mfma2(C0, C1, Cb, w2);  load_slot(t4 + 6, C0, C1, Cb);
                #pragma unroll
                for (int ms = 0; ms < 4; ++ms)
                    #pragma unroll
                    for (int r = 0; r < 4; ++r)
                        o0[ms][0][r] = fmaf(s0v[ms][r]*cu[ms][r], w2[ms][r], o0[ms][0][r]);
            }
            {
                f32x4 w2[4];
                mfma2(D0, D1, Db, w2);  load_slot(t4 + 7, D0, D1, Db);
                #pragma unroll
                for (int ms = 0; ms < 4; ++ms)
                    #pragma unroll
                    for (int r = 0; r < 4; ++r)
                        o0[ms][1][r] = fmaf(s0v[ms][r]*cu[ms][r], w2[ms][r], o0[ms][1][r]);
            }
        }
    }

    // ---- region 2: tiles 64..79, u = 2*(t-64)+qh, coef x0[u], tt ------------
    #define EPI_R2(U) { _Pragma("unroll") for (int ms = 0; ms < 4; ++ms) { \
        f32x4 cfv = ld_cf4(&cfh[U][ebase + ms*16]); \
        _Pragma("unroll") for (int r = 0; r < 4; ++r) \
            ttv[ms][r] = fmaf(cfv[r], w2[ms][r], ttv[ms][r]); } }

    #pragma unroll 1
    for (int d = 0; d < 4; ++d) {
        const int t4 = 64 + 4*d;
        { f32x4 w2[4]; mfma2(A0, A1, Ab, w2); load_slot(t4 + 4, A0, A1, Ab); EPI_R2(8*d + qh) }
        { f32x4 w2[4]; mfma2(B0, B1, Bb, w2); load_slot(t4 + 5, B0, B1, Bb); EPI_R2(8*d + 2 + qh) }
        { f32x4 w2[4]; mfma2(C0, C1, Cb, w2); load_slot(t4 + 6, C0, C1, Cb); EPI_R2(8*d + 4 + qh) }
        { f32x4 w2[4]; mfma2(D0, D1, Db, w2); load_slot(t4 + 7, D0, D1, Db); EPI_R2(8*d + 6 + qh) }
    }
    #undef EPI_R2

    // ---- region 3: tiles 80..83, u = 2*tc+qh, coef s0*x1[u][m], o1 ----------
    #define EPI_R3(U) { _Pragma("unroll") for (int ms = 0; ms < 4; ++ms) \
        _Pragma("unroll") for (int m = 0; m < 3; ++m) { \
            f32x4 cfv = ld_cf4(&cfh[32 + (U)*3 + m][ebase + ms*16]); \
            _Pragma("unroll") for (int r = 0; r < 4; ++r) \
                o1v[ms][r][m] = fmaf(cfv[r], w2[ms][r], o1v[ms][r][m]); } }
    {
        { f32x4 w2[4]; mfma2(A0, A1, Ab, w2); load_slot(84, A0, A1, Ab); EPI_R3(qh) }
        { f32x4 w2[4]; mfma2(B0, B1, Bb, w2); load_slot(85, B0, B1, Bb); EPI_R3(2 + qh) }
        { f32x4 w2[4]; mfma2(C0, C1, Cb, w2); load_slot(86, C0, C1, Cb); EPI_R3(4 + qh) }
        { f32x4 w2[4]; mfma2(D0, D1, Db, w2); load_slot(87, D0, D1, Db); EPI_R3(6 + qh) }
    }
    #undef EPI_R3

    // ---- region 4: tiles 84..99, coef y1[u4], out0 --------------------------
    #pragma unroll 1
    for (int d = 0; d < 4; ++d) {
        const int t4 = 84 + 4*d;
        int tn;
        {   // u0 = 2d : slots A, B
            const int u0 = 2*d;
            f32x4 cu[4];
            #pragma unroll
            for (int ms = 0; ms < 4; ++ms) cu[ms] = ld_cf4(&cfh[56 + u0][ebase + ms*16]);
            {
                f32x4 w2[4];
                mfma2(A0, A1, Ab, w2);  tn = t4 + 4; load_slot(tn < 100 ? tn : 99, A0, A1, Ab);
                #pragma unroll
                for (int ms = 0; ms < 4; ++ms)
                    #pragma unroll
                    for (int r = 0; r < 4; ++r)
                        o0[ms][0][r] = fmaf(cu[ms][r], w2[ms][r], o0[ms][0][r]);
            }
            {
                f32x4 w2[4];
                mfma2(B0, B1, Bb, w2);  tn = t4 + 5; load_slot(tn < 100 ? tn : 99, B0, B1, Bb);
                #pragma unroll
                for (int ms = 0; ms < 4; ++ms)
                    #pragma unroll
                    for (int r = 0; r < 4; ++r)
                        o0[ms][1][r] = fmaf(cu[ms][r], w2[ms][r], o0[ms][1][r]);
            }
        }
        {   // u1 = 2d+1 : slots C, D
            const int u1 = 2*d + 1;
            f32x4 cu[4];
            #pragma unroll
            for (int ms = 0; ms < 4; ++ms) cu[ms] = ld_cf4(&cfh[56 + u1][ebase + ms*16]);
            {
                f32x4 w2[4];
                mfma2(C0, C1, Cb, w2);  tn = t4 + 6; load_slot(tn < 100 ? tn : 99, C0, C1, Cb);
                #pragma unroll
                for (int ms = 0; ms < 4; ++ms)
                    #pragma unroll
                    for (int r = 0; r < 4; ++r)
                        o0[ms][0][r] = fmaf(cu[ms][r], w2[ms][r], o0[ms][0][r]);
            }
            {
                f32x4 w2[4];
                mfma2(D0, D1, Db, w2);  tn = t4 + 7; load_slot(tn < 100 ? tn : 99, D0, D1, Db);
                #pragma unroll
                for (int ms = 0; ms < 4; ++ms)
                    #pragma unroll
                    for (int r = 0; r < 4; ++r)
                        o0[ms][1][r] = fmaf(cu[ms][r], w2[ms][r], o0[ms][1][r]);
            }
        }
    }

    // ---- finish: reduce u-halves (lane ^ 8), coalesced per-edge stores ------
    #pragma unroll
    for (int ms = 0; ms < 4; ++ms)
        #pragma unroll
        for (int r = 0; r < 4; ++r) {
            ttv[ms][r] += __shfl_xor(ttv[ms][r], 8, 64);
            #pragma unroll
            for (int m = 0; m < 3; ++m)
                o1v[ms][r][m] += __shfl_xor(o1v[ms][r][m], 8, 64);
        }

    #pragma unroll
    for (int ms = 0; ms < 4; ++ms) {
        const int eb = ebase + ms*16;
        const f32x4 s1x = *reinterpret_cast<const f32x4*>(&shS[1][eb]);
        const f32x4 s1y = *reinterpret_cast<const f32x4*>(&shS[2][eb]);
        const f32x4 s1z = *reinterpret_cast<const f32x4*>(&shS[3][eb]);
        #pragma unroll
        for (int r = 0; r < 4; ++r) {
            float* tp = tpbuf + (size_t)(E0 + eb + r) * IND;
            tp[q]      = PATH_NORM_C * o0[ms][0][r];
            tp[16 + q] = PATH_NORM_C * o0[ms][1][r];
            if ((q & 8) == 0) {
                const int v = q & 7;
                tp[32 + 3*v + 0] = PATH_NORM_C * (o1v[ms][r][0] + s1x[r]*ttv[ms][r]);
                tp[32 + 3*v + 1] = PATH_NORM_C * (o1v[ms][r][1] + s1y[r]*ttv[ms][r]);
                tp[32 + 3*v + 2] = PATH_NORM_C * (o1v[ms][r][2] + s1z[r]*ttv[ms][r]);
            }
        }
    }
}

// ---- gather: one wave per node, mean + residual ---------------------------
__global__ __launch_bounds__(256) void gather_kernel(
    const float* __restrict__ tpbuf, const int* __restrict__ cursor,
    const int* __restrict__ elist, const float* __restrict__ node_attr,
    float* __restrict__ out)
{
    const int node = blockIdx.x * 4 + (threadIdx.x >> 6);
    const int j = threadIdx.x & 63;
    if (node >= NN) return;
    const int degt = cursor[node];
    const int deg = (degt < DCAP) ? degt : DCAP;
    float sum = 0.f;
    #pragma unroll 4
    for (int i = 0; i < deg; ++i) {
        const int e = elist[node * DCAP + i];
        if (j < 56) sum += tpbuf[(size_t)e * IND + j];
    }
    if (j < 56) {
        const float c = (degt > 0) ? (float)degt : 1.f;
        out[node * IND + j] = sum / c + node_attr[node * IND + j];
    }
}

// ================= fallback path (atomics, small ws) ========================
__global__ __launch_bounds__(256, 3) void edge_kernel_fb(
    const float* __restrict__ node_attr, const float* __restrict__ edge_attr,
    const float* __restrict__ edge_sh, const float* __restrict__ fc_b1,
    const float* __restrict__ fc_b2, const int* __restrict__ edge_index,
    const ushort* __restrict__ W1T, const ushort* __restrict__ W2F,
    float* __restrict__ acc, float* __restrict__ cnt)
{
    __shared__ ushort cfh[64][EPB];
    __shared__ float  shS[4][EPB];
    __shared__ int    src_lds[EPB];
    __shared__ __attribute__((aligned(16))) ushort pool[8192];

    const int tid  = threadIdx.x;
    const int wave = tid >> 6;
    const int lane = tid & 63;
    const int g    = lane >> 4;
    const int q    = lane & 15;
    const int E0   = blockIdx.x * EPB;

    if (tid < EPB) {
        const int e    = tid;
        const int srcn = edge_index[E0 + e];
        const int dstn = edge_index[NE + E0 + e];
        src_lds[e] = srcn;
        const float4 sh = reinterpret_cast<const float4*>(edge_sh)[E0 + e];
        const float4* xp = reinterpret_cast<const float4*>(node_attr + (size_t)dstn * IND);
        float xr[56];
        #pragma unroll
        for (int i = 0; i < 14; ++i) {
            float4 v = xp[i];
            xr[4*i] = v.x; xr[4*i+1] = v.y; xr[4*i+2] = v.z; xr[4*i+3] = v.w;
        }
        #pragma unroll
        for (int u = 0; u < 32; ++u) cfh[u][e] = (ushort)f2bf(xr[u]);
        #pragma unroll
        for (int u = 0; u < 8; ++u) {
            cfh[32 + 3*u + 0][e] = (ushort)f2bf(sh.x * xr[32 + 3*u + 0]);
            cfh[32 + 3*u + 1][e] = (ushort)f2bf(sh.x * xr[32 + 3*u + 1]);
            cfh[32 + 3*u + 2][e] = (ushort)f2bf(sh.x * xr[32 + 3*u + 2]);
            cfh[56 + u][e] = (ushort)f2bf(
                CG_C * (xr[32+3*u]*sh.y + xr[32+3*u+1]*sh.z + xr[32+3*u+2]*sh.w));
        }
        shS[0][e] = sh.x;
        shS[1][e] = sh.y;  shS[2][e] = sh.z;  shS[3][e] = sh.w;
    }

    f32x4 d1[2][4];
    #pragma unroll
    for (int mt = 0; mt < 4; ++mt) {
        const float4 b1v = *reinterpret_cast<const float4*>(fc_b1 + mt*16 + 4*g);
        #pragma unroll
        for (int ms = 0; ms < 2; ++ms)
            d1[ms][mt] = (f32x4){b1v.x, b1v.y, b1v.z, b1v.w};
    }
    #pragma unroll
    for (int kh = 0; kh < 2; ++kh) {
        bf16x8 bfr[2];
        #pragma unroll
        for (int ms = 0; ms < 2; ++ms) {
            const int e = E0 + wave*32 + ms*16 + q;
            const float* ap = edge_attr + (size_t)e * 64 + kh*32 + g*8;
            float4 f0 = *reinterpret_cast<const float4*>(ap);
            float4 f1 = *reinterpret_cast<const float4*>(ap + 4);
            union { uint32_t u[4]; bf16x8 v; } cv;
            cv.u[0] = pack2(f0.x, f0.y); cv.u[1] = pack2(f0.z, f0.w);
            cv.u[2] = pack2(f1.x, f1.y); cv.u[3] = pack2(f1.z, f1.w);
            bfr[ms] = cv.v;
        }
        #pragma unroll
        for (int mt = 0; mt < 4; ++mt) {
            bf16x8 afr = *reinterpret_cast<const bf16x8*>(W1T + (mt*16 + q)*64 + kh*32 + g*8);
            #pragma unroll
            for (int ms = 0; ms < 2; ++ms)
                d1[ms][mt] = __builtin_amdgcn_mfma_f32_16x16x32_bf16(afr, bfr[ms], d1[ms][mt], 0, 0, 0);
        }
    }
    #pragma unroll
    for (int mt = 0; mt < 4; ++mt) {
        const int kg = 2*mt + (g >> 1);
        #pragma unroll
        for (int ms = 0; ms < 2; ++ms) {
            float v0 = fmaxf(d1[ms][mt][0], 0.f);
            float v1 = fmaxf(d1[ms][mt][1], 0.f);
            float v2 = fmaxf(d1[ms][mt][2], 0.f);
            float v3 = fmaxf(d1[ms][mt][3], 0.f);
            uint32_t* wp = reinterpret_cast<uint32_t*>(
                &pool[wave*2048 + ms*1024 + (kg*16 + q)*8 + 4*(g & 1)]);
            wp[0] = pack2(v0, v1);
            wp[1] = pack2(v2, v3);
        }
    }
    bf16x8 af[2][2];
    #pragma unroll
    for (int ms = 0; ms < 2; ++ms)
        #pragma unroll
        for (int kh = 0; kh < 2; ++kh)
            af[ms][kh] = *reinterpret_cast<const bf16x8*>(
                &pool[wave*2048 + ms*1024 + ((kh*4 + g)*16 + q)*8]);

    bf16x8 A0, A1, B0, B1, C0, C1, D0, D1;
    float  Ab, Bb, Cb, Db;
    auto load_slot = [&](int t, bf16x8& b0, bf16x8& b1, float& bb) {
        const ushort* p = W2F + (size_t)t * 1024 + lane * 8;
        b0 = *reinterpret_cast<const bf16x8*>(p);
        b1 = *reinterpret_cast<const bf16x8*>(p + 512);
        bb = fc_b2[t * 16 + q];
    };
    load_slot(0, A0, A1, Ab);
    load_slot(1, B0, B1, Bb);
    load_slot(2, C0, C1, Cb);
    load_slot(3, D0, D1, Db);
    __syncthreads();

    const int ebase = wave*32 + 4*g;
    f32x4 s0v[2];
    s0v[0] = *reinterpret_cast<const f32x4*>(&shS[0][ebase]);
    s0v[1] = *reinterpret_cast<const f32x4*>(&shS[0][ebase + 16]);
    float o0[2][2][4];
    float ttv[2][4];
    float o1v[2][4][3];
    #pragma unroll
    for (int ms = 0; ms < 2; ++ms)
        #pragma unroll
        for (int r = 0; r < 4; ++r) {
            o0[ms][0][r] = 0.f; o0[ms][1][r] = 0.f; ttv[ms][r] = 0.f;
            o1v[ms][r][0] = 0.f; o1v[ms][r][1] = 0.f; o1v[ms][r][2] = 0.f;
        }
    auto mfma2 = [&](const bf16x8& b0, const bf16x8& b1, float b2v, f32x4* accv) {
        #pragma unroll
        for (int ms = 0; ms < 2; ++ms) {
            f32x4 a = (f32x4){b2v, b2v, b2v, b2v};
            a = __builtin_amdgcn_mfma_f32_16x16x32_bf16(af[ms][0], b0, a, 0, 0, 0);
            a = __builtin_amdgcn_mfma_f32_16x16x32_bf16(af[ms][1], b1, a, 0, 0, 0);
            accv[ms] = a;
        }
    };
    const int qh = q >> 3;
    #pragma unroll 1
    for (int c = 0; c < 16; ++c) {
        const int t4 = 4*c;
        const int u0 = 2*c, u1 = 2*c + 1;
        f32x4 c00 = ld_cf4(&cfh[u0][ebase]);
        f32x4 c01 = ld_cf4(&cfh[u0][ebase + 16]);
        f32x4 c10 = ld_cf4(&cfh[u1][ebase]);
        f32x4 c11 = ld_cf4(&cfh[u1][ebase + 16]);
        f32x4 w2[2];
        mfma2(A0, A1, Ab, w2);  load_slot(t4 + 4, A0, A1, Ab);
        #pragma unroll
        for (int r = 0; r < 4; ++r) {
            o0[0][0][r] = fmaf(s0v[0][r]*c00[r], w2[0][r], o0[0][0][r]);
            o0[1][0][r] = fmaf(s0v[1][r]*c01[r], w2[1][r], o0[1][0][r]);
        }
        mfma2(B0, B1, Bb, w2);  load_slot(t4 + 5, B0, B1, Bb);
        #pragma unroll
        for (int r = 0; r < 4; ++r) {
            o0[0][1][r] = fmaf(s0v[0][r]*c00[r], w2[0][r], o0[0][1][r]);
            o0[1][1][r] = fmaf(s0v[1][r]*c01[r], w2[1][r], o0[1][1][r]);
        }
        mfma2(C0, C1, Cb, w2);  load_slot(t4 + 6, C0, C1, Cb);
        #pragma unroll
        for (int r = 0; r < 4; ++r) {
            o0[0][0][r] = fmaf(s0v[0][r]*c10[r], w2[0][r], o0[0][0][r]);
            o0[1][0][r] = fmaf(s0v[1][r]*c11[r], w2[1][r], o0[1][0][r]);
        }
        mfma2(D0, D1, Db, w2);  load_slot(t4 + 7, D0, D1, Db);
        #pragma unroll
        for (int r = 0; r < 4; ++r) {
            o0[0][1][r] = fmaf(s0v[0][r]*c10[r], w2[0][r], o0[0][1][r]);
            o0[1][1][r] = fmaf(s0v[1][r]*c11[r], w2[1][r], o0[1][1][r]);
        }
    }
    #pragma unroll 1
    for (int d = 0; d < 4; ++d) {
        const int t4 = 64 + 4*d;
        f32x4 w2[2];
        mfma2(A0, A1, Ab, w2);  load_slot(t4 + 4, A0, A1, Ab);
        {
            const int u = 8*d + qh;
            #pragma unroll
            for (int ms = 0; ms < 2; ++ms) {
                f32x4 cfv = ld_cf4(&cfh[u][ebase + ms*16]);
                #pragma unroll
                for (int r = 0; r < 4; ++r) ttv[ms][r] = fmaf(cfv[r], w2[ms][r], ttv[ms][r]);
            }
        }
        mfma2(B0, B1, Bb, w2);  load_slot(t4 + 5, B0, B1, Bb);
        {
            const int u = 8*d + 2 + qh;
            #pragma unroll
            for (int ms = 0; ms < 2; ++ms) {
                f32x4 cfv = ld_cf4(&cfh[u][ebase + ms*16]);
                #pragma unroll
                for (int r = 0; r < 4; ++r) ttv[ms][r] = fmaf(cfv[r], w2[ms][r], ttv[ms][r]);
            }
        }
        mfma2(C0, C1, Cb, w2);  load_slot(t4 + 6, C0, C1, Cb);
        {
            const int u = 8*d + 4 + qh;
            #pragma unroll
            for (int ms = 0; ms < 2; ++ms) {
                f32x4 cfv = ld_cf4(&cfh[u][ebase + ms*16]);
                #pragma unroll
                for (int r = 0; r < 4; ++r) ttv[ms][r] = fmaf(cfv[r], w2[ms][r], ttv[ms][r]);
            }
        }
        mfma2(D0, D1, Db, w2);  load_slot(t4 + 7, D0, D1, Db);
        {
            const int u = 8*d + 6 + qh;
            #pragma unroll
            for (int ms = 0; ms < 2; ++ms) {
                f32x4 cfv = ld_cf4(&cfh[u][ebase + ms*16]);
                #pragma unroll
                for (int r = 0; r < 4; ++r) ttv[ms][r] = fmaf(cfv[r], w2[ms][r], ttv[ms][r]);
            }
        }
    }
    {
        f32x4 w2[2];
        #define R3_BODY(TC)                                                         \
            {                                                                       \
                const int u = 2*(TC) + qh;                                          \
                _Pragma("unroll")                                                   \
                for (int ms = 0; ms < 2; ++ms)                                      \
                    _Pragma("unroll")                                               \
                    for (int m = 0; m < 3; ++m) {                                   \
                        f32x4 cfv = ld_cf4(&cfh[32 + u*3 + m][ebase + ms*16]);      \
                        _Pragma("unroll")                                           \
                        for (int r = 0; r < 4; ++r)                                 \
                            o1v[ms][r][m] = fmaf(cfv[r], w2[ms][r], o1v[ms][r][m]); \
                    }                                                               \
            }
        mfma2(A0, A1, Ab, w2);  load_slot(84, A0, A1, Ab);  R3_BODY(0)
        mfma2(B0, B1, Bb, w2);  load_slot(85, B0, B1, Bb);  R3_BODY(1)
        mfma2(C0, C1, Cb, w2);  load_slot(86, C0, C1, Cb);  R3_BODY(2)
        mfma2(D0, D1, Db, w2);  load_slot(87, D0, D1, Db);  R3_BODY(3)
        #undef R3_BODY
    }
    #pragma unroll 1
    for (int d = 0; d < 4; ++d) {
        const int t4 = 84 + 4*d;
        const int u0 = 2*d, u1 = 2*d + 1;
        f32x4 c00 = ld_cf4(&cfh[56 + u0][ebase]);
        f32x4 c01 = ld_cf4(&cfh[56 + u0][ebase + 16]);
        f32x4 c10 = ld_cf4(&cfh[56 + u1][ebase]);
        f32x4 c11 = ld_cf4(&cfh[56 + u1][ebase + 16]);
        f32x4 w2[2];
        int tn;
        mfma2(A0, A1, Ab, w2);  tn = t4 + 4; load_slot(tn < 100 ? tn : 99, A0, A1, Ab);
        #pragma unroll
        for (int r = 0; r < 4; ++r) {
            o0[0][0][r] = fmaf(c00[r], w2[0][r], o0[0][0][r]);
            o0[1][0][r] = fmaf(c01[r], w2[1][r], o0[1][0][r]);
        }
        mfma2(B0, B1, Bb, w2);  tn = t4 + 5; load_slot(tn < 100 ? tn : 99, B0, B1, Bb);
        #pragma unroll
        for (int r = 0; r < 4; ++r) {
            o0[0][1][r] = fmaf(c00[r], w2[0][r], o0[0][1][r]);
            o0[1][1][r] = fmaf(c01[r], w2[1][r], o0[1][1][r]);
        }
        mfma2(C0, C1, Cb, w2);  tn = t4 + 6; load_slot(tn < 100 ? tn : 99, C0, C1, Cb);
        #pragma unroll
        for (int r = 0; r < 4; ++r) {
            o0[0][0][r] = fmaf(c10[r], w2[0][r], o0[0][0][r]);
            o0[1][0][r] = fmaf(c11[r], w2[1][r], o0[1][0][r]);
        }
        mfma2(D0, D1, Db, w2);  tn = t4 + 7; load_slot(tn < 100 ? tn : 99, D0, D1, Db);
        #pragma unroll
        for (int r = 0; r < 4; ++r) {
            o0[0][1][r] = fmaf(c10[r], w2[0][r], o0[0][1][r]);
            o0[1][1][r] = fmaf(c11[r], w2[1][r], o0[1][1][r]);
        }
    }
    #pragma unroll
    for (int ms = 0; ms < 2; ++ms)
        #pragma unroll
        for (int r = 0; r < 4; ++r) {
            ttv[ms][r] += __shfl_xor(ttv[ms][r], 8, 64);
            #pragma unroll
            for (int m = 0; m < 3; ++m)
                o1v[ms][r][m] += __shfl_xor(o1v[ms][r][m], 8, 64);
        }
    #pragma unroll
    for (int ms = 0; ms < 2; ++ms) {
        const int eb = ebase + ms*16;
        const int4 srcv = *reinterpret_cast<const int4*>(&src_lds[eb]);
        const f32x4 s1x = *reinterpret_cast<const f32x4*>(&shS[1][eb]);
        const f32x4 s1y = *reinterpret_cast<const f32x4*>(&shS[2][eb]);
        const f32x4 s1z = *reinterpret_cast<const f32x4*>(&shS[3][eb]);
        #pragma unroll
        for (int r = 0; r < 4; ++r) {
            const int node = (r == 0) ? srcv.x : (r == 1) ? srcv.y : (r == 2) ? srcv.z : srcv.w;
            float* ap = acc + (size_t)node * IND;
            atomicAdd(ap + q,      PATH_NORM_C * o0[ms][0][r]);
            atomicAdd(ap + 16 + q, PATH_NORM_C * o0[ms][1][r]);
            if ((q & 8) == 0) {
                const int v = q & 7;
                atomicAdd(ap + 32 + 3*v + 0, PATH_NORM_C * (o1v[ms][r][0] + s1x[r]*ttv[ms][r]));
                atomicAdd(ap + 32 + 3*v + 1, PATH_NORM_C * (o1v[ms][r][1] + s1y[r]*ttv[ms][r]));
                atomicAdd(ap + 32 + 3*v + 2, PATH_NORM_C * (o1v[ms][r][2] + s1z[r]*ttv[ms][r]));
            }
        }
    }
    if (lane < 32) atomicAdd(cnt + src_lds[wave*32 + lane], 1.0f);
}

__global__ __launch_bounds__(256) void finalize_kernel(
    const float* __restrict__ acc, const float* __restrict__ cnt,
    const float* __restrict__ node_attr, float* __restrict__ out)
{
    const int i = blockIdx.x * 256 + threadIdx.x;
    if (i >= NN * IND) return;
    const int n = i / IND;
    const float c = fmaxf(cnt[n], 1.0f);
    out[i] = acc[i] / c + node_attr[i];
}

extern "C" void kernel_launch(void* const* d_in, const int* in_sizes, int n_in,
                              void* d_out, int out_size, void* d_ws, size_t ws_size,
                              hipStream_t stream) {
    const float* node_attr = (const float*)d_in[0];
    const float* edge_attr = (const float*)d_in[1];
    const float* edge_sh   = (const float*)d_in[2];
    const float* fc_w1     = (const float*)d_in[3];
    const float* fc_b1     = (const float*)d_in[4];
    const float* fc_w2     = (const float*)d_in[5];
    const float* fc_b2     = (const float*)d_in[6];
    const int*   edge_index = (const int*)d_in[7];

    char* ws = (char*)d_ws;
    // main-path layout
    int*    cursor = (int*)(ws + 0);                  // 40,000
    int*    elist  = (int*)(ws + 40000);              // 2,560,000 -> ends 2,600,000
    ushort* W1T    = (ushort*)(ws + 2600000);         // 8,192
    ushort* W2F    = (ushort*)(ws + 2608192);         // 204,800 -> ends 2,812,992
    float*  tpbuf  = (float*)(ws + 2812992);          // 35,840,000 -> 38,652,992
    const size_t WS_NEEDED = 2812992ull + (size_t)NE * IND * 4;

    if (ws_size >= WS_NEEDED) {
        hipMemsetAsync(cursor, 0, 40000, stream);
        prep_kernel<<<(64*64 + 100*1024 + NE + 255) / 256, 256, 0, stream>>>(
            fc_w1, fc_w2, edge_index, W1T, W2F, cursor, elist, 1);
        edge_kernel<<<NBLK2, 256, 0, stream>>>(
            node_attr, edge_attr, edge_sh, fc_b1, fc_b2, edge_index, W1T, W2F, tpbuf);
        gather_kernel<<<(NN + 3) / 4, 256, 0, stream>>>(
            tpbuf, cursor, elist, node_attr, (float*)d_out);
    } else {
        // fallback layout: acc/cnt at ws+0, weights after
        float*  acc  = (float*)ws;                    // 2,240,000
        float*  cnt  = (float*)(ws + 2240000);        // 40,000 -> 2,280,000
        ushort* W1Tf = (ushort*)(ws + 2280000);
        ushort* W2Ff = (ushort*)(ws + 2288192);
        hipMemsetAsync(ws, 0, 2280000, stream);
        prep_kernel<<<(64*64 + 100*1024 + NE + 255) / 256, 256, 0, stream>>>(
            fc_w1, fc_w2, edge_index, W1Tf, W2Ff, (int*)W1Tf, (int*)W1Tf, 0);
        edge_kernel_fb<<<NBLK, 256, 0, stream>>>(
            node_attr, edge_attr, edge_sh, fc_b1, fc_b2, edge_index, W1Tf, W2Ff, acc, cnt);
        finalize_kernel<<<(NN * IND + 255) / 256, 256, 0, stream>>>(
            acc, cnt, node_attr, (float*)d_out);
    }
}

// Round 14
// 127.262 us; speedup vs baseline: 1.0133x; 1.0133x over previous
//
#include <hip/hip_runtime.h>

#define NN 10000
#define NE 160000
#define IND 56          // 32 + 3*8
#define WN 1600
#define EPB 128         // edges per block (4 waves x 32)
#define NBLK (NE / EPB) // 1250
#define DCAP 64         // max edges per source node bucket

typedef __attribute__((ext_vector_type(8))) short bf16x8;
typedef __attribute__((ext_vector_type(4))) float f32x4;

static constexpr float PATH_NORM_C = 0.15811388300841897f; // 1/sqrt(40)
static constexpr float CG_C        = 0.57735026918962576f; // 1/sqrt(3)

__device__ __forceinline__ uint32_t f2bf(float f) {
    uint32_t x = __float_as_uint(f);
    return (x + 0x7fffu + ((x >> 16) & 1u)) >> 16;   // RNE
}
__device__ __forceinline__ uint32_t pack2(float a, float b) {
    return f2bf(a) | (f2bf(b) << 16);
}
__device__ __forceinline__ f32x4 ld_cf4(const ushort* p) {
    uint2 w = *reinterpret_cast<const uint2*>(p);
    f32x4 v;
    v[0] = __uint_as_float(w.x << 16);
    v[1] = __uint_as_float(w.x & 0xffff0000u);
    v[2] = __uint_as_float(w.y << 16);
    v[3] = __uint_as_float(w.y & 0xffff0000u);
    return v;
}

// ---- pre-pass: W1T + W2F (fragment order) + bucket fill --------------------
__global__ __launch_bounds__(256) void prep_kernel(
    const float* __restrict__ fc_w1, const float* __restrict__ fc_w2,
    const int* __restrict__ edge_index,
    ushort* __restrict__ W1T, ushort* __restrict__ W2F,
    int* __restrict__ cursor, int* __restrict__ elist, int do_fill)
{
    int i = blockIdx.x * 256 + threadIdx.x;
    if (i < 64 * 64) {
        int k = i >> 6, j = i & 63;
        W1T[k * 64 + j] = (ushort)f2bf(fc_w1[j * 64 + k]);
    }
    int i2 = i - 64 * 64;
    if (i2 >= 0 && i2 < 100 * 1024) {
        int t  = i2 >> 10, r = i2 & 1023;
        int kh = r >> 9,  rr = r & 511;
        int l  = rr >> 3, ii = rr & 7;
        int j  = t * 16 + (l & 15);
        int k  = kh * 32 + ((l >> 4) << 3) + ii;
        W2F[i2] = (ushort)f2bf(fc_w2[k * WN + j]);
    }
    int i3 = i2 - 100 * 1024;
    if (i3 >= 0 && i3 < NE && do_fill) {
        int s = edge_index[i3];
        int pos = atomicAdd(&cursor[s], 1);
        if (pos < DCAP) elist[s * DCAP + pos] = i3;
    }
}

// ==== edge kernel: EPB=128 (good TLP) + 8-deep pipeline + (256,1) ceiling ===
__global__ __launch_bounds__(256, 1) void edge_kernel(
    const float* __restrict__ node_attr,
    const float* __restrict__ edge_attr,
    const float* __restrict__ edge_sh,
    const float* __restrict__ fc_b1,
    const float* __restrict__ fc_b2,
    const int*   __restrict__ edge_index,
    const ushort* __restrict__ W1T,
    const ushort* __restrict__ W2F,
    float* __restrict__ tpbuf)
{
    __shared__ ushort cfh[64][EPB];                               // 16 KB
    __shared__ float  shS[4][EPB];                                //  2 KB
    __shared__ __attribute__((aligned(16))) ushort pool[8192];    // 16 KB relay

    const int tid  = threadIdx.x;
    const int wave = tid >> 6;
    const int lane = tid & 63;
    const int g    = lane >> 4;
    const int q    = lane & 15;
    const int E0   = blockIdx.x * EPB;

    // ---------------- preamble: per-edge coefficient table -------------------
    if (tid < EPB) {
        const int e    = tid;
        const int dstn = edge_index[NE + E0 + e];
        const float4 sh = reinterpret_cast<const float4*>(edge_sh)[E0 + e];
        const float4* xp = reinterpret_cast<const float4*>(node_attr + (size_t)dstn * IND);
        float xr[56];
        #pragma unroll
        for (int i = 0; i < 14; ++i) {
            float4 v = xp[i];
            xr[4*i] = v.x; xr[4*i+1] = v.y; xr[4*i+2] = v.z; xr[4*i+3] = v.w;
        }
        #pragma unroll
        for (int u = 0; u < 32; ++u) cfh[u][e] = (ushort)f2bf(xr[u]);
        #pragma unroll
        for (int u = 0; u < 8; ++u) {
            cfh[32 + 3*u + 0][e] = (ushort)f2bf(sh.x * xr[32 + 3*u + 0]);
            cfh[32 + 3*u + 1][e] = (ushort)f2bf(sh.x * xr[32 + 3*u + 1]);
            cfh[32 + 3*u + 2][e] = (ushort)f2bf(sh.x * xr[32 + 3*u + 2]);
            cfh[56 + u][e] = (ushort)f2bf(
                CG_C * (xr[32+3*u]*sh.y + xr[32+3*u+1]*sh.z + xr[32+3*u+2]*sh.w));
        }
        shS[0][e] = sh.x;
        shS[1][e] = sh.y;  shS[2][e] = sh.z;  shS[3][e] = sh.w;
    }

    // ---------------- GEMM1 via transposed MFMA: h_pre[k][e] -----------------
    f32x4 d1[2][4];
    #pragma unroll
    for (int mt = 0; mt < 4; ++mt) {
        const float4 b1v = *reinterpret_cast<const float4*>(fc_b1 + mt*16 + 4*g);
        #pragma unroll
        for (int ms = 0; ms < 2; ++ms)
            d1[ms][mt] = (f32x4){b1v.x, b1v.y, b1v.z, b1v.w};
    }

    #pragma unroll
    for (int kh = 0; kh < 2; ++kh) {
        bf16x8 bfr[2];
        #pragma unroll
        for (int ms = 0; ms < 2; ++ms) {
            const int e = E0 + wave*32 + ms*16 + q;
            const float* ap = edge_attr + (size_t)e * 64 + kh*32 + g*8;
            float4 f0 = *reinterpret_cast<const float4*>(ap);
            float4 f1 = *reinterpret_cast<const float4*>(ap + 4);
            union { uint32_t u[4]; bf16x8 v; } cv;
            cv.u[0] = pack2(f0.x, f0.y); cv.u[1] = pack2(f0.z, f0.w);
            cv.u[2] = pack2(f1.x, f1.y); cv.u[3] = pack2(f1.z, f1.w);
            bfr[ms] = cv.v;
        }
        #pragma unroll
        for (int mt = 0; mt < 4; ++mt) {
            bf16x8 afr = *reinterpret_cast<const bf16x8*>(W1T + (mt*16 + q)*64 + kh*32 + g*8);
            #pragma unroll
            for (int ms = 0; ms < 2; ++ms)
                d1[ms][mt] = __builtin_amdgcn_mfma_f32_16x16x32_bf16(afr, bfr[ms], d1[ms][mt], 0, 0, 0);
        }
    }
    #pragma unroll
    for (int mt = 0; mt < 4; ++mt) {
        const int kg = 2*mt + (g >> 1);
        #pragma unroll
        for (int ms = 0; ms < 2; ++ms) {
            float v0 = fmaxf(d1[ms][mt][0], 0.f);
            float v1 = fmaxf(d1[ms][mt][1], 0.f);
            float v2 = fmaxf(d1[ms][mt][2], 0.f);
            float v3 = fmaxf(d1[ms][mt][3], 0.f);
            uint32_t* wp = reinterpret_cast<uint32_t*>(
                &pool[wave*2048 + ms*1024 + (kg*16 + q)*8 + 4*(g & 1)]);
            wp[0] = pack2(v0, v1);
            wp[1] = pack2(v2, v3);
        }
    }

    bf16x8 af[2][2];
    #pragma unroll
    for (int ms = 0; ms < 2; ++ms)
        #pragma unroll
        for (int kh = 0; kh < 2; ++kh)
            af[ms][kh] = *reinterpret_cast<const bf16x8*>(
                &pool[wave*2048 + ms*1024 + ((kh*4 + g)*16 + q)*8]);

    // 8-deep named-slot prefetch pipeline (slot = tile mod 8)
    bf16x8 P0a,P0b,P1a,P1b,P2a,P2b,P3a,P3b,P4a,P4b,P5a,P5b,P6a,P6b,P7a,P7b;
    float  Pb0,Pb1,Pb2,Pb3,Pb4,Pb5,Pb6,Pb7;
    auto load_slot = [&](int t, bf16x8& b0, bf16x8& b1, float& bb) {
        const ushort* p = W2F + (size_t)t * 1024 + lane * 8;
        b0 = *reinterpret_cast<const bf16x8*>(p);
        b1 = *reinterpret_cast<const bf16x8*>(p + 512);
        bb = fc_b2[t * 16 + q];
    };
    load_slot(0, P0a, P0b, Pb0);
    load_slot(1, P1a, P1b, Pb1);
    load_slot(2, P2a, P2b, Pb2);
    load_slot(3, P3a, P3b, Pb3);
    load_slot(4, P4a, P4b, Pb4);
    load_slot(5, P5a, P5b, Pb5);
    load_slot(6, P6a, P6b, Pb6);
    load_slot(7, P7a, P7b, Pb7);

    __syncthreads();

    const int ebase = wave*32 + 4*g;
    f32x4 s0v[2];
    s0v[0] = *reinterpret_cast<const f32x4*>(&shS[0][ebase]);
    s0v[1] = *reinterpret_cast<const f32x4*>(&shS[0][ebase + 16]);

    float o0[2][2][4];
    float ttv[2][4];
    float o1v[2][4][3];
    #pragma unroll
    for (int ms = 0; ms < 2; ++ms) {
        #pragma unroll
        for (int r = 0; r < 4; ++r) {
            o0[ms][0][r] = 0.f; o0[ms][1][r] = 0.f; ttv[ms][r] = 0.f;
            o1v[ms][r][0] = 0.f; o1v[ms][r][1] = 0.f; o1v[ms][r][2] = 0.f;
        }
    }

    auto mfma2 = [&](const bf16x8& b0, const bf16x8& b1, float b2v, f32x4* accv) {
        #pragma unroll
        for (int ms = 0; ms < 2; ++ms) {
            f32x4 a = (f32x4){b2v, b2v, b2v, b2v};
            a = __builtin_amdgcn_mfma_f32_16x16x32_bf16(af[ms][0], b0, a, 0, 0, 0);
            a = __builtin_amdgcn_mfma_f32_16x16x32_bf16(af[ms][1], b1, a, 0, 0, 0);
            accv[ms] = a;
        }
    };

    const int qh = q >> 3;

    // consume slot I (tile), refill with tile TN, run epilogue
    #define CONS(I, TN, ...) do { f32x4 w2[2]; mfma2(P##I##a, P##I##b, Pb##I, w2); \
        load_slot(TN, P##I##a, P##I##b, Pb##I); __VA_ARGS__ } while (0)
    #define CONSF(I, ...) do { f32x4 w2[2]; mfma2(P##I##a, P##I##b, Pb##I, w2); \
        __VA_ARGS__ } while (0)

    #define EPI_R1(VC, C0, C1) { _Pragma("unroll") for (int r = 0; r < 4; ++r) { \
        o0[0][VC][r] = fmaf(s0v[0][r]*C0[r], w2[0][r], o0[0][VC][r]); \
        o0[1][VC][r] = fmaf(s0v[1][r]*C1[r], w2[1][r], o0[1][VC][r]); } }
    #define EPI_R2(U) { _Pragma("unroll") for (int ms = 0; ms < 2; ++ms) { \
        f32x4 cfv = ld_cf4(&cfh[U][ebase + ms*16]); \
        _Pragma("unroll") for (int r = 0; r < 4; ++r) \
            ttv[ms][r] = fmaf(cfv[r], w2[ms][r], ttv[ms][r]); } }
    #define EPI_R3(U) { _Pragma("unroll") for (int ms = 0; ms < 2; ++ms) \
        _Pragma("unroll") for (int m = 0; m < 3; ++m) { \
            f32x4 cfv = ld_cf4(&cfh[32 + (U)*3 + m][ebase + ms*16]); \
            _Pragma("unroll") for (int r = 0; r < 4; ++r) \
                o1v[ms][r][m] = fmaf(cfv[r], w2[ms][r], o1v[ms][r][m]); } }
    #define EPI_R4(VC, C0, C1) { _Pragma("unroll") for (int r = 0; r < 4; ++r) { \
        o0[0][VC][r] = fmaf(C0[r], w2[0][r], o0[0][VC][r]); \
        o0[1][VC][r] = fmaf(C1[r], w2[1][r], o0[1][VC][r]); } }

    // ---- region 1: tiles 0..63, chunks of 8, coef s0*x0[u] ------------------
    #pragma unroll 1
    for (int c = 0; c < 8; ++c) {
        const int t8 = 8*c;
        const int u0 = 4*c;
        {
            f32x4 a0 = ld_cf4(&cfh[u0][ebase]),     a1 = ld_cf4(&cfh[u0][ebase + 16]);
            CONS(0, t8 + 8,  EPI_R1(0, a0, a1));
            CONS(1, t8 + 9,  EPI_R1(1, a0, a1));
        }
        {
            f32x4 b0 = ld_cf4(&cfh[u0+1][ebase]),   b1 = ld_cf4(&cfh[u0+1][ebase + 16]);
            CONS(2, t8 + 10, EPI_R1(0, b0, b1));
            CONS(3, t8 + 11, EPI_R1(1, b0, b1));
        }
        {
            f32x4 c0 = ld_cf4(&cfh[u0+2][ebase]),   c1 = ld_cf4(&cfh[u0+2][ebase + 16]);
            CONS(4, t8 + 12, EPI_R1(0, c0, c1));
            CONS(5, t8 + 13, EPI_R1(1, c0, c1));
        }
        {
            f32x4 d0 = ld_cf4(&cfh[u0+3][ebase]),   d1_ = ld_cf4(&cfh[u0+3][ebase + 16]);
            CONS(6, t8 + 14, EPI_R1(0, d0, d1_));
            CONS(7, t8 + 15, EPI_R1(1, d0, d1_));
        }
    }

    // ---- region 2: tiles 64..79, u = 2*(t-64)+qh, coef x0[u] ----------------
    #pragma unroll 1
    for (int d = 0; d < 2; ++d) {
        const int t8 = 64 + 8*d;
        const int ub = 16*d + qh;
        CONS(0, t8 + 8,  EPI_R2(ub));
        CONS(1, t8 + 9,  EPI_R2(ub + 2));
        CONS(2, t8 + 10, EPI_R2(ub + 4));
        CONS(3, t8 + 11, EPI_R2(ub + 6));
        CONS(4, t8 + 12, EPI_R2(ub + 8));
        CONS(5, t8 + 13, EPI_R2(ub + 10));
        CONS(6, t8 + 14, EPI_R2(ub + 12));
        CONS(7, t8 + 15, EPI_R2(ub + 14));
    }

    // ---- region 3: tiles 80..83 (slots 0..3), coef s0*x1[u][m] --------------
    CONS(0, 88, EPI_R3(qh));
    CONS(1, 89, EPI_R3(2 + qh));
    CONS(2, 90, EPI_R3(4 + qh));
    CONS(3, 91, EPI_R3(6 + qh));

    // ---- region 4: tiles 84..99, coef y1[u4] --------------------------------
    {   // tiles 84..87 (slots 4..7), u4 = 0,0,1,1
        f32x4 e00 = ld_cf4(&cfh[56][ebase]),    e01 = ld_cf4(&cfh[56][ebase + 16]);
        f32x4 e10 = ld_cf4(&cfh[57][ebase]),    e11 = ld_cf4(&cfh[57][ebase + 16]);
        CONS(4, 92, EPI_R4(0, e00, e01));
        CONS(5, 93, EPI_R4(1, e00, e01));
        CONS(6, 94, EPI_R4(0, e10, e11));
        CONS(7, 95, EPI_R4(1, e10, e11));
    }
    {   // tiles 88..95 (slots 0..7), u4 = 2..5; refills clamp to 99
        f32x4 f00 = ld_cf4(&cfh[58][ebase]),    f01 = ld_cf4(&cfh[58][ebase + 16]);
        CONS(0, 96, EPI_R4(0, f00, f01));
        CONS(1, 97, EPI_R4(1, f00, f01));
        f32x4 f10 = ld_cf4(&cfh[59][ebase]),    f11 = ld_cf4(&cfh[59][ebase + 16]);
        CONS(2, 98, EPI_R4(0, f10, f11));
        CONS(3, 99, EPI_R4(1, f10, f11));
        f32x4 f20 = ld_cf4(&cfh[60][ebase]),    f21 = ld_cf4(&cfh[60][ebase + 16]);
        CONSF(4, EPI_R4(0, f20, f21));
        CONSF(5, EPI_R4(1, f20, f21));
        f32x4 f30 = ld_cf4(&cfh[61][ebase]),    f31 = ld_cf4(&cfh[61][ebase + 16]);
        CONSF(6, EPI_R4(0, f30, f31));
        CONSF(7, EPI_R4(1, f30, f31));
    }
    {   // tiles 96..99 (slots 0..3), u4 = 6,6,7,7 — final
        f32x4 g00 = ld_cf4(&cfh[62][ebase]),    g01 = ld_cf4(&cfh[62][ebase + 16]);
        CONSF(0, EPI_R4(0, g00, g01));
        CONSF(1, EPI_R4(1, g00, g01));
        f32x4 g10 = ld_cf4(&cfh[63][ebase]),    g11 = ld_cf4(&cfh[63][ebase + 16]);
        CONSF(2, EPI_R4(0, g10, g11));
        CONSF(3, EPI_R4(1, g10, g11));
    }

    #undef CONS
    #undef CONSF
    #undef EPI_R1
    #undef EPI_R2
    #undef EPI_R3
    #undef EPI_R4

    // ---- finish: reduce u-halves (lane ^ 8), coalesced per-edge stores ------
    #pragma unroll
    for (int ms = 0; ms < 2; ++ms)
        #pragma unroll
        for (int r = 0; r < 4; ++r) {
            ttv[ms][r] += __shfl_xor(ttv[ms][r], 8, 64);
            #pragma unroll
            for (int m = 0; m < 3; ++m)
                o1v[ms][r][m] += __shfl_xor(o1v[ms][r][m], 8, 64);
        }

    #pragma unroll
    for (int ms = 0; ms < 2; ++ms) {
        const int eb = ebase + ms*16;
        const f32x4 s1x = *reinterpret_cast<const f32x4*>(&shS[1][eb]);
        const f32x4 s1y = *reinterpret_cast<const f32x4*>(&shS[2][eb]);
        const f32x4 s1z = *reinterpret_cast<const f32x4*>(&shS[3][eb]);
        #pragma unroll
        for (int r = 0; r < 4; ++r) {
            float* tp = tpbuf + (size_t)(E0 + eb + r) * IND;
            tp[q]      = PATH_NORM_C * o0[ms][0][r];
            tp[16 + q] = PATH_NORM_C * o0[ms][1][r];
            if ((q & 8) == 0) {
                const int v = q & 7;
                tp[32 + 3*v + 0] = PATH_NORM_C * (o1v[ms][r][0] + s1x[r]*ttv[ms][r]);
                tp[32 + 3*v + 1] = PATH_NORM_C * (o1v[ms][r][1] + s1y[r]*ttv[ms][r]);
                tp[32 + 3*v + 2] = PATH_NORM_C * (o1v[ms][r][2] + s1z[r]*ttv[ms][r]);
            }
        }
    }
}

// ---- gather: one wave per node, mean + residual ---------------------------
__global__ __launch_bounds__(256) void gather_kernel(
    const float* __restrict__ tpbuf, const int* __restrict__ cursor,
    const int* __restrict__ elist, const float* __restrict__ node_attr,
    float* __restrict__ out)
{
    const int node = blockIdx.x * 4 + (threadIdx.x >> 6);
    const int j = threadIdx.x & 63;
    if (node >= NN) return;
    const int degt = cursor[node];
    const int deg = (degt < DCAP) ? degt : DCAP;
    float sum = 0.f;
    #pragma unroll 4
    for (int i = 0; i < deg; ++i) {
        const int e = elist[node * DCAP + i];
        if (j < 56) sum += tpbuf[(size_t)e * IND + j];
    }
    if (j < 56) {
        const float c = (degt > 0) ? (float)degt : 1.f;
        out[node * IND + j] = sum / c + node_attr[node * IND + j];
    }
}

// ================= fallback path (atomics, small ws) ========================
__global__ __launch_bounds__(256, 3) void edge_kernel_fb(
    const float* __restrict__ node_attr, const float* __restrict__ edge_attr,
    const float* __restrict__ edge_sh, const float* __restrict__ fc_b1,
    const float* __restrict__ fc_b2, const int* __restrict__ edge_index,
    const ushort* __restrict__ W1T, const ushort* __restrict__ W2F,
    float* __restrict__ acc, float* __restrict__ cnt)
{
    __shared__ ushort cfh[64][EPB];
    __shared__ float  shS[4][EPB];
    __shared__ int    src_lds[EPB];
    __shared__ __attribute__((aligned(16))) ushort pool[8192];

    const int tid  = threadIdx.x;
    const int wave = tid >> 6;
    const int lane = tid & 63;
    const int g    = lane >> 4;
    const int q    = lane & 15;
    const int E0   = blockIdx.x * EPB;

    if (tid < EPB) {
        const int e    = tid;
        const int srcn = edge_index[E0 + e];
        const int dstn = edge_index[NE + E0 + e];
        src_lds[e] = srcn;
        const float4 sh = reinterpret_cast<const float4*>(edge_sh)[E0 + e];
        const float4* xp = reinterpret_cast<const float4*>(node_attr + (size_t)dstn * IND);
        float xr[56];
        #pragma unroll
        for (int i = 0; i < 14; ++i) {
            float4 v = xp[i];
            xr[4*i] = v.x; xr[4*i+1] = v.y; xr[4*i+2] = v.z; xr[4*i+3] = v.w;
        }
        #pragma unroll
        for (int u = 0; u < 32; ++u) cfh[u][e] = (ushort)f2bf(xr[u]);
        #pragma unroll
        for (int u = 0; u < 8; ++u) {
            cfh[32 + 3*u + 0][e] = (ushort)f2bf(sh.x * xr[32 + 3*u + 0]);
            cfh[32 + 3*u + 1][e] = (ushort)f2bf(sh.x * xr[32 + 3*u + 1]);
            cfh[32 + 3*u + 2][e] = (ushort)f2bf(sh.x * xr[32 + 3*u + 2]);
            cfh[56 + u][e] = (ushort)f2bf(
                CG_C * (xr[32+3*u]*sh.y + xr[32+3*u+1]*sh.z + xr[32+3*u+2]*sh.w));
        }
        shS[0][e] = sh.x;
        shS[1][e] = sh.y;  shS[2][e] = sh.z;  shS[3][e] = sh.w;
    }

    f32x4 d1[2][4];
    #pragma unroll
    for (int mt = 0; mt < 4; ++mt) {
        const float4 b1v = *reinterpret_cast<const float4*>(fc_b1 + mt*16 + 4*g);
        #pragma unroll
        for (int ms = 0; ms < 2; ++ms)
            d1[ms][mt] = (f32x4){b1v.x, b1v.y, b1v.z, b1v.w};
    }
    #pragma unroll
    for (int kh = 0; kh < 2; ++kh) {
        bf16x8 bfr[2];
        #pragma unroll
        for (int ms = 0; ms < 2; ++ms) {
            const int e = E0 + wave*32 + ms*16 + q;
            const float* ap = edge_attr + (size_t)e * 64 + kh*32 + g*8;
            float4 f0 = *reinterpret_cast<const float4*>(ap);
            float4 f1 = *reinterpret_cast<const float4*>(ap + 4);
            union { uint32_t u[4]; bf16x8 v; } cv;
            cv.u[0] = pack2(f0.x, f0.y); cv.u[1] = pack2(f0.z, f0.w);
            cv.u[2] = pack2(f1.x, f1.y); cv.u[3] = pack2(f1.z, f1.w);
            bfr[ms] = cv.v;
        }
        #pragma unroll
        for (int mt = 0; mt < 4; ++mt) {
            bf16x8 afr = *reinterpret_cast<const bf16x8*>(W1T + (mt*16 + q)*64 + kh*32 + g*8);
            #pragma unroll
            for (int ms = 0; ms < 2; ++ms)
                d1[ms][mt] = __builtin_amdgcn_mfma_f32_16x16x32_bf16(afr, bfr[ms], d1[ms][mt], 0, 0, 0);
        }
    }
    #pragma unroll
    for (int mt = 0; mt < 4; ++mt) {
        const int kg = 2*mt + (g >> 1);
        #pragma unroll
        for (int ms = 0; ms < 2; ++ms) {
            float v0 = fmaxf(d1[ms][mt][0], 0.f);
            float v1 = fmaxf(d1[ms][mt][1], 0.f);
            float v2 = fmaxf(d1[ms][mt][2], 0.f);
            float v3 = fmaxf(d1[ms][mt][3], 0.f);
            uint32_t* wp = reinterpret_cast<uint32_t*>(
                &pool[wave*2048 + ms*1024 + (kg*16 + q)*8 + 4*(g & 1)]);
            wp[0] = pack2(v0, v1);
            wp[1] = pack2(v2, v3);
        }
    }
    bf16x8 af[2][2];
    #pragma unroll
    for (int ms = 0; ms < 2; ++ms)
        #pragma unroll
        for (int kh = 0; kh < 2; ++kh)
            af[ms][kh] = *reinterpret_cast<const bf16x8*>(
                &pool[wave*2048 + ms*1024 + ((kh*4 + g)*16 + q)*8]);

    bf16x8 A0, A1, B0, B1, C0, C1, D0, D1;
    float  Ab, Bb, Cb, Db;
    auto load_slot = [&](int t, bf16x8& b0, bf16x8& b1, float& bb) {
        const ushort* p = W2F + (size_t)t * 1024 + lane * 8;
        b0 = *reinterpret_cast<const bf16x8*>(p);
        b1 = *reinterpret_cast<const bf16x8*>(p + 512);
        bb = fc_b2[t * 16 + q];
    };
    load_slot(0, A0, A1, Ab);
    load_slot(1, B0, B1, Bb);
    load_slot(2, C0, C1, Cb);
    load_slot(3, D0, D1, Db);
    __syncthreads();

    const int ebase = wave*32 + 4*g;
    f32x4 s0v[2];
    s0v[0] = *reinterpret_cast<const f32x4*>(&shS[0][ebase]);
    s0v[1] = *reinterpret_cast<const f32x4*>(&shS[0][ebase + 16]);
    float o0[2][2][4];
    float ttv[2][4];
    float o1v[2][4][3];
    #pragma unroll
    for (int ms = 0; ms < 2; ++ms)
        #pragma unroll
        for (int r = 0; r < 4; ++r) {
            o0[ms][0][r] = 0.f; o0[ms][1][r] = 0.f; ttv[ms][r] = 0.f;
            o1v[ms][r][0] = 0.f; o1v[ms][r][1] = 0.f; o1v[ms][r][2] = 0.f;
        }
    auto mfma2 = [&](const bf16x8& b0, const bf16x8& b1, float b2v, f32x4* accv) {
        #pragma unroll
        for (int ms = 0; ms < 2; ++ms) {
            f32x4 a = (f32x4){b2v, b2v, b2v, b2v};
            a = __builtin_amdgcn_mfma_f32_16x16x32_bf16(af[ms][0], b0, a, 0, 0, 0);
            a = __builtin_amdgcn_mfma_f32_16x16x32_bf16(af[ms][1], b1, a, 0, 0, 0);
            accv[ms] = a;
        }
    };
    const int qh = q >> 3;
    #pragma unroll 1
    for (int c = 0; c < 16; ++c) {
        const int t4 = 4*c;
        const int u0 = 2*c, u1 = 2*c + 1;
        f32x4 c00 = ld_cf4(&cfh[u0][ebase]);
        f32x4 c01 = ld_cf4(&cfh[u0][ebase + 16]);
        f32x4 c10 = ld_cf4(&cfh[u1][ebase]);
        f32x4 c11 = ld_cf4(&cfh[u1][ebase + 16]);
        f32x4 w2[2];
        mfma2(A0, A1, Ab, w2);  load_slot(t4 + 4, A0, A1, Ab);
        #pragma unroll
        for (int r = 0; r < 4; ++r) {
            o0[0][0][r] = fmaf(s0v[0][r]*c00[r], w2[0][r], o0[0][0][r]);
            o0[1][0][r] = fmaf(s0v[1][r]*c01[r], w2[1][r], o0[1][0][r]);
        }
        mfma2(B0, B1, Bb, w2);  load_slot(t4 + 5, B0, B1, Bb);
        #pragma unroll
        for (int r = 0; r < 4; ++r) {
            o0[0][1][r] = fmaf(s0v[0][r]*c00[r], w2[0][r], o0[0][1][r]);
            o0[1][1][r] = fmaf(s0v[1][r]*c01[r], w2[1][r], o0[1][1][r]);
        }
        mfma2(C0, C1, Cb, w2);  load_slot(t4 + 6, C0, C1, Cb);
        #pragma unroll
        for (int r = 0; r < 4; ++r) {
            o0[0][0][r] = fmaf(s0v[0][r]*c10[r], w2[0][r], o0[0][0][r]);
            o0[1][0][r] = fmaf(s0v[1][r]*c11[r], w2[1][r], o0[1][0][r]);
        }
        mfma2(D0, D1, Db, w2);  load_slot(t4 + 7, D0, D1, Db);
        #pragma unroll
        for (int r = 0; r < 4; ++r) {
            o0[0][1][r] = fmaf(s0v[0][r]*c10[r], w2[0][r], o0[0][1][r]);
            o0[1][1][r] = fmaf(s0v[1][r]*c11[r], w2[1][r], o0[1][1][r]);
        }
    }
    #pragma unroll 1
    for (int d = 0; d < 4; ++d) {
        const int t4 = 64 + 4*d;
        f32x4 w2[2];
        mfma2(A0, A1, Ab, w2);  load_slot(t4 + 4, A0, A1, Ab);
        {
            const int u = 8*d + qh;
            #pragma unroll
            for (int ms = 0; ms < 2; ++ms) {
                f32x4 cfv = ld_cf4(&cfh[u][ebase + ms*16]);
                #pragma unroll
                for (int r = 0; r < 4; ++r) ttv[ms][r] = fmaf(cfv[r], w2[ms][r], ttv[ms][r]);
            }
        }
        mfma2(B0, B1, Bb, w2);  load_slot(t4 + 5, B0, B1, Bb);
        {
            const int u = 8*d + 2 + qh;
            #pragma unroll
            for (int ms = 0; ms < 2; ++ms) {
                f32x4 cfv = ld_cf4(&cfh[u][ebase + ms*16]);
                #pragma unroll
                for (int r = 0; r < 4; ++r) ttv[ms][r] = fmaf(cfv[r], w2[ms][r], ttv[ms][r]);
            }
        }
        mfma2(C0, C1, Cb, w2);  load_slot(t4 + 6, C0, C1, Cb);
        {
            const int u = 8*d + 4 + qh;
            #pragma unroll
            for (int ms = 0; ms < 2; ++ms) {
                f32x4 cfv = ld_cf4(&cfh[u][ebase + ms*16]);
                #pragma unroll
                for (int r = 0; r < 4; ++r) ttv[ms][r] = fmaf(cfv[r], w2[ms][r], ttv[ms][r]);
            }
        }
        mfma2(D0, D1, Db, w2);  load_slot(t4 + 7, D0, D1, Db);
        {
            const int u = 8*d + 6 + qh;
            #pragma unroll
            for (int ms = 0; ms < 2; ++ms) {
                f32x4 cfv = ld_cf4(&cfh[u][ebase + ms*16]);
                #pragma unroll
                for (int r = 0; r < 4; ++r) ttv[ms][r] = fmaf(cfv[r], w2[ms][r], ttv[ms][r]);
            }
        }
    }
    {
        f32x4 w2[2];
        #define R3_BODY(TC)                                                         \
            {                                                                       \
                const int u = 2*(TC) + qh;                                          \
                _Pragma("unroll")                                                   \
                for (int ms = 0; ms < 2; ++ms)                                      \
                    _Pragma("unroll")                                               \
                    for (int m = 0; m < 3; ++m) {                                   \
                        f32x4 cfv = ld_cf4(&cfh[32 + u*3 + m][ebase + ms*16]);      \
                        _Pragma("unroll")                                           \
                        for (int r = 0; r < 4; ++r)                                 \
                            o1v[ms][r][m] = fmaf(cfv[r], w2[ms][r], o1v[ms][r][m]); \
                    }                                                               \
            }
        mfma2(A0, A1, Ab, w2);  load_slot(84, A0, A1, Ab);  R3_BODY(0)
        mfma2(B0, B1, Bb, w2);  load_slot(85, B0, B1, Bb);  R3_BODY(1)
        mfma2(C0, C1, Cb, w2);  load_slot(86, C0, C1, Cb);  R3_BODY(2)
        mfma2(D0, D1, Db, w2);  load_slot(87, D0, D1, Db);  R3_BODY(3)
        #undef R3_BODY
    }
    #pragma unroll 1
    for (int d = 0; d < 4; ++d) {
        const int t4 = 84 + 4*d;
        const int u0 = 2*d, u1 = 2*d + 1;
        f32x4 c00 = ld_cf4(&cfh[56 + u0][ebase]);
        f32x4 c01 = ld_cf4(&cfh[56 + u0][ebase + 16]);
        f32x4 c10 = ld_cf4(&cfh[56 + u1][ebase]);
        f32x4 c11 = ld_cf4(&cfh[56 + u1][ebase + 16]);
        f32x4 w2[2];
        int tn;
        mfma2(A0, A1, Ab, w2);  tn = t4 + 4; load_slot(tn < 100 ? tn : 99, A0, A1, Ab);
        #pragma unroll
        for (int r = 0; r < 4; ++r) {
            o0[0][0][r] = fmaf(c00[r], w2[0][r], o0[0][0][r]);
            o0[1][0][r] = fmaf(c01[r], w2[1][r], o0[1][0][r]);
        }
        mfma2(B0, B1, Bb, w2);  tn = t4 + 5; load_slot(tn < 100 ? tn : 99, B0, B1, Bb);
        #pragma unroll
        for (int r = 0; r < 4; ++r) {
            o0[0][1][r] = fmaf(c00[r], w2[0][r], o0[0][1][r]);
            o0[1][1][r] = fmaf(c01[r], w2[1][r], o0[1][1][r]);
        }
        mfma2(C0, C1, Cb, w2);  tn = t4 + 6; load_slot(tn < 100 ? tn : 99, C0, C1, Cb);
        #pragma unroll
        for (int r = 0; r < 4; ++r) {
            o0[0][0][r] = fmaf(c10[r], w2[0][r], o0[0][0][r]);
            o0[1][0][r] = fmaf(c11[r], w2[1][r], o0[1][0][r]);
        }
        mfma2(D0, D1, Db, w2);  tn = t4 + 7; load_slot(tn < 100 ? tn : 99, D0, D1, Db);
        #pragma unroll
        for (int r = 0; r < 4; ++r) {
            o0[0][1][r] = fmaf(c10[r], w2[0][r], o0[0][1][r]);
            o0[1][1][r] = fmaf(c11[r], w2[1][r], o0[1][1][r]);
        }
    }
    #pragma unroll
    for (int ms = 0; ms < 2; ++ms)
        #pragma unroll
        for (int r = 0; r < 4; ++r) {
            ttv[ms][r] += __shfl_xor(ttv[ms][r], 8, 64);
            #pragma unroll
            for (int m = 0; m < 3; ++m)
                o1v[ms][r][m] += __shfl_xor(o1v[ms][r][m], 8, 64);
        }
    #pragma unroll
    for (int ms = 0; ms < 2; ++ms) {
        const int eb = ebase + ms*16;
        const int4 srcv = *reinterpret_cast<const int4*>(&src_lds[eb]);
        const f32x4 s1x = *reinterpret_cast<const f32x4*>(&shS[1][eb]);
        const f32x4 s1y = *reinterpret_cast<const f32x4*>(&shS[2][eb]);
        const f32x4 s1z = *reinterpret_cast<const f32x4*>(&shS[3][eb]);
        #pragma unroll
        for (int r = 0; r < 4; ++r) {
            const int node = (r == 0) ? srcv.x : (r == 1) ? srcv.y : (r == 2) ? srcv.z : srcv.w;
            float* ap = acc + (size_t)node * IND;
            atomicAdd(ap + q,      PATH_NORM_C * o0[ms][0][r]);
            atomicAdd(ap + 16 + q, PATH_NORM_C * o0[ms][1][r]);
            if ((q & 8) == 0) {
                const int v = q & 7;
                atomicAdd(ap + 32 + 3*v + 0, PATH_NORM_C * (o1v[ms][r][0] + s1x[r]*ttv[ms][r]));
                atomicAdd(ap + 32 + 3*v + 1, PATH_NORM_C * (o1v[ms][r][1] + s1y[r]*ttv[ms][r]));
                atomicAdd(ap + 32 + 3*v + 2, PATH_NORM_C * (o1v[ms][r][2] + s1z[r]*ttv[ms][r]));
            }
        }
    }
    if (lane < 32) atomicAdd(cnt + src_lds[wave*32 + lane], 1.0f);
}

__global__ __launch_bounds__(256) void finalize_kernel(
    const float* __restrict__ acc, const float* __restrict__ cnt,
    const float* __restrict__ node_attr, float* __restrict__ out)
{
    const int i = blockIdx.x * 256 + threadIdx.x;
    if (i >= NN * IND) return;
    const int n = i / IND;
    const float c = fmaxf(cnt[n], 1.0f);
    out[i] = acc[i] / c + node_attr[i];
}

extern "C" void kernel_launch(void* const* d_in, const int* in_sizes, int n_in,
                              void* d_out, int out_size, void* d_ws, size_t ws_size,
                              hipStream_t stream) {
    const float* node_attr = (const float*)d_in[0];
    const float* edge_attr = (const float*)d_in[1];
    const float* edge_sh   = (const float*)d_in[2];
    const float* fc_w1     = (const float*)d_in[3];
    const float* fc_b1     = (const float*)d_in[4];
    const float* fc_w2     = (const float*)d_in[5];
    const float* fc_b2     = (const float*)d_in[6];
    const int*   edge_index = (const int*)d_in[7];

    char* ws = (char*)d_ws;
    // main-path layout
    int*    cursor = (int*)(ws + 0);                  // 40,000
    int*    elist  = (int*)(ws + 40000);              // 2,560,000 -> ends 2,600,000
    ushort* W1T    = (ushort*)(ws + 2600000);         // 8,192
    ushort* W2F    = (ushort*)(ws + 2608192);         // 204,800 -> ends 2,812,992
    float*  tpbuf  = (float*)(ws + 2812992);          // 35,840,000 -> 38,652,992
    const size_t WS_NEEDED = 2812992ull + (size_t)NE * IND * 4;

    if (ws_size >= WS_NEEDED) {
        hipMemsetAsync(cursor, 0, 40000, stream);
        prep_kernel<<<(64*64 + 100*1024 + NE + 255) / 256, 256, 0, stream>>>(
            fc_w1, fc_w2, edge_index, W1T, W2F, cursor, elist, 1);
        edge_kernel<<<NBLK, 256, 0, stream>>>(
            node_attr, edge_attr, edge_sh, fc_b1, fc_b2, edge_index, W1T, W2F, tpbuf);
        gather_kernel<<<(NN + 3) / 4, 256, 0, stream>>>(
            tpbuf, cursor, elist, node_attr, (float*)d_out);
    } else {
        // fallback layout: acc/cnt at ws+0, weights after
        float*  acc  = (float*)ws;                    // 2,240,000
        float*  cnt  = (float*)(ws + 2240000);        // 40,000 -> 2,280,000
        ushort* W1Tf = (ushort*)(ws + 2280000);
        ushort* W2Ff = (ushort*)(ws + 2288192);
        hipMemsetAsync(ws, 0, 2280000, stream);
        prep_kernel<<<(64*64 + 100*1024 + NE + 255) / 256, 256, 0, stream>>>(
            fc_w1, fc_w2, edge_index, W1Tf, W2Ff, (int*)W1Tf, (int*)W1Tf, 0);
        edge_kernel_fb<<<NBLK, 256, 0, stream>>>(
            node_attr, edge_attr, edge_sh, fc_b1, fc_b2, edge_index, W1Tf, W2Ff, acc, cnt);
        finalize_kernel<<<(NN * IND + 255) / 256, 256, 0, stream>>>(
            acc, cnt, node_attr, (float*)d_out);
    }
}

// Round 15
// 113.878 us; speedup vs baseline: 1.1323x; 1.1175x over previous
//
#include <hip/hip_runtime.h>

#define NN 10000
#define NE 160000
#define IND 56          // 32 + 3*8
#define WN 1600
#define EPB 128         // edges per block (4 waves x 32)
#define NBLK (NE / EPB) // 1250
#define DCAP 64         // max edges per source node bucket

typedef __attribute__((ext_vector_type(8))) short bf16x8;
typedef __attribute__((ext_vector_type(4))) float f32x4;

static constexpr float PATH_NORM_C = 0.15811388300841897f; // 1/sqrt(40)
static constexpr float CG_C        = 0.57735026918962576f; // 1/sqrt(3)

__device__ __forceinline__ uint32_t f2bf(float f) {
    uint32_t x = __float_as_uint(f);
    return (x + 0x7fffu + ((x >> 16) & 1u)) >> 16;   // RNE
}
__device__ __forceinline__ uint32_t pack2(float a, float b) {
    return f2bf(a) | (f2bf(b) << 16);
}
__device__ __forceinline__ f32x4 ld_cf4(const ushort* p) {
    uint2 w = *reinterpret_cast<const uint2*>(p);
    f32x4 v;
    v[0] = __uint_as_float(w.x << 16);
    v[1] = __uint_as_float(w.x & 0xffff0000u);
    v[2] = __uint_as_float(w.y << 16);
    v[3] = __uint_as_float(w.y & 0xffff0000u);
    return v;
}

// ---- pre-pass: W1T + W2F (fragment order) + bucket fill --------------------
__global__ __launch_bounds__(256) void prep_kernel(
    const float* __restrict__ fc_w1, const float* __restrict__ fc_w2,
    const int* __restrict__ edge_index,
    ushort* __restrict__ W1T, ushort* __restrict__ W2F,
    int* __restrict__ cursor, int* __restrict__ elist, int do_fill)
{
    int i = blockIdx.x * 256 + threadIdx.x;
    if (i < 64 * 64) {
        int k = i >> 6, j = i & 63;
        W1T[k * 64 + j] = (ushort)f2bf(fc_w1[j * 64 + k]);
    }
    int i2 = i - 64 * 64;
    if (i2 >= 0 && i2 < 100 * 1024) {
        int t  = i2 >> 10, r = i2 & 1023;
        int kh = r >> 9,  rr = r & 511;
        int l  = rr >> 3, ii = rr & 7;
        int j  = t * 16 + (l & 15);
        int k  = kh * 32 + ((l >> 4) << 3) + ii;
        W2F[i2] = (ushort)f2bf(fc_w2[k * WN + j]);
    }
    int i3 = i2 - 100 * 1024;
    if (i3 >= 0 && i3 < NE && do_fill) {
        int s = edge_index[i3];
        int pos = atomicAdd(&cursor[s], 1);
        if (pos < DCAP) elist[s * DCAP + pos] = i3;
    }
}

// ---- GEMM1 kernel (R7-proven): h = relu(edge_attr @ W1 + b1), A-frag order -
__global__ __launch_bounds__(256) void h_kernel(
    const float* __restrict__ edge_attr,
    const float* __restrict__ fc_b1,
    const ushort* __restrict__ W1T,
    ushort* __restrict__ Hbuf)
{
    const int tid  = threadIdx.x;
    const int wave = tid >> 6;
    const int lane = tid & 63;
    const int g    = lane >> 4;
    const int q    = lane & 15;
    const int E0   = blockIdx.x * EPB;

    f32x4 d1[2][4];
    #pragma unroll
    for (int mt = 0; mt < 4; ++mt) {
        const float4 b1v = *reinterpret_cast<const float4*>(fc_b1 + mt*16 + 4*g);
        #pragma unroll
        for (int ms = 0; ms < 2; ++ms)
            d1[ms][mt] = (f32x4){b1v.x, b1v.y, b1v.z, b1v.w};
    }

    #pragma unroll
    for (int kh = 0; kh < 2; ++kh) {
        bf16x8 bfr[2];
        #pragma unroll
        for (int ms = 0; ms < 2; ++ms) {
            const int e = E0 + wave*32 + ms*16 + q;
            const float* ap = edge_attr + (size_t)e * 64 + kh*32 + g*8;
            float4 f0 = *reinterpret_cast<const float4*>(ap);
            float4 f1 = *reinterpret_cast<const float4*>(ap + 4);
            union { uint32_t u[4]; bf16x8 v; } cv;
            cv.u[0] = pack2(f0.x, f0.y); cv.u[1] = pack2(f0.z, f0.w);
            cv.u[2] = pack2(f1.x, f1.y); cv.u[3] = pack2(f1.z, f1.w);
            bfr[ms] = cv.v;
        }
        #pragma unroll
        for (int mt = 0; mt < 4; ++mt) {
            bf16x8 afr = *reinterpret_cast<const bf16x8*>(W1T + (mt*16 + q)*64 + kh*32 + g*8);
            #pragma unroll
            for (int ms = 0; ms < 2; ++ms)
                d1[ms][mt] = __builtin_amdgcn_mfma_f32_16x16x32_bf16(afr, bfr[ms], d1[ms][mt], 0, 0, 0);
        }
    }
    #pragma unroll
    for (int mt = 0; mt < 4; ++mt) {
        const int kg = 2*mt + (g >> 1);
        #pragma unroll
        for (int ms = 0; ms < 2; ++ms) {
            const int group = blockIdx.x*8 + wave*2 + ms;
            float v0 = fmaxf(d1[ms][mt][0], 0.f);
            float v1 = fmaxf(d1[ms][mt][1], 0.f);
            float v2 = fmaxf(d1[ms][mt][2], 0.f);
            float v3 = fmaxf(d1[ms][mt][3], 0.f);
            uint2 w;
            w.x = pack2(v0, v1);
            w.y = pack2(v2, v3);
            *reinterpret_cast<uint2*>(Hbuf + (size_t)group*1024 + (kg*16 + q)*8 + 4*(g & 1)) = w;
        }
    }
}

// ===== split edge kernel: GEMM2 + TP only, no pool, LDS 18.4KB ==============
__global__ __launch_bounds__(256) void edge_kernel_split(
    const float* __restrict__ node_attr,
    const float* __restrict__ edge_sh,
    const float* __restrict__ fc_b2,
    const int*   __restrict__ edge_index,
    const ushort* __restrict__ W2F,
    const ushort* __restrict__ Hbuf,
    float* __restrict__ tpbuf)
{
    __shared__ ushort cfh[64][EPB];                               // 16 KB
    __shared__ float  shS[4][EPB];                                //  2 KB

    const int tid  = threadIdx.x;
    const int wave = tid >> 6;
    const int lane = tid & 63;
    const int g    = lane >> 4;
    const int q    = lane & 15;
    const int E0   = blockIdx.x * EPB;

    // ---------------- preamble: per-edge coefficient table -------------------
    if (tid < EPB) {
        const int e    = tid;
        const int dstn = edge_index[NE + E0 + e];
        const float4 sh = reinterpret_cast<const float4*>(edge_sh)[E0 + e];
        const float4* xp = reinterpret_cast<const float4*>(node_attr + (size_t)dstn * IND);
        float xr[56];
        #pragma unroll
        for (int i = 0; i < 14; ++i) {
            float4 v = xp[i];
            xr[4*i] = v.x; xr[4*i+1] = v.y; xr[4*i+2] = v.z; xr[4*i+3] = v.w;
        }
        #pragma unroll
        for (int u = 0; u < 32; ++u) cfh[u][e] = (ushort)f2bf(xr[u]);
        #pragma unroll
        for (int u = 0; u < 8; ++u) {
            cfh[32 + 3*u + 0][e] = (ushort)f2bf(sh.x * xr[32 + 3*u + 0]);
            cfh[32 + 3*u + 1][e] = (ushort)f2bf(sh.x * xr[32 + 3*u + 1]);
            cfh[32 + 3*u + 2][e] = (ushort)f2bf(sh.x * xr[32 + 3*u + 2]);
            cfh[56 + u][e] = (ushort)f2bf(
                CG_C * (xr[32+3*u]*sh.y + xr[32+3*u+1]*sh.z + xr[32+3*u+2]*sh.w));
        }
        shS[0][e] = sh.x;
        shS[1][e] = sh.y;  shS[2][e] = sh.z;  shS[3][e] = sh.w;
    }

    // A-fragments straight from Hbuf (R7-proven formula; coalesced 16B/lane)
    bf16x8 af[2][2];
    #pragma unroll
    for (int ms = 0; ms < 2; ++ms)
        #pragma unroll
        for (int kh = 0; kh < 2; ++kh)
            af[ms][kh] = *reinterpret_cast<const bf16x8*>(
                Hbuf + (size_t)(blockIdx.x*8 + wave*2 + ms)*1024 + kh*512 + g*128 + q*8);

    // 4-deep named-slot prefetch pipeline for the W2F tile stream
    bf16x8 A0, A1, B0, B1, C0, C1, D0, D1;
    float  Ab, Bb, Cb, Db;
    auto load_slot = [&](int t, bf16x8& b0, bf16x8& b1, float& bb) {
        const ushort* p = W2F + (size_t)t * 1024 + lane * 8;
        b0 = *reinterpret_cast<const bf16x8*>(p);
        b1 = *reinterpret_cast<const bf16x8*>(p + 512);
        bb = fc_b2[t * 16 + q];
    };
    load_slot(0, A0, A1, Ab);
    load_slot(1, B0, B1, Bb);
    load_slot(2, C0, C1, Cb);
    load_slot(3, D0, D1, Db);

    __syncthreads();   // cfh/shS visible

    const int ebase = wave*32 + 4*g;
    f32x4 s0v[2];
    s0v[0] = *reinterpret_cast<const f32x4*>(&shS[0][ebase]);
    s0v[1] = *reinterpret_cast<const f32x4*>(&shS[0][ebase + 16]);

    float o0[2][2][4];
    float ttv[2][4];
    float o1v[2][4][3];
    #pragma unroll
    for (int ms = 0; ms < 2; ++ms) {
        #pragma unroll
        for (int r = 0; r < 4; ++r) {
            o0[ms][0][r] = 0.f; o0[ms][1][r] = 0.f; ttv[ms][r] = 0.f;
            o1v[ms][r][0] = 0.f; o1v[ms][r][1] = 0.f; o1v[ms][r][2] = 0.f;
        }
    }

    auto mfma2 = [&](const bf16x8& b0, const bf16x8& b1, float b2v, f32x4* accv) {
        #pragma unroll
        for (int ms = 0; ms < 2; ++ms) {
            f32x4 a = (f32x4){b2v, b2v, b2v, b2v};
            a = __builtin_amdgcn_mfma_f32_16x16x32_bf16(af[ms][0], b0, a, 0, 0, 0);
            a = __builtin_amdgcn_mfma_f32_16x16x32_bf16(af[ms][1], b1, a, 0, 0, 0);
            accv[ms] = a;
        }
    };

    const int qh = q >> 3;

    // ---- region 1: tiles 0..63 (chunks of 4), coef s0*x0[u], out0 -----------
    #pragma unroll 1
    for (int c = 0; c < 16; ++c) {
        const int t4 = 4*c;
        const int u0 = 2*c, u1 = 2*c + 1;
        f32x4 c00 = ld_cf4(&cfh[u0][ebase]);
        f32x4 c01 = ld_cf4(&cfh[u0][ebase + 16]);
        f32x4 c10 = ld_cf4(&cfh[u1][ebase]);
        f32x4 c11 = ld_cf4(&cfh[u1][ebase + 16]);
        f32x4 w2[2];

        mfma2(A0, A1, Ab, w2);  load_slot(t4 + 4, A0, A1, Ab);
        #pragma unroll
        for (int r = 0; r < 4; ++r) {
            o0[0][0][r] = fmaf(s0v[0][r]*c00[r], w2[0][r], o0[0][0][r]);
            o0[1][0][r] = fmaf(s0v[1][r]*c01[r], w2[1][r], o0[1][0][r]);
        }
        mfma2(B0, B1, Bb, w2);  load_slot(t4 + 5, B0, B1, Bb);
        #pragma unroll
        for (int r = 0; r < 4; ++r) {
            o0[0][1][r] = fmaf(s0v[0][r]*c00[r], w2[0][r], o0[0][1][r]);
            o0[1][1][r] = fmaf(s0v[1][r]*c01[r], w2[1][r], o0[1][1][r]);
        }
        mfma2(C0, C1, Cb, w2);  load_slot(t4 + 6, C0, C1, Cb);
        #pragma unroll
        for (int r = 0; r < 4; ++r) {
            o0[0][0][r] = fmaf(s0v[0][r]*c10[r], w2[0][r], o0[0][0][r]);
            o0[1][0][r] = fmaf(s0v[1][r]*c11[r], w2[1][r], o0[1][0][r]);
        }
        mfma2(D0, D1, Db, w2);  load_slot(t4 + 7, D0, D1, Db);
        #pragma unroll
        for (int r = 0; r < 4; ++r) {
            o0[0][1][r] = fmaf(s0v[0][r]*c10[r], w2[0][r], o0[0][1][r]);
            o0[1][1][r] = fmaf(s0v[1][r]*c11[r], w2[1][r], o0[1][1][r]);
        }
    }

    // ---- region 2: tiles 64..79, u = 8d+2*tc+qh, coef x0[u], tt -------------
    #pragma unroll 1
    for (int d = 0; d < 4; ++d) {
        const int t4 = 64 + 4*d;
        f32x4 w2[2];

        mfma2(A0, A1, Ab, w2);  load_slot(t4 + 4, A0, A1, Ab);
        {
            const int u = 8*d + qh;
            #pragma unroll
            for (int ms = 0; ms < 2; ++ms) {
                f32x4 cfv = ld_cf4(&cfh[u][ebase + ms*16]);
                #pragma unroll
                for (int r = 0; r < 4; ++r) ttv[ms][r] = fmaf(cfv[r], w2[ms][r], ttv[ms][r]);
            }
        }
        mfma2(B0, B1, Bb, w2);  load_slot(t4 + 5, B0, B1, Bb);
        {
            const int u = 8*d + 2 + qh;
            #pragma unroll
            for (int ms = 0; ms < 2; ++ms) {
                f32x4 cfv = ld_cf4(&cfh[u][ebase + ms*16]);
                #pragma unroll
                for (int r = 0; r < 4; ++r) ttv[ms][r] = fmaf(cfv[r], w2[ms][r], ttv[ms][r]);
            }
        }
        mfma2(C0, C1, Cb, w2);  load_slot(t4 + 6, C0, C1, Cb);
        {
            const int u = 8*d + 4 + qh;
            #pragma unroll
            for (int ms = 0; ms < 2; ++ms) {
                f32x4 cfv = ld_cf4(&cfh[u][ebase + ms*16]);
                #pragma unroll
                for (int r = 0; r < 4; ++r) ttv[ms][r] = fmaf(cfv[r], w2[ms][r], ttv[ms][r]);
            }
        }
        mfma2(D0, D1, Db, w2);  load_slot(t4 + 7, D0, D1, Db);
        {
            const int u = 8*d + 6 + qh;
            #pragma unroll
            for (int ms = 0; ms < 2; ++ms) {
                f32x4 cfv = ld_cf4(&cfh[u][ebase + ms*16]);
                #pragma unroll
                for (int r = 0; r < 4; ++r) ttv[ms][r] = fmaf(cfv[r], w2[ms][r], ttv[ms][r]);
            }
        }
    }

    // ---- region 3: tiles 80..83, u = 2*tc+qh, coef s0*x1[u][m], o1 ----------
    {
        f32x4 w2[2];
        #define R3_BODY(TC)                                                         \
            {                                                                       \
                const int u = 2*(TC) + qh;                                          \
                _Pragma("unroll")                                                   \
                for (int ms = 0; ms < 2; ++ms)                                      \
                    _Pragma("unroll")                                               \
                    for (int m = 0; m < 3; ++m) {                                   \
                        f32x4 cfv = ld_cf4(&cfh[32 + u*3 + m][ebase + ms*16]);      \
                        _Pragma("unroll")                                           \
                        for (int r = 0; r < 4; ++r)                                 \
                            o1v[ms][r][m] = fmaf(cfv[r], w2[ms][r], o1v[ms][r][m]); \
                    }                                                               \
            }
        mfma2(A0, A1, Ab, w2);  load_slot(84, A0, A1, Ab);  R3_BODY(0)
        mfma2(B0, B1, Bb, w2);  load_slot(85, B0, B1, Bb);  R3_BODY(1)
        mfma2(C0, C1, Cb, w2);  load_slot(86, C0, C1, Cb);  R3_BODY(2)
        mfma2(D0, D1, Db, w2);  load_slot(87, D0, D1, Db);  R3_BODY(3)
        #undef R3_BODY
    }

    // ---- region 4: tiles 84..99, coef y1[u4], out0 --------------------------
    #pragma unroll 1
    for (int d = 0; d < 4; ++d) {
        const int t4 = 84 + 4*d;
        const int u0 = 2*d, u1 = 2*d + 1;
        f32x4 c00 = ld_cf4(&cfh[56 + u0][ebase]);
        f32x4 c01 = ld_cf4(&cfh[56 + u0][ebase + 16]);
        f32x4 c10 = ld_cf4(&cfh[56 + u1][ebase]);
        f32x4 c11 = ld_cf4(&cfh[56 + u1][ebase + 16]);
        f32x4 w2[2];
        int tn;

        mfma2(A0, A1, Ab, w2);  tn = t4 + 4; load_slot(tn < 100 ? tn : 99, A0, A1, Ab);
        #pragma unroll
        for (int r = 0; r < 4; ++r) {
            o0[0][0][r] = fmaf(c00[r], w2[0][r], o0[0][0][r]);
            o0[1][0][r] = fmaf(c01[r], w2[1][r], o0[1][0][r]);
        }
        mfma2(B0, B1, Bb, w2);  tn = t4 + 5; load_slot(tn < 100 ? tn : 99, B0, B1, Bb);
        #pragma unroll
        for (int r = 0; r < 4; ++r) {
            o0[0][1][r] = fmaf(c00[r], w2[0][r], o0[0][1][r]);
            o0[1][1][r] = fmaf(c01[r], w2[1][r], o0[1][1][r]);
        }
        mfma2(C0, C1, Cb, w2);  tn = t4 + 6; load_slot(tn < 100 ? tn : 99, C0, C1, Cb);
        #pragma unroll
        for (int r = 0; r < 4; ++r) {
            o0[0][0][r] = fmaf(c10[r], w2[0][r], o0[0][0][r]);
            o0[1][0][r] = fmaf(c11[r], w2[1][r], o0[1][0][r]);
        }
        mfma2(D0, D1, Db, w2);  tn = t4 + 7; load_slot(tn < 100 ? tn : 99, D0, D1, Db);
        #pragma unroll
        for (int r = 0; r < 4; ++r) {
            o0[0][1][r] = fmaf(c10[r], w2[0][r], o0[0][1][r]);
            o0[1][1][r] = fmaf(c11[r], w2[1][r], o0[1][1][r]);
        }
    }

    // ---- finish: reduce u-halves (lane ^ 8), coalesced per-edge stores ------
    #pragma unroll
    for (int ms = 0; ms < 2; ++ms)
        #pragma unroll
        for (int r = 0; r < 4; ++r) {
            ttv[ms][r] += __shfl_xor(ttv[ms][r], 8, 64);
            #pragma unroll
            for (int m = 0; m < 3; ++m)
                o1v[ms][r][m] += __shfl_xor(o1v[ms][r][m], 8, 64);
        }

    #pragma unroll
    for (int ms = 0; ms < 2; ++ms) {
        const int eb = ebase + ms*16;
        const f32x4 s1x = *reinterpret_cast<const f32x4*>(&shS[1][eb]);
        const f32x4 s1y = *reinterpret_cast<const f32x4*>(&shS[2][eb]);
        const f32x4 s1z = *reinterpret_cast<const f32x4*>(&shS[3][eb]);
        #pragma unroll
        for (int r = 0; r < 4; ++r) {
            float* tp = tpbuf + (size_t)(E0 + eb + r) * IND;
            tp[q]      = PATH_NORM_C * o0[ms][0][r];
            tp[16 + q] = PATH_NORM_C * o0[ms][1][r];
            if ((q & 8) == 0) {
                const int v = q & 7;
                tp[32 + 3*v + 0] = PATH_NORM_C * (o1v[ms][r][0] + s1x[r]*ttv[ms][r]);
                tp[32 + 3*v + 1] = PATH_NORM_C * (o1v[ms][r][1] + s1y[r]*ttv[ms][r]);
                tp[32 + 3*v + 2] = PATH_NORM_C * (o1v[ms][r][2] + s1z[r]*ttv[ms][r]);
            }
        }
    }
}

// ===== mono edge kernel (R11 verbatim, 111.6 µs proven): middle tier ========
__global__ __launch_bounds__(256, 3) void edge_kernel_mono(
    const float* __restrict__ node_attr,
    const float* __restrict__ edge_attr,
    const float* __restrict__ edge_sh,
    const float* __restrict__ fc_b1,
    const float* __restrict__ fc_b2,
    const int*   __restrict__ edge_index,
    const ushort* __restrict__ W1T,
    const ushort* __restrict__ W2F,
    float* __restrict__ tpbuf)
{
    __shared__ ushort cfh[64][EPB];
    __shared__ float  shS[4][EPB];
    __shared__ __attribute__((aligned(16))) ushort pool[8192];

    const int tid  = threadIdx.x;
    const int wave = tid >> 6;
    const int lane = tid & 63;
    const int g    = lane >> 4;
    const int q    = lane & 15;
    const int E0   = blockIdx.x * EPB;

    if (tid < EPB) {
        const int e    = tid;
        const int dstn = edge_index[NE + E0 + e];
        const float4 sh = reinterpret_cast<const float4*>(edge_sh)[E0 + e];
        const float4* xp = reinterpret_cast<const float4*>(node_attr + (size_t)dstn * IND);
        float xr[56];
        #pragma unroll
        for (int i = 0; i < 14; ++i) {
            float4 v = xp[i];
            xr[4*i] = v.x; xr[4*i+1] = v.y; xr[4*i+2] = v.z; xr[4*i+3] = v.w;
        }
        #pragma unroll
        for (int u = 0; u < 32; ++u) cfh[u][e] = (ushort)f2bf(xr[u]);
        #pragma unroll
        for (int u = 0; u < 8; ++u) {
            cfh[32 + 3*u + 0][e] = (ushort)f2bf(sh.x * xr[32 + 3*u + 0]);
            cfh[32 + 3*u + 1][e] = (ushort)f2bf(sh.x * xr[32 + 3*u + 1]);
            cfh[32 + 3*u + 2][e] = (ushort)f2bf(sh.x * xr[32 + 3*u + 2]);
            cfh[56 + u][e] = (ushort)f2bf(
                CG_C * (xr[32+3*u]*sh.y + xr[32+3*u+1]*sh.z + xr[32+3*u+2]*sh.w));
        }
        shS[0][e] = sh.x;
        shS[1][e] = sh.y;  shS[2][e] = sh.z;  shS[3][e] = sh.w;
    }

    f32x4 d1[2][4];
    #pragma unroll
    for (int mt = 0; mt < 4; ++mt) {
        const float4 b1v = *reinterpret_cast<const float4*>(fc_b1 + mt*16 + 4*g);
        #pragma unroll
        for (int ms = 0; ms < 2; ++ms)
            d1[ms][mt] = (f32x4){b1v.x, b1v.y, b1v.z, b1v.w};
    }
    #pragma unroll
    for (int kh = 0; kh < 2; ++kh) {
        bf16x8 bfr[2];
        #pragma unroll
        for (int ms = 0; ms < 2; ++ms) {
            const int e = E0 + wave*32 + ms*16 + q;
            const float* ap = edge_attr + (size_t)e * 64 + kh*32 + g*8;
            float4 f0 = *reinterpret_cast<const float4*>(ap);
            float4 f1 = *reinterpret_cast<const float4*>(ap + 4);
            union { uint32_t u[4]; bf16x8 v; } cv;
            cv.u[0] = pack2(f0.x, f0.y); cv.u[1] = pack2(f0.z, f0.w);
            cv.u[2] = pack2(f1.x, f1.y); cv.u[3] = pack2(f1.z, f1.w);
            bfr[ms] = cv.v;
        }
        #pragma unroll
        for (int mt = 0; mt < 4; ++mt) {
            bf16x8 afr = *reinterpret_cast<const bf16x8*>(W1T + (mt*16 + q)*64 + kh*32 + g*8);
            #pragma unroll
            for (int ms = 0; ms < 2; ++ms)
                d1[ms][mt] = __builtin_amdgcn_mfma_f32_16x16x32_bf16(afr, bfr[ms], d1[ms][mt], 0, 0, 0);
        }
    }
    #pragma unroll
    for (int mt = 0; mt < 4; ++mt) {
        const int kg = 2*mt + (g >> 1);
        #pragma unroll
        for (int ms = 0; ms < 2; ++ms) {
            float v0 = fmaxf(d1[ms][mt][0], 0.f);
            float v1 = fmaxf(d1[ms][mt][1], 0.f);
            float v2 = fmaxf(d1[ms][mt][2], 0.f);
            float v3 = fmaxf(d1[ms][mt][3], 0.f);
            uint32_t* wp = reinterpret_cast<uint32_t*>(
                &pool[wave*2048 + ms*1024 + (kg*16 + q)*8 + 4*(g & 1)]);
            wp[0] = pack2(v0, v1);
            wp[1] = pack2(v2, v3);
        }
    }

    bf16x8 af[2][2];
    #pragma unroll
    for (int ms = 0; ms < 2; ++ms)
        #pragma unroll
        for (int kh = 0; kh < 2; ++kh)
            af[ms][kh] = *reinterpret_cast<const bf16x8*>(
                &pool[wave*2048 + ms*1024 + ((kh*4 + g)*16 + q)*8]);

    bf16x8 A0, A1, B0, B1, C0, C1, D0, D1;
    float  Ab, Bb, Cb, Db;
    auto load_slot = [&](int t, bf16x8& b0, bf16x8& b1, float& bb) {
        const ushort* p = W2F + (size_t)t * 1024 + lane * 8;
        b0 = *reinterpret_cast<const bf16x8*>(p);
        b1 = *reinterpret_cast<const bf16x8*>(p + 512);
        bb = fc_b2[t * 16 + q];
    };
    load_slot(0, A0, A1, Ab);
    load_slot(1, B0, B1, Bb);
    load_slot(2, C0, C1, Cb);
    load_slot(3, D0, D1, Db);

    __syncthreads();

    const int ebase = wave*32 + 4*g;
    f32x4 s0v[2];
    s0v[0] = *reinterpret_cast<const f32x4*>(&shS[0][ebase]);
    s0v[1] = *reinterpret_cast<const f32x4*>(&shS[0][ebase + 16]);

    float o0[2][2][4];
    float ttv[2][4];
    float o1v[2][4][3];
    #pragma unroll
    for (int ms = 0; ms < 2; ++ms) {
        #pragma unroll
        for (int r = 0; r < 4; ++r) {
            o0[ms][0][r] = 0.f; o0[ms][1][r] = 0.f; ttv[ms][r] = 0.f;
            o1v[ms][r][0] = 0.f; o1v[ms][r][1] = 0.f; o1v[ms][r][2] = 0.f;
        }
    }

    auto mfma2 = [&](const bf16x8& b0, const bf16x8& b1, float b2v, f32x4* accv) {
        #pragma unroll
        for (int ms = 0; ms < 2; ++ms) {
            f32x4 a = (f32x4){b2v, b2v, b2v, b2v};
            a = __builtin_amdgcn_mfma_f32_16x16x32_bf16(af[ms][0], b0, a, 0, 0, 0);
            a = __builtin_amdgcn_mfma_f32_16x16x32_bf16(af[ms][1], b1, a, 0, 0, 0);
            accv[ms] = a;
        }
    };

    const int qh = q >> 3;

    #pragma unroll 1
    for (int c = 0; c < 16; ++c) {
        const int t4 = 4*c;
        const int u0 = 2*c, u1 = 2*c + 1;
        f32x4 c00 = ld_cf4(&cfh[u0][ebase]);
        f32x4 c01 = ld_cf4(&cfh[u0][ebase + 16]);
        f32x4 c10 = ld_cf4(&cfh[u1][ebase]);
        f32x4 c11 = ld_cf4(&cfh[u1][ebase + 16]);
        f32x4 w2[2];

        mfma2(A0, A1, Ab, w2);  load_slot(t4 + 4, A0, A1, Ab);
        #pragma unroll
        for (int r = 0; r < 4; ++r) {
            o0[0][0][r] = fmaf(s0v[0][r]*c00[r], w2[0][r], o0[0][0][r]);
            o0[1][0][r] = fmaf(s0v[1][r]*c01[r], w2[1][r], o0[1][0][r]);
        }
        mfma2(B0, B1, Bb, w2);  load_slot(t4 + 5, B0, B1, Bb);
        #pragma unroll
        for (int r = 0; r < 4; ++r) {
            o0[0][1][r] = fmaf(s0v[0][r]*c00[r], w2[0][r], o0[0][1][r]);
            o0[1][1][r] = fmaf(s0v[1][r]*c01[r], w2[1][r], o0[1][1][r]);
        }
        mfma2(C0, C1, Cb, w2);  load_slot(t4 + 6, C0, C1, Cb);
        #pragma unroll
        for (int r = 0; r < 4; ++r) {
            o0[0][0][r] = fmaf(s0v[0][r]*c10[r], w2[0][r], o0[0][0][r]);
            o0[1][0][r] = fmaf(s0v[1][r]*c11[r], w2[1][r], o0[1][0][r]);
        }
        mfma2(D0, D1, Db, w2);  load_slot(t4 + 7, D0, D1, Db);
        #pragma unroll
        for (int r = 0; r < 4; ++r) {
            o0[0][1][r] = fmaf(s0v[0][r]*c10[r], w2[0][r], o0[0][1][r]);
            o0[1][1][r] = fmaf(s0v[1][r]*c11[r], w2[1][r], o0[1][1][r]);
        }
    }

    #pragma unroll 1
    for (int d = 0; d < 4; ++d) {
        const int t4 = 64 + 4*d;
        f32x4 w2[2];

        mfma2(A0, A1, Ab, w2);  load_slot(t4 + 4, A0, A1, Ab);
        {
            const int u = 8*d + qh;
            #pragma unroll
            for (int ms = 0; ms < 2; ++ms) {
                f32x4 cfv = ld_cf4(&cfh[u][ebase + ms*16]);
                #pragma unroll
                for (int r = 0; r < 4; ++r) ttv[ms][r] = fmaf(cfv[r], w2[ms][r], ttv[ms][r]);
            }
        }
        mfma2(B0, B1, Bb, w2);  load_slot(t4 + 5, B0, B1, Bb);
        {
            const int u = 8*d + 2 + qh;
            #pragma unroll
            for (int ms = 0; ms < 2; ++ms) {
                f32x4 cfv = ld_cf4(&cfh[u][ebase + ms*16]);
                #pragma unroll
                for (int r = 0; r < 4; ++r) ttv[ms][r] = fmaf(cfv[r], w2[ms][r], ttv[ms][r]);
            }
        }
        mfma2(C0, C1, Cb, w2);  load_slot(t4 + 6, C0, C1, Cb);
        {
            const int u = 8*d + 4 + qh;
            #pragma unroll
            for (int ms = 0; ms < 2; ++ms) {
                f32x4 cfv = ld_cf4(&cfh[u][ebase + ms*16]);
                #pragma unroll
                for (int r = 0; r < 4; ++r) ttv[ms][r] = fmaf(cfv[r], w2[ms][r], ttv[ms][r]);
            }
        }
        mfma2(D0, D1, Db, w2);  load_slot(t4 + 7, D0, D1, Db);
        {
            const int u = 8*d + 6 + qh;
            #pragma unroll
            for (int ms = 0; ms < 2; ++ms) {
                f32x4 cfv = ld_cf4(&cfh[u][ebase + ms*16]);
                #pragma unroll
                for (int r = 0; r < 4; ++r) ttv[ms][r] = fmaf(cfv[r], w2[ms][r], ttv[ms][r]);
            }
        }
    }

    {
        f32x4 w2[2];
        #define R3_BODY(TC)                                                         \
            {                                                                       \
                const int u = 2*(TC) + qh;                                          \
                _Pragma("unroll")                                                   \
                for (int ms = 0; ms < 2; ++ms)                                      \
                    _Pragma("unroll")                                               \
                    for (int m = 0; m < 3; ++m) {                                   \
                        f32x4 cfv = ld_cf4(&cfh[32 + u*3 + m][ebase + ms*16]);      \
                        _Pragma("unroll")                                           \
                        for (int r = 0; r < 4; ++r)                                 \
                            o1v[ms][r][m] = fmaf(cfv[r], w2[ms][r], o1v[ms][r][m]); \
                    }                                                               \
            }
        mfma2(A0, A1, Ab, w2);  load_slot(84, A0, A1, Ab);  R3_BODY(0)
        mfma2(B0, B1, Bb, w2);  load_slot(85, B0, B1, Bb);  R3_BODY(1)
        mfma2(C0, C1, Cb, w2);  load_slot(86, C0, C1, Cb);  R3_BODY(2)
        mfma2(D0, D1, Db, w2);  load_slot(87, D0, D1, Db);  R3_BODY(3)
        #undef R3_BODY
    }

    #pragma unroll 1
    for (int d = 0; d < 4; ++d) {
        const int t4 = 84 + 4*d;
        const int u0 = 2*d, u1 = 2*d + 1;
        f32x4 c00 = ld_cf4(&cfh[56 + u0][ebase]);
        f32x4 c01 = ld_cf4(&cfh[56 + u0][ebase + 16]);
        f32x4 c10 = ld_cf4(&cfh[56 + u1][ebase]);
        f32x4 c11 = ld_cf4(&cfh[56 + u1][ebase + 16]);
        f32x4 w2[2];
        int tn;

        mfma2(A0, A1, Ab, w2);  tn = t4 + 4; load_slot(tn < 100 ? tn : 99, A0, A1, Ab);
        #pragma unroll
        for (int r = 0; r < 4; ++r) {
            o0[0][0][r] = fmaf(c00[r], w2[0][r], o0[0][0][r]);
            o0[1][0][r] = fmaf(c01[r], w2[1][r], o0[1][0][r]);
        }
        mfma2(B0, B1, Bb, w2);  tn = t4 + 5; load_slot(tn < 100 ? tn : 99, B0, B1, Bb);
        #pragma unroll
        for (int r = 0; r < 4; ++r) {
            o0[0][1][r] = fmaf(c00[r], w2[0][r], o0[0][1][r]);
            o0[1][1][r] = fmaf(c01[r], w2[1][r], o0[1][1][r]);
        }
        mfma2(C0, C1, Cb, w2);  tn = t4 + 6; load_slot(tn < 100 ? tn : 99, C0, C1, Cb);
        #pragma unroll
        for (int r = 0; r < 4; ++r) {
            o0[0][0][r] = fmaf(c10[r], w2[0][r], o0[0][0][r]);
            o0[1][0][r] = fmaf(c11[r], w2[1][r], o0[1][0][r]);
        }
        mfma2(D0, D1, Db, w2);  tn = t4 + 7; load_slot(tn < 100 ? tn : 99, D0, D1, Db);
        #pragma unroll
        for (int r = 0; r < 4; ++r) {
            o0[0][1][r] = fmaf(c10[r], w2[0][r], o0[0][1][r]);
            o0[1][1][r] = fmaf(c11[r], w2[1][r], o0[1][1][r]);
        }
    }

    #pragma unroll
    for (int ms = 0; ms < 2; ++ms)
        #pragma unroll
        for (int r = 0; r < 4; ++r) {
            ttv[ms][r] += __shfl_xor(ttv[ms][r], 8, 64);
            #pragma unroll
            for (int m = 0; m < 3; ++m)
                o1v[ms][r][m] += __shfl_xor(o1v[ms][r][m], 8, 64);
        }

    #pragma unroll
    for (int ms = 0; ms < 2; ++ms) {
        const int eb = ebase + ms*16;
        const f32x4 s1x = *reinterpret_cast<const f32x4*>(&shS[1][eb]);
        const f32x4 s1y = *reinterpret_cast<const f32x4*>(&shS[2][eb]);
        const f32x4 s1z = *reinterpret_cast<const f32x4*>(&shS[3][eb]);
        #pragma unroll
        for (int r = 0; r < 4; ++r) {
            float* tp = tpbuf + (size_t)(E0 + eb + r) * IND;
            tp[q]      = PATH_NORM_C * o0[ms][0][r];
            tp[16 + q] = PATH_NORM_C * o0[ms][1][r];
            if ((q & 8) == 0) {
                const int v = q & 7;
                tp[32 + 3*v + 0] = PATH_NORM_C * (o1v[ms][r][0] + s1x[r]*ttv[ms][r]);
                tp[32 + 3*v + 1] = PATH_NORM_C * (o1v[ms][r][1] + s1y[r]*ttv[ms][r]);
                tp[32 + 3*v + 2] = PATH_NORM_C * (o1v[ms][r][2] + s1z[r]*ttv[ms][r]);
            }
        }
    }
}

// ---- gather: one wave per node, mean + residual ---------------------------
__global__ __launch_bounds__(256) void gather_kernel(
    const float* __restrict__ tpbuf, const int* __restrict__ cursor,
    const int* __restrict__ elist, const float* __restrict__ node_attr,
    float* __restrict__ out)
{
    const int node = blockIdx.x * 4 + (threadIdx.x >> 6);
    const int j = threadIdx.x & 63;
    if (node >= NN) return;
    const int degt = cursor[node];
    const int deg = (degt < DCAP) ? degt : DCAP;
    float sum = 0.f;
    #pragma unroll 4
    for (int i = 0; i < deg; ++i) {
        const int e = elist[node * DCAP + i];
        if (j < 56) sum += tpbuf[(size_t)e * IND + j];
    }
    if (j < 56) {
        const float c = (degt > 0) ? (float)degt : 1.f;
        out[node * IND + j] = sum / c + node_attr[node * IND + j];
    }
}

// ---- last-resort fallback: naive per-edge atomic kernel (fp32) -------------
__global__ __launch_bounds__(256) void finalize_fb_kernel(
    const float* __restrict__ acc, const float* __restrict__ cnt,
    const float* __restrict__ node_attr, float* __restrict__ out)
{
    const int i = blockIdx.x * 256 + threadIdx.x;
    if (i >= NN * IND) return;
    const int n = i / IND;
    const float c = fmaxf(cnt[n], 1.0f);
    out[i] = acc[i] / c + node_attr[i];
}

__global__ __launch_bounds__(256) void edge_fb_kernel(
    const float* __restrict__ node_attr, const float* __restrict__ edge_attr,
    const float* __restrict__ edge_sh, const float* __restrict__ fc_w1,
    const float* __restrict__ fc_b1, const float* __restrict__ fc_w2,
    const float* __restrict__ fc_b2, const int* __restrict__ edge_index,
    float* __restrict__ acc, float* __restrict__ cnt)
{
    // one thread per (edge, v-slice of 8): slow but tiny-ws-safe
    const int idx = blockIdx.x * 256 + threadIdx.x;
    if (idx >= NE) return;
    const int e = idx;
    const int src = edge_index[e];
    const int dst = edge_index[NE + e];
    float h[64];
    #pragma unroll 1
    for (int k = 0; k < 64; ++k) {
        float s = fc_b1[k];
        for (int j = 0; j < 64; ++j) s += edge_attr[(size_t)e*64 + j] * fc_w1[j*64 + k];
        h[k] = fmaxf(s, 0.f);
    }
    const float4 sh = reinterpret_cast<const float4*>(edge_sh)[e];
    const float* x = node_attr + (size_t)dst * IND;
    float out0[32];
    #pragma unroll 1
    for (int v = 0; v < 32; ++v) out0[v] = 0.f;
    float tt[8], o1[24];
    #pragma unroll 1
    for (int v = 0; v < 8; ++v) tt[v] = 0.f;
    #pragma unroll 1
    for (int i = 0; i < 24; ++i) o1[i] = 0.f;
    #pragma unroll 1
    for (int u = 0; u < 32; ++u) {
        const float c1 = sh.x * x[u];
        for (int v = 0; v < 32; ++v) {
            float w = fc_b2[u*32 + v];
            for (int k = 0; k < 64; ++k) w += h[k] * fc_w2[k*WN + u*32 + v];
            out0[v] += c1 * w;
        }
        for (int v = 0; v < 8; ++v) {
            float w = fc_b2[1024 + u*8 + v];
            for (int k = 0; k < 64; ++k) w += h[k] * fc_w2[k*WN + 1024 + u*8 + v];
            tt[v] += x[u] * w;
        }
    }
    #pragma unroll 1
    for (int u = 0; u < 8; ++u) {
        const float y1 = CG_C * (x[32+3*u]*sh.y + x[32+3*u+1]*sh.z + x[32+3*u+2]*sh.w);
        for (int v = 0; v < 8; ++v) {
            float w = fc_b2[1280 + u*8 + v];
            for (int k = 0; k < 64; ++k) w += h[k] * fc_w2[k*WN + 1280 + u*8 + v];
            o1[3*v+0] += sh.x * w * x[32+3*u+0];
            o1[3*v+1] += sh.x * w * x[32+3*u+1];
            o1[3*v+2] += sh.x * w * x[32+3*u+2];
        }
        for (int v = 0; v < 32; ++v) {
            float w = fc_b2[1344 + u*32 + v];
            for (int k = 0; k < 64; ++k) w += h[k] * fc_w2[k*WN + 1344 + u*32 + v];
            out0[v] += y1 * w;
        }
    }
    float* ap = acc + (size_t)src * IND;
    for (int v = 0; v < 32; ++v) atomicAdd(ap + v, PATH_NORM_C * out0[v]);
    for (int v = 0; v < 8; ++v) {
        atomicAdd(ap + 32 + 3*v + 0, PATH_NORM_C * (o1[3*v+0] + sh.y * tt[v]));
        atomicAdd(ap + 32 + 3*v + 1, PATH_NORM_C * (o1[3*v+1] + sh.z * tt[v]));
        atomicAdd(ap + 32 + 3*v + 2, PATH_NORM_C * (o1[3*v+2] + sh.w * tt[v]));
    }
    atomicAdd(cnt + src, 1.0f);
}

extern "C" void kernel_launch(void* const* d_in, const int* in_sizes, int n_in,
                              void* d_out, int out_size, void* d_ws, size_t ws_size,
                              hipStream_t stream) {
    const float* node_attr = (const float*)d_in[0];
    const float* edge_attr = (const float*)d_in[1];
    const float* edge_sh   = (const float*)d_in[2];
    const float* fc_w1     = (const float*)d_in[3];
    const float* fc_b1     = (const float*)d_in[4];
    const float* fc_w2     = (const float*)d_in[5];
    const float* fc_b2     = (const float*)d_in[6];
    const int*   edge_index = (const int*)d_in[7];

    char* ws = (char*)d_ws;
    int*    cursor = (int*)(ws + 0);                  // 40,000
    int*    elist  = (int*)(ws + 40000);              // -> 2,600,000
    ushort* W1T    = (ushort*)(ws + 2600000);         // -> 2,608,192
    ushort* W2F    = (ushort*)(ws + 2608192);         // -> 2,812,992
    float*  tpbuf  = (float*)(ws + 2812992);          // -> 38,652,992
    ushort* Hbuf   = (ushort*)(ws + 38652992);        // -> 59,132,992
    const size_t WS_SPLIT = 59132992ull;
    const size_t WS_MONO  = 38652992ull;

    if (ws_size >= WS_MONO) {
        hipMemsetAsync(cursor, 0, 40000, stream);
        prep_kernel<<<(64*64 + 100*1024 + NE + 255) / 256, 256, 0, stream>>>(
            fc_w1, fc_w2, edge_index, W1T, W2F, cursor, elist, 1);
        if (ws_size >= WS_SPLIT) {
            h_kernel<<<NBLK, 256, 0, stream>>>(edge_attr, fc_b1, W1T, Hbuf);
            edge_kernel_split<<<NBLK, 256, 0, stream>>>(
                node_attr, edge_sh, fc_b2, edge_index, W2F, Hbuf, tpbuf);
        } else {
            edge_kernel_mono<<<NBLK, 256, 0, stream>>>(
                node_attr, edge_attr, edge_sh, fc_b1, fc_b2, edge_index, W1T, W2F, tpbuf);
        }
        gather_kernel<<<(NN + 3) / 4, 256, 0, stream>>>(
            tpbuf, cursor, elist, node_attr, (float*)d_out);
    } else {
        // tiny-ws last resort: fp32 atomic path
        float* acc = (float*)ws;                      // 2,240,000
        float* cnt = (float*)(ws + 2240000);          // -> 2,280,000
        hipMemsetAsync(ws, 0, 2280000, stream);
        edge_fb_kernel<<<(NE + 255) / 256, 256, 0, stream>>>(
            node_attr, edge_attr, edge_sh, fc_w1, fc_b1, fc_w2, fc_b2, edge_index, acc, cnt);
        finalize_fb_kernel<<<(NN * IND + 255) / 256, 256, 0, stream>>>(
            acc, cnt, node_attr, (float*)d_out);
    }
}

// Round 16
// 105.110 us; speedup vs baseline: 1.2268x; 1.0834x over previous
//
#include <hip/hip_runtime.h>

#define NN 10000
#define NE 160000
#define IND 56          // 32 + 3*8
#define WN 1600
#define EPB 128         // edges per block (4 waves x 32)
#define NBLK (NE / EPB) // 1250
#define DCAP 64         // max edges per source node bucket

typedef __attribute__((ext_vector_type(8))) short bf16x8;
typedef __attribute__((ext_vector_type(4))) float f32x4;

static constexpr float PATH_NORM_C = 0.15811388300841897f; // 1/sqrt(40)
static constexpr float CG_C        = 0.57735026918962576f; // 1/sqrt(3)

__device__ __forceinline__ uint32_t f2bf(float f) {
    uint32_t x = __float_as_uint(f);
    return (x + 0x7fffu + ((x >> 16) & 1u)) >> 16;   // RNE
}
__device__ __forceinline__ uint32_t pack2(float a, float b) {
    return f2bf(a) | (f2bf(b) << 16);
}
__device__ __forceinline__ f32x4 ld_cf4(const ushort* p) {
    uint2 w = *reinterpret_cast<const uint2*>(p);
    f32x4 v;
    v[0] = __uint_as_float(w.x << 16);
    v[1] = __uint_as_float(w.x & 0xffff0000u);
    v[2] = __uint_as_float(w.y << 16);
    v[3] = __uint_as_float(w.y & 0xffff0000u);
    return v;
}

// ==== front kernel: GEMM1 (W1 via LDS) + W2F conversion + elist fill ========
__global__ __launch_bounds__(256) void front_kernel(
    const float* __restrict__ edge_attr,
    const float* __restrict__ fc_w1,
    const float* __restrict__ fc_b1,
    const float* __restrict__ fc_w2,
    const int*   __restrict__ edge_index,
    ushort* __restrict__ W2F,
    int* __restrict__ cursor, int* __restrict__ elist,
    ushort* __restrict__ Hbuf)
{
    __shared__ ushort w1lds[64 * 66];   // [k][j], pitch 66 (bank-conflict-free)

    const int tid  = threadIdx.x;
    const int wave = tid >> 6;
    const int lane = tid & 63;
    const int g    = lane >> 4;
    const int q    = lane & 15;
    const int E0   = blockIdx.x * EPB;

    // coop W1 bf16-transpose into LDS: idx = j*64+k, consecutive tid -> k
    #pragma unroll
    for (int it = 0; it < 16; ++it) {
        const int idx = it * 256 + tid;
        const int j = idx >> 6, k = idx & 63;
        w1lds[k * 66 + j] = (ushort)f2bf(fc_w1[idx]);
    }
    __syncthreads();

    // GEMM1: h = relu(edge_attr @ W1 + b1), A-frag from LDS
    f32x4 d1[2][4];
    #pragma unroll
    for (int mt = 0; mt < 4; ++mt) {
        const float4 b1v = *reinterpret_cast<const float4*>(fc_b1 + mt*16 + 4*g);
        #pragma unroll
        for (int ms = 0; ms < 2; ++ms)
            d1[ms][mt] = (f32x4){b1v.x, b1v.y, b1v.z, b1v.w};
    }

    #pragma unroll
    for (int kh = 0; kh < 2; ++kh) {
        bf16x8 bfr[2];
        #pragma unroll
        for (int ms = 0; ms < 2; ++ms) {
            const int e = E0 + wave*32 + ms*16 + q;
            const float* ap = edge_attr + (size_t)e * 64 + kh*32 + g*8;
            float4 f0 = *reinterpret_cast<const float4*>(ap);
            float4 f1 = *reinterpret_cast<const float4*>(ap + 4);
            union { uint32_t u[4]; bf16x8 v; } cv;
            cv.u[0] = pack2(f0.x, f0.y); cv.u[1] = pack2(f0.z, f0.w);
            cv.u[2] = pack2(f1.x, f1.y); cv.u[3] = pack2(f1.z, f1.w);
            bfr[ms] = cv.v;
        }
        #pragma unroll
        for (int mt = 0; mt < 4; ++mt) {
            bf16x8 afr = *reinterpret_cast<const bf16x8*>(
                &w1lds[(mt*16 + q) * 66 + kh*32 + g*8]);
            #pragma unroll
            for (int ms = 0; ms < 2; ++ms)
                d1[ms][mt] = __builtin_amdgcn_mfma_f32_16x16x32_bf16(afr, bfr[ms], d1[ms][mt], 0, 0, 0);
        }
    }
    #pragma unroll
    for (int mt = 0; mt < 4; ++mt) {
        const int kg = 2*mt + (g >> 1);
        #pragma unroll
        for (int ms = 0; ms < 2; ++ms) {
            const int group = blockIdx.x*8 + wave*2 + ms;
            float v0 = fmaxf(d1[ms][mt][0], 0.f);
            float v1 = fmaxf(d1[ms][mt][1], 0.f);
            float v2 = fmaxf(d1[ms][mt][2], 0.f);
            float v3 = fmaxf(d1[ms][mt][3], 0.f);
            uint2 w;
            w.x = pack2(v0, v1);
            w.y = pack2(v2, v3);
            *reinterpret_cast<uint2*>(Hbuf + (size_t)group*1024 + (kg*16 + q)*8 + 4*(g & 1)) = w;
        }
    }

    // piggyback prep items: W2F conversion then elist fill
    const int gid = blockIdx.x * 256 + tid;
    if (gid < 100 * 1024) {
        int t  = gid >> 10, r = gid & 1023;
        int kh = r >> 9,  rr = r & 511;
        int l  = rr >> 3, ii = rr & 7;
        int j  = t * 16 + (l & 15);
        int k  = kh * 32 + ((l >> 4) << 3) + ii;
        W2F[gid] = (ushort)f2bf(fc_w2[k * WN + j]);
    } else {
        const int i3 = gid - 100 * 1024;
        if (i3 < NE) {
            int s = edge_index[i3];
            int pos = atomicAdd(&cursor[s], 1);
            if (pos < DCAP) elist[s * DCAP + pos] = i3;
        }
    }
}

// ---- pre-pass for mono tier: W1T + W2F + bucket fill -----------------------
__global__ __launch_bounds__(256) void prep_kernel(
    const float* __restrict__ fc_w1, const float* __restrict__ fc_w2,
    const int* __restrict__ edge_index,
    ushort* __restrict__ W1T, ushort* __restrict__ W2F,
    int* __restrict__ cursor, int* __restrict__ elist, int do_fill)
{
    int i = blockIdx.x * 256 + threadIdx.x;
    if (i < 64 * 64) {
        int k = i >> 6, j = i & 63;
        W1T[k * 64 + j] = (ushort)f2bf(fc_w1[j * 64 + k]);
    }
    int i2 = i - 64 * 64;
    if (i2 >= 0 && i2 < 100 * 1024) {
        int t  = i2 >> 10, r = i2 & 1023;
        int kh = r >> 9,  rr = r & 511;
        int l  = rr >> 3, ii = rr & 7;
        int j  = t * 16 + (l & 15);
        int k  = kh * 32 + ((l >> 4) << 3) + ii;
        W2F[i2] = (ushort)f2bf(fc_w2[k * WN + j]);
    }
    int i3 = i2 - 100 * 1024;
    if (i3 >= 0 && i3 < NE && do_fill) {
        int s = edge_index[i3];
        int pos = atomicAdd(&cursor[s], 1);
        if (pos < DCAP) elist[s * DCAP + pos] = i3;
    }
}

// ===== split edge kernel (R15 verbatim, 75 µs proven) =======================
__global__ __launch_bounds__(256) void edge_kernel_split(
    const float* __restrict__ node_attr,
    const float* __restrict__ edge_sh,
    const float* __restrict__ fc_b2,
    const int*   __restrict__ edge_index,
    const ushort* __restrict__ W2F,
    const ushort* __restrict__ Hbuf,
    float* __restrict__ tpbuf)
{
    __shared__ ushort cfh[64][EPB];                               // 16 KB
    __shared__ float  shS[4][EPB];                                //  2 KB

    const int tid  = threadIdx.x;
    const int wave = tid >> 6;
    const int lane = tid & 63;
    const int g    = lane >> 4;
    const int q    = lane & 15;
    const int E0   = blockIdx.x * EPB;

    if (tid < EPB) {
        const int e    = tid;
        const int dstn = edge_index[NE + E0 + e];
        const float4 sh = reinterpret_cast<const float4*>(edge_sh)[E0 + e];
        const float4* xp = reinterpret_cast<const float4*>(node_attr + (size_t)dstn * IND);
        float xr[56];
        #pragma unroll
        for (int i = 0; i < 14; ++i) {
            float4 v = xp[i];
            xr[4*i] = v.x; xr[4*i+1] = v.y; xr[4*i+2] = v.z; xr[4*i+3] = v.w;
        }
        #pragma unroll
        for (int u = 0; u < 32; ++u) cfh[u][e] = (ushort)f2bf(xr[u]);
        #pragma unroll
        for (int u = 0; u < 8; ++u) {
            cfh[32 + 3*u + 0][e] = (ushort)f2bf(sh.x * xr[32 + 3*u + 0]);
            cfh[32 + 3*u + 1][e] = (ushort)f2bf(sh.x * xr[32 + 3*u + 1]);
            cfh[32 + 3*u + 2][e] = (ushort)f2bf(sh.x * xr[32 + 3*u + 2]);
            cfh[56 + u][e] = (ushort)f2bf(
                CG_C * (xr[32+3*u]*sh.y + xr[32+3*u+1]*sh.z + xr[32+3*u+2]*sh.w));
        }
        shS[0][e] = sh.x;
        shS[1][e] = sh.y;  shS[2][e] = sh.z;  shS[3][e] = sh.w;
    }

    bf16x8 af[2][2];
    #pragma unroll
    for (int ms = 0; ms < 2; ++ms)
        #pragma unroll
        for (int kh = 0; kh < 2; ++kh)
            af[ms][kh] = *reinterpret_cast<const bf16x8*>(
                Hbuf + (size_t)(blockIdx.x*8 + wave*2 + ms)*1024 + kh*512 + g*128 + q*8);

    bf16x8 A0, A1, B0, B1, C0, C1, D0, D1;
    float  Ab, Bb, Cb, Db;
    auto load_slot = [&](int t, bf16x8& b0, bf16x8& b1, float& bb) {
        const ushort* p = W2F + (size_t)t * 1024 + lane * 8;
        b0 = *reinterpret_cast<const bf16x8*>(p);
        b1 = *reinterpret_cast<const bf16x8*>(p + 512);
        bb = fc_b2[t * 16 + q];
    };
    load_slot(0, A0, A1, Ab);
    load_slot(1, B0, B1, Bb);
    load_slot(2, C0, C1, Cb);
    load_slot(3, D0, D1, Db);

    __syncthreads();

    const int ebase = wave*32 + 4*g;
    f32x4 s0v[2];
    s0v[0] = *reinterpret_cast<const f32x4*>(&shS[0][ebase]);
    s0v[1] = *reinterpret_cast<const f32x4*>(&shS[0][ebase + 16]);

    float o0[2][2][4];
    float ttv[2][4];
    float o1v[2][4][3];
    #pragma unroll
    for (int ms = 0; ms < 2; ++ms) {
        #pragma unroll
        for (int r = 0; r < 4; ++r) {
            o0[ms][0][r] = 0.f; o0[ms][1][r] = 0.f; ttv[ms][r] = 0.f;
            o1v[ms][r][0] = 0.f; o1v[ms][r][1] = 0.f; o1v[ms][r][2] = 0.f;
        }
    }

    auto mfma2 = [&](const bf16x8& b0, const bf16x8& b1, float b2v, f32x4* accv) {
        #pragma unroll
        for (int ms = 0; ms < 2; ++ms) {
            f32x4 a = (f32x4){b2v, b2v, b2v, b2v};
            a = __builtin_amdgcn_mfma_f32_16x16x32_bf16(af[ms][0], b0, a, 0, 0, 0);
            a = __builtin_amdgcn_mfma_f32_16x16x32_bf16(af[ms][1], b1, a, 0, 0, 0);
            accv[ms] = a;
        }
    };

    const int qh = q >> 3;

    #pragma unroll 1
    for (int c = 0; c < 16; ++c) {
        const int t4 = 4*c;
        const int u0 = 2*c, u1 = 2*c + 1;
        f32x4 c00 = ld_cf4(&cfh[u0][ebase]);
        f32x4 c01 = ld_cf4(&cfh[u0][ebase + 16]);
        f32x4 c10 = ld_cf4(&cfh[u1][ebase]);
        f32x4 c11 = ld_cf4(&cfh[u1][ebase + 16]);
        f32x4 w2[2];

        mfma2(A0, A1, Ab, w2);  load_slot(t4 + 4, A0, A1, Ab);
        #pragma unroll
        for (int r = 0; r < 4; ++r) {
            o0[0][0][r] = fmaf(s0v[0][r]*c00[r], w2[0][r], o0[0][0][r]);
            o0[1][0][r] = fmaf(s0v[1][r]*c01[r], w2[1][r], o0[1][0][r]);
        }
        mfma2(B0, B1, Bb, w2);  load_slot(t4 + 5, B0, B1, Bb);
        #pragma unroll
        for (int r = 0; r < 4; ++r) {
            o0[0][1][r] = fmaf(s0v[0][r]*c00[r], w2[0][r], o0[0][1][r]);
            o0[1][1][r] = fmaf(s0v[1][r]*c01[r], w2[1][r], o0[1][1][r]);
        }
        mfma2(C0, C1, Cb, w2);  load_slot(t4 + 6, C0, C1, Cb);
        #pragma unroll
        for (int r = 0; r < 4; ++r) {
            o0[0][0][r] = fmaf(s0v[0][r]*c10[r], w2[0][r], o0[0][0][r]);
            o0[1][0][r] = fmaf(s0v[1][r]*c11[r], w2[1][r], o0[1][0][r]);
        }
        mfma2(D0, D1, Db, w2);  load_slot(t4 + 7, D0, D1, Db);
        #pragma unroll
        for (int r = 0; r < 4; ++r) {
            o0[0][1][r] = fmaf(s0v[0][r]*c10[r], w2[0][r], o0[0][1][r]);
            o0[1][1][r] = fmaf(s0v[1][r]*c11[r], w2[1][r], o0[1][1][r]);
        }
    }

    #pragma unroll 1
    for (int d = 0; d < 4; ++d) {
        const int t4 = 64 + 4*d;
        f32x4 w2[2];

        mfma2(A0, A1, Ab, w2);  load_slot(t4 + 4, A0, A1, Ab);
        {
            const int u = 8*d + qh;
            #pragma unroll
            for (int ms = 0; ms < 2; ++ms) {
                f32x4 cfv = ld_cf4(&cfh[u][ebase + ms*16]);
                #pragma unroll
                for (int r = 0; r < 4; ++r) ttv[ms][r] = fmaf(cfv[r], w2[ms][r], ttv[ms][r]);
            }
        }
        mfma2(B0, B1, Bb, w2);  load_slot(t4 + 5, B0, B1, Bb);
        {
            const int u = 8*d + 2 + qh;
            #pragma unroll
            for (int ms = 0; ms < 2; ++ms) {
                f32x4 cfv = ld_cf4(&cfh[u][ebase + ms*16]);
                #pragma unroll
                for (int r = 0; r < 4; ++r) ttv[ms][r] = fmaf(cfv[r], w2[ms][r], ttv[ms][r]);
            }
        }
        mfma2(C0, C1, Cb, w2);  load_slot(t4 + 6, C0, C1, Cb);
        {
            const int u = 8*d + 4 + qh;
            #pragma unroll
            for (int ms = 0; ms < 2; ++ms) {
                f32x4 cfv = ld_cf4(&cfh[u][ebase + ms*16]);
                #pragma unroll
                for (int r = 0; r < 4; ++r) ttv[ms][r] = fmaf(cfv[r], w2[ms][r], ttv[ms][r]);
            }
        }
        mfma2(D0, D1, Db, w2);  load_slot(t4 + 7, D0, D1, Db);
        {
            const int u = 8*d + 6 + qh;
            #pragma unroll
            for (int ms = 0; ms < 2; ++ms) {
                f32x4 cfv = ld_cf4(&cfh[u][ebase + ms*16]);
                #pragma unroll
                for (int r = 0; r < 4; ++r) ttv[ms][r] = fmaf(cfv[r], w2[ms][r], ttv[ms][r]);
            }
        }
    }

    {
        f32x4 w2[2];
        #define R3_BODY(TC)                                                         \
            {                                                                       \
                const int u = 2*(TC) + qh;                                          \
                _Pragma("unroll")                                                   \
                for (int ms = 0; ms < 2; ++ms)                                      \
                    _Pragma("unroll")                                               \
                    for (int m = 0; m < 3; ++m) {                                   \
                        f32x4 cfv = ld_cf4(&cfh[32 + u*3 + m][ebase + ms*16]);      \
                        _Pragma("unroll")                                           \
                        for (int r = 0; r < 4; ++r)                                 \
                            o1v[ms][r][m] = fmaf(cfv[r], w2[ms][r], o1v[ms][r][m]); \
                    }                                                               \
            }
        mfma2(A0, A1, Ab, w2);  load_slot(84, A0, A1, Ab);  R3_BODY(0)
        mfma2(B0, B1, Bb, w2);  load_slot(85, B0, B1, Bb);  R3_BODY(1)
        mfma2(C0, C1, Cb, w2);  load_slot(86, C0, C1, Cb);  R3_BODY(2)
        mfma2(D0, D1, Db, w2);  load_slot(87, D0, D1, Db);  R3_BODY(3)
        #undef R3_BODY
    }

    #pragma unroll 1
    for (int d = 0; d < 4; ++d) {
        const int t4 = 84 + 4*d;
        const int u0 = 2*d, u1 = 2*d + 1;
        f32x4 c00 = ld_cf4(&cfh[56 + u0][ebase]);
        f32x4 c01 = ld_cf4(&cfh[56 + u0][ebase + 16]);
        f32x4 c10 = ld_cf4(&cfh[56 + u1][ebase]);
        f32x4 c11 = ld_cf4(&cfh[56 + u1][ebase + 16]);
        f32x4 w2[2];
        int tn;

        mfma2(A0, A1, Ab, w2);  tn = t4 + 4; load_slot(tn < 100 ? tn : 99, A0, A1, Ab);
        #pragma unroll
        for (int r = 0; r < 4; ++r) {
            o0[0][0][r] = fmaf(c00[r], w2[0][r], o0[0][0][r]);
            o0[1][0][r] = fmaf(c01[r], w2[1][r], o0[1][0][r]);
        }
        mfma2(B0, B1, Bb, w2);  tn = t4 + 5; load_slot(tn < 100 ? tn : 99, B0, B1, Bb);
        #pragma unroll
        for (int r = 0; r < 4; ++r) {
            o0[0][1][r] = fmaf(c00[r], w2[0][r], o0[0][1][r]);
            o0[1][1][r] = fmaf(c01[r], w2[1][r], o0[1][1][r]);
        }
        mfma2(C0, C1, Cb, w2);  tn = t4 + 6; load_slot(tn < 100 ? tn : 99, C0, C1, Cb);
        #pragma unroll
        for (int r = 0; r < 4; ++r) {
            o0[0][0][r] = fmaf(c10[r], w2[0][r], o0[0][0][r]);
            o0[1][0][r] = fmaf(c11[r], w2[1][r], o0[1][0][r]);
        }
        mfma2(D0, D1, Db, w2);  tn = t4 + 7; load_slot(tn < 100 ? tn : 99, D0, D1, Db);
        #pragma unroll
        for (int r = 0; r < 4; ++r) {
            o0[0][1][r] = fmaf(c10[r], w2[0][r], o0[0][1][r]);
            o0[1][1][r] = fmaf(c11[r], w2[1][r], o0[1][1][r]);
        }
    }

    #pragma unroll
    for (int ms = 0; ms < 2; ++ms)
        #pragma unroll
        for (int r = 0; r < 4; ++r) {
            ttv[ms][r] += __shfl_xor(ttv[ms][r], 8, 64);
            #pragma unroll
            for (int m = 0; m < 3; ++m)
                o1v[ms][r][m] += __shfl_xor(o1v[ms][r][m], 8, 64);
        }

    #pragma unroll
    for (int ms = 0; ms < 2; ++ms) {
        const int eb = ebase + ms*16;
        const f32x4 s1x = *reinterpret_cast<const f32x4*>(&shS[1][eb]);
        const f32x4 s1y = *reinterpret_cast<const f32x4*>(&shS[2][eb]);
        const f32x4 s1z = *reinterpret_cast<const f32x4*>(&shS[3][eb]);
        #pragma unroll
        for (int r = 0; r < 4; ++r) {
            float* tp = tpbuf + (size_t)(E0 + eb + r) * IND;
            tp[q]      = PATH_NORM_C * o0[ms][0][r];
            tp[16 + q] = PATH_NORM_C * o0[ms][1][r];
            if ((q & 8) == 0) {
                const int v = q & 7;
                tp[32 + 3*v + 0] = PATH_NORM_C * (o1v[ms][r][0] + s1x[r]*ttv[ms][r]);
                tp[32 + 3*v + 1] = PATH_NORM_C * (o1v[ms][r][1] + s1y[r]*ttv[ms][r]);
                tp[32 + 3*v + 2] = PATH_NORM_C * (o1v[ms][r][2] + s1z[r]*ttv[ms][r]);
            }
        }
    }
}

// ===== mono edge kernel (R11 verbatim): middle tier =========================
__global__ __launch_bounds__(256, 3) void edge_kernel_mono(
    const float* __restrict__ node_attr,
    const float* __restrict__ edge_attr,
    const float* __restrict__ edge_sh,
    const float* __restrict__ fc_b1,
    const float* __restrict__ fc_b2,
    const int*   __restrict__ edge_index,
    const ushort* __restrict__ W1T,
    const ushort* __restrict__ W2F,
    float* __restrict__ tpbuf)
{
    __shared__ ushort cfh[64][EPB];
    __shared__ float  shS[4][EPB];
    __shared__ __attribute__((aligned(16))) ushort pool[8192];

    const int tid  = threadIdx.x;
    const int wave = tid >> 6;
    const int lane = tid & 63;
    const int g    = lane >> 4;
    const int q    = lane & 15;
    const int E0   = blockIdx.x * EPB;

    if (tid < EPB) {
        const int e    = tid;
        const int dstn = edge_index[NE + E0 + e];
        const float4 sh = reinterpret_cast<const float4*>(edge_sh)[E0 + e];
        const float4* xp = reinterpret_cast<const float4*>(node_attr + (size_t)dstn * IND);
        float xr[56];
        #pragma unroll
        for (int i = 0; i < 14; ++i) {
            float4 v = xp[i];
            xr[4*i] = v.x; xr[4*i+1] = v.y; xr[4*i+2] = v.z; xr[4*i+3] = v.w;
        }
        #pragma unroll
        for (int u = 0; u < 32; ++u) cfh[u][e] = (ushort)f2bf(xr[u]);
        #pragma unroll
        for (int u = 0; u < 8; ++u) {
            cfh[32 + 3*u + 0][e] = (ushort)f2bf(sh.x * xr[32 + 3*u + 0]);
            cfh[32 + 3*u + 1][e] = (ushort)f2bf(sh.x * xr[32 + 3*u + 1]);
            cfh[32 + 3*u + 2][e] = (ushort)f2bf(sh.x * xr[32 + 3*u + 2]);
            cfh[56 + u][e] = (ushort)f2bf(
                CG_C * (xr[32+3*u]*sh.y + xr[32+3*u+1]*sh.z + xr[32+3*u+2]*sh.w));
        }
        shS[0][e] = sh.x;
        shS[1][e] = sh.y;  shS[2][e] = sh.z;  shS[3][e] = sh.w;
    }

    f32x4 d1[2][4];
    #pragma unroll
    for (int mt = 0; mt < 4; ++mt) {
        const float4 b1v = *reinterpret_cast<const float4*>(fc_b1 + mt*16 + 4*g);
        #pragma unroll
        for (int ms = 0; ms < 2; ++ms)
            d1[ms][mt] = (f32x4){b1v.x, b1v.y, b1v.z, b1v.w};
    }
    #pragma unroll
    for (int kh = 0; kh < 2; ++kh) {
        bf16x8 bfr[2];
        #pragma unroll
        for (int ms = 0; ms < 2; ++ms) {
            const int e = E0 + wave*32 + ms*16 + q;
            const float* ap = edge_attr + (size_t)e * 64 + kh*32 + g*8;
            float4 f0 = *reinterpret_cast<const float4*>(ap);
            float4 f1 = *reinterpret_cast<const float4*>(ap + 4);
            union { uint32_t u[4]; bf16x8 v; } cv;
            cv.u[0] = pack2(f0.x, f0.y); cv.u[1] = pack2(f0.z, f0.w);
            cv.u[2] = pack2(f1.x, f1.y); cv.u[3] = pack2(f1.z, f1.w);
            bfr[ms] = cv.v;
        }
        #pragma unroll
        for (int mt = 0; mt < 4; ++mt) {
            bf16x8 afr = *reinterpret_cast<const bf16x8*>(W1T + (mt*16 + q)*64 + kh*32 + g*8);
            #pragma unroll
            for (int ms = 0; ms < 2; ++ms)
                d1[ms][mt] = __builtin_amdgcn_mfma_f32_16x16x32_bf16(afr, bfr[ms], d1[ms][mt], 0, 0, 0);
        }
    }
    #pragma unroll
    for (int mt = 0; mt < 4; ++mt) {
        const int kg = 2*mt + (g >> 1);
        #pragma unroll
        for (int ms = 0; ms < 2; ++ms) {
            float v0 = fmaxf(d1[ms][mt][0], 0.f);
            float v1 = fmaxf(d1[ms][mt][1], 0.f);
            float v2 = fmaxf(d1[ms][mt][2], 0.f);
            float v3 = fmaxf(d1[ms][mt][3], 0.f);
            uint32_t* wp = reinterpret_cast<uint32_t*>(
                &pool[wave*2048 + ms*1024 + (kg*16 + q)*8 + 4*(g & 1)]);
            wp[0] = pack2(v0, v1);
            wp[1] = pack2(v2, v3);
        }
    }

    bf16x8 af[2][2];
    #pragma unroll
    for (int ms = 0; ms < 2; ++ms)
        #pragma unroll
        for (int kh = 0; kh < 2; ++kh)
            af[ms][kh] = *reinterpret_cast<const bf16x8*>(
                &pool[wave*2048 + ms*1024 + ((kh*4 + g)*16 + q)*8]);

    bf16x8 A0, A1, B0, B1, C0, C1, D0, D1;
    float  Ab, Bb, Cb, Db;
    auto load_slot = [&](int t, bf16x8& b0, bf16x8& b1, float& bb) {
        const ushort* p = W2F + (size_t)t * 1024 + lane * 8;
        b0 = *reinterpret_cast<const bf16x8*>(p);
        b1 = *reinterpret_cast<const bf16x8*>(p + 512);
        bb = fc_b2[t * 16 + q];
    };
    load_slot(0, A0, A1, Ab);
    load_slot(1, B0, B1, Bb);
    load_slot(2, C0, C1, Cb);
    load_slot(3, D0, D1, Db);

    __syncthreads();

    const int ebase = wave*32 + 4*g;
    f32x4 s0v[2];
    s0v[0] = *reinterpret_cast<const f32x4*>(&shS[0][ebase]);
    s0v[1] = *reinterpret_cast<const f32x4*>(&shS[0][ebase + 16]);

    float o0[2][2][4];
    float ttv[2][4];
    float o1v[2][4][3];
    #pragma unroll
    for (int ms = 0; ms < 2; ++ms) {
        #pragma unroll
        for (int r = 0; r < 4; ++r) {
            o0[ms][0][r] = 0.f; o0[ms][1][r] = 0.f; ttv[ms][r] = 0.f;
            o1v[ms][r][0] = 0.f; o1v[ms][r][1] = 0.f; o1v[ms][r][2] = 0.f;
        }
    }

    auto mfma2 = [&](const bf16x8& b0, const bf16x8& b1, float b2v, f32x4* accv) {
        #pragma unroll
        for (int ms = 0; ms < 2; ++ms) {
            f32x4 a = (f32x4){b2v, b2v, b2v, b2v};
            a = __builtin_amdgcn_mfma_f32_16x16x32_bf16(af[ms][0], b0, a, 0, 0, 0);
            a = __builtin_amdgcn_mfma_f32_16x16x32_bf16(af[ms][1], b1, a, 0, 0, 0);
            accv[ms] = a;
        }
    };

    const int qh = q >> 3;

    #pragma unroll 1
    for (int c = 0; c < 16; ++c) {
        const int t4 = 4*c;
        const int u0 = 2*c, u1 = 2*c + 1;
        f32x4 c00 = ld_cf4(&cfh[u0][ebase]);
        f32x4 c01 = ld_cf4(&cfh[u0][ebase + 16]);
        f32x4 c10 = ld_cf4(&cfh[u1][ebase]);
        f32x4 c11 = ld_cf4(&cfh[u1][ebase + 16]);
        f32x4 w2[2];

        mfma2(A0, A1, Ab, w2);  load_slot(t4 + 4, A0, A1, Ab);
        #pragma unroll
        for (int r = 0; r < 4; ++r) {
            o0[0][0][r] = fmaf(s0v[0][r]*c00[r], w2[0][r], o0[0][0][r]);
            o0[1][0][r] = fmaf(s0v[1][r]*c01[r], w2[1][r], o0[1][0][r]);
        }
        mfma2(B0, B1, Bb, w2);  load_slot(t4 + 5, B0, B1, Bb);
        #pragma unroll
        for (int r = 0; r < 4; ++r) {
            o0[0][1][r] = fmaf(s0v[0][r]*c00[r], w2[0][r], o0[0][1][r]);
            o0[1][1][r] = fmaf(s0v[1][r]*c01[r], w2[1][r], o0[1][1][r]);
        }
        mfma2(C0, C1, Cb, w2);  load_slot(t4 + 6, C0, C1, Cb);
        #pragma unroll
        for (int r = 0; r < 4; ++r) {
            o0[0][0][r] = fmaf(s0v[0][r]*c10[r], w2[0][r], o0[0][0][r]);
            o0[1][0][r] = fmaf(s0v[1][r]*c11[r], w2[1][r], o0[1][0][r]);
        }
        mfma2(D0, D1, Db, w2);  load_slot(t4 + 7, D0, D1, Db);
        #pragma unroll
        for (int r = 0; r < 4; ++r) {
            o0[0][1][r] = fmaf(s0v[0][r]*c10[r], w2[0][r], o0[0][1][r]);
            o0[1][1][r] = fmaf(s0v[1][r]*c11[r], w2[1][r], o0[1][1][r]);
        }
    }

    #pragma unroll 1
    for (int d = 0; d < 4; ++d) {
        const int t4 = 64 + 4*d;
        f32x4 w2[2];

        mfma2(A0, A1, Ab, w2);  load_slot(t4 + 4, A0, A1, Ab);
        {
            const int u = 8*d + qh;
            #pragma unroll
            for (int ms = 0; ms < 2; ++ms) {
                f32x4 cfv = ld_cf4(&cfh[u][ebase + ms*16]);
                #pragma unroll
                for (int r = 0; r < 4; ++r) ttv[ms][r] = fmaf(cfv[r], w2[ms][r], ttv[ms][r]);
            }
        }
        mfma2(B0, B1, Bb, w2);  load_slot(t4 + 5, B0, B1, Bb);
        {
            const int u = 8*d + 2 + qh;
            #pragma unroll
            for (int ms = 0; ms < 2; ++ms) {
                f32x4 cfv = ld_cf4(&cfh[u][ebase + ms*16]);
                #pragma unroll
                for (int r = 0; r < 4; ++r) ttv[ms][r] = fmaf(cfv[r], w2[ms][r], ttv[ms][r]);
            }
        }
        mfma2(C0, C1, Cb, w2);  load_slot(t4 + 6, C0, C1, Cb);
        {
            const int u = 8*d + 4 + qh;
            #pragma unroll
            for (int ms = 0; ms < 2; ++ms) {
                f32x4 cfv = ld_cf4(&cfh[u][ebase + ms*16]);
                #pragma unroll
                for (int r = 0; r < 4; ++r) ttv[ms][r] = fmaf(cfv[r], w2[ms][r], ttv[ms][r]);
            }
        }
        mfma2(D0, D1, Db, w2);  load_slot(t4 + 7, D0, D1, Db);
        {
            const int u = 8*d + 6 + qh;
            #pragma unroll
            for (int ms = 0; ms < 2; ++ms) {
                f32x4 cfv = ld_cf4(&cfh[u][ebase + ms*16]);
                #pragma unroll
                for (int r = 0; r < 4; ++r) ttv[ms][r] = fmaf(cfv[r], w2[ms][r], ttv[ms][r]);
            }
        }
    }

    {
        f32x4 w2[2];
        #define R3_BODY(TC)                                                         \
            {                                                                       \
                const int u = 2*(TC) + qh;                                          \
                _Pragma("unroll")                                                   \
                for (int ms = 0; ms < 2; ++ms)                                      \
                    _Pragma("unroll")                                               \
                    for (int m = 0; m < 3; ++m) {                                   \
                        f32x4 cfv = ld_cf4(&cfh[32 + u*3 + m][ebase + ms*16]);      \
                        _Pragma("unroll")                                           \
                        for (int r = 0; r < 4; ++r)                                 \
                            o1v[ms][r][m] = fmaf(cfv[r], w2[ms][r], o1v[ms][r][m]); \
                    }                                                               \
            }
        mfma2(A0, A1, Ab, w2);  load_slot(84, A0, A1, Ab);  R3_BODY(0)
        mfma2(B0, B1, Bb, w2);  load_slot(85, B0, B1, Bb);  R3_BODY(1)
        mfma2(C0, C1, Cb, w2);  load_slot(86, C0, C1, Cb);  R3_BODY(2)
        mfma2(D0, D1, Db, w2);  load_slot(87, D0, D1, Db);  R3_BODY(3)
        #undef R3_BODY
    }

    #pragma unroll 1
    for (int d = 0; d < 4; ++d) {
        const int t4 = 84 + 4*d;
        const int u0 = 2*d, u1 = 2*d + 1;
        f32x4 c00 = ld_cf4(&cfh[56 + u0][ebase]);
        f32x4 c01 = ld_cf4(&cfh[56 + u0][ebase + 16]);
        f32x4 c10 = ld_cf4(&cfh[56 + u1][ebase]);
        f32x4 c11 = ld_cf4(&cfh[56 + u1][ebase + 16]);
        f32x4 w2[2];
        int tn;

        mfma2(A0, A1, Ab, w2);  tn = t4 + 4; load_slot(tn < 100 ? tn : 99, A0, A1, Ab);
        #pragma unroll
        for (int r = 0; r < 4; ++r) {
            o0[0][0][r] = fmaf(c00[r], w2[0][r], o0[0][0][r]);
            o0[1][0][r] = fmaf(c01[r], w2[1][r], o0[1][0][r]);
        }
        mfma2(B0, B1, Bb, w2);  tn = t4 + 5; load_slot(tn < 100 ? tn : 99, B0, B1, Bb);
        #pragma unroll
        for (int r = 0; r < 4; ++r) {
            o0[0][1][r] = fmaf(c00[r], w2[0][r], o0[0][1][r]);
            o0[1][1][r] = fmaf(c01[r], w2[1][r], o0[1][1][r]);
        }
        mfma2(C0, C1, Cb, w2);  tn = t4 + 6; load_slot(tn < 100 ? tn : 99, C0, C1, Cb);
        #pragma unroll
        for (int r = 0; r < 4; ++r) {
            o0[0][0][r] = fmaf(c10[r], w2[0][r], o0[0][0][r]);
            o0[1][0][r] = fmaf(c11[r], w2[1][r], o0[1][0][r]);
        }
        mfma2(D0, D1, Db, w2);  tn = t4 + 7; load_slot(tn < 100 ? tn : 99, D0, D1, Db);
        #pragma unroll
        for (int r = 0; r < 4; ++r) {
            o0[0][1][r] = fmaf(c10[r], w2[0][r], o0[0][1][r]);
            o0[1][1][r] = fmaf(c11[r], w2[1][r], o0[1][1][r]);
        }
    }

    #pragma unroll
    for (int ms = 0; ms < 2; ++ms)
        #pragma unroll
        for (int r = 0; r < 4; ++r) {
            ttv[ms][r] += __shfl_xor(ttv[ms][r], 8, 64);
            #pragma unroll
            for (int m = 0; m < 3; ++m)
                o1v[ms][r][m] += __shfl_xor(o1v[ms][r][m], 8, 64);
        }

    #pragma unroll
    for (int ms = 0; ms < 2; ++ms) {
        const int eb = ebase + ms*16;
        const f32x4 s1x = *reinterpret_cast<const f32x4*>(&shS[1][eb]);
        const f32x4 s1y = *reinterpret_cast<const f32x4*>(&shS[2][eb]);
        const f32x4 s1z = *reinterpret_cast<const f32x4*>(&shS[3][eb]);
        #pragma unroll
        for (int r = 0; r < 4; ++r) {
            float* tp = tpbuf + (size_t)(E0 + eb + r) * IND;
            tp[q]      = PATH_NORM_C * o0[ms][0][r];
            tp[16 + q] = PATH_NORM_C * o0[ms][1][r];
            if ((q & 8) == 0) {
                const int v = q & 7;
                tp[32 + 3*v + 0] = PATH_NORM_C * (o1v[ms][r][0] + s1x[r]*ttv[ms][r]);
                tp[32 + 3*v + 1] = PATH_NORM_C * (o1v[ms][r][1] + s1y[r]*ttv[ms][r]);
                tp[32 + 3*v + 2] = PATH_NORM_C * (o1v[ms][r][2] + s1z[r]*ttv[ms][r]);
            }
        }
    }
}

// ---- gather: one wave per node, mean + residual ---------------------------
__global__ __launch_bounds__(256) void gather_kernel(
    const float* __restrict__ tpbuf, const int* __restrict__ cursor,
    const int* __restrict__ elist, const float* __restrict__ node_attr,
    float* __restrict__ out)
{
    const int node = blockIdx.x * 4 + (threadIdx.x >> 6);
    const int j = threadIdx.x & 63;
    if (node >= NN) return;
    const int degt = cursor[node];
    const int deg = (degt < DCAP) ? degt : DCAP;
    float sum = 0.f;
    #pragma unroll 4
    for (int i = 0; i < deg; ++i) {
        const int e = elist[node * DCAP + i];
        if (j < 56) sum += tpbuf[(size_t)e * IND + j];
    }
    if (j < 56) {
        const float c = (degt > 0) ? (float)degt : 1.f;
        out[node * IND + j] = sum / c + node_attr[node * IND + j];
    }
}

// ---- last-resort fallback: naive per-edge atomic kernel (fp32) -------------
__global__ __launch_bounds__(256) void finalize_fb_kernel(
    const float* __restrict__ acc, const float* __restrict__ cnt,
    const float* __restrict__ node_attr, float* __restrict__ out)
{
    const int i = blockIdx.x * 256 + threadIdx.x;
    if (i >= NN * IND) return;
    const int n = i / IND;
    const float c = fmaxf(cnt[n], 1.0f);
    out[i] = acc[i] / c + node_attr[i];
}

__global__ __launch_bounds__(256) void edge_fb_kernel(
    const float* __restrict__ node_attr, const float* __restrict__ edge_attr,
    const float* __restrict__ edge_sh, const float* __restrict__ fc_w1,
    const float* __restrict__ fc_b1, const float* __restrict__ fc_w2,
    const float* __restrict__ fc_b2, const int* __restrict__ edge_index,
    float* __restrict__ acc, float* __restrict__ cnt)
{
    const int idx = blockIdx.x * 256 + threadIdx.x;
    if (idx >= NE) return;
    const int e = idx;
    const int src = edge_index[e];
    const int dst = edge_index[NE + e];
    float h[64];
    #pragma unroll 1
    for (int k = 0; k < 64; ++k) {
        float s = fc_b1[k];
        for (int j = 0; j < 64; ++j) s += edge_attr[(size_t)e*64 + j] * fc_w1[j*64 + k];
        h[k] = fmaxf(s, 0.f);
    }
    const float4 sh = reinterpret_cast<const float4*>(edge_sh)[e];
    const float* x = node_attr + (size_t)dst * IND;
    float out0[32];
    #pragma unroll 1
    for (int v = 0; v < 32; ++v) out0[v] = 0.f;
    float tt[8], o1[24];
    #pragma unroll 1
    for (int v = 0; v < 8; ++v) tt[v] = 0.f;
    #pragma unroll 1
    for (int i = 0; i < 24; ++i) o1[i] = 0.f;
    #pragma unroll 1
    for (int u = 0; u < 32; ++u) {
        const float c1 = sh.x * x[u];
        for (int v = 0; v < 32; ++v) {
            float w = fc_b2[u*32 + v];
            for (int k = 0; k < 64; ++k) w += h[k] * fc_w2[k*WN + u*32 + v];
            out0[v] += c1 * w;
        }
        for (int v = 0; v < 8; ++v) {
            float w = fc_b2[1024 + u*8 + v];
            for (int k = 0; k < 64; ++k) w += h[k] * fc_w2[k*WN + 1024 + u*8 + v];
            tt[v] += x[u] * w;
        }
    }
    #pragma unroll 1
    for (int u = 0; u < 8; ++u) {
        const float y1 = CG_C * (x[32+3*u]*sh.y + x[32+3*u+1]*sh.z + x[32+3*u+2]*sh.w);
        for (int v = 0; v < 8; ++v) {
            float w = fc_b2[1280 + u*8 + v];
            for (int k = 0; k < 64; ++k) w += h[k] * fc_w2[k*WN + 1280 + u*8 + v];
            o1[3*v+0] += sh.x * w * x[32+3*u+0];
            o1[3*v+1] += sh.x * w * x[32+3*u+1];
            o1[3*v+2] += sh.x * w * x[32+3*u+2];
        }
        for (int v = 0; v < 32; ++v) {
            float w = fc_b2[1344 + u*32 + v];
            for (int k = 0; k < 64; ++k) w += h[k] * fc_w2[k*WN + 1344 + u*32 + v];
            out0[v] += y1 * w;
        }
    }
    float* ap = acc + (size_t)src * IND;
    for (int v = 0; v < 32; ++v) atomicAdd(ap + v, PATH_NORM_C * out0[v]);
    for (int v = 0; v < 8; ++v) {
        atomicAdd(ap + 32 + 3*v + 0, PATH_NORM_C * (o1[3*v+0] + sh.y * tt[v]));
        atomicAdd(ap + 32 + 3*v + 1, PATH_NORM_C * (o1[3*v+1] + sh.z * tt[v]));
        atomicAdd(ap + 32 + 3*v + 2, PATH_NORM_C * (o1[3*v+2] + sh.w * tt[v]));
    }
    atomicAdd(cnt + src, 1.0f);
}

extern "C" void kernel_launch(void* const* d_in, const int* in_sizes, int n_in,
                              void* d_out, int out_size, void* d_ws, size_t ws_size,
                              hipStream_t stream) {
    const float* node_attr = (const float*)d_in[0];
    const float* edge_attr = (const float*)d_in[1];
    const float* edge_sh   = (const float*)d_in[2];
    const float* fc_w1     = (const float*)d_in[3];
    const float* fc_b1     = (const float*)d_in[4];
    const float* fc_w2     = (const float*)d_in[5];
    const float* fc_b2     = (const float*)d_in[6];
    const int*   edge_index = (const int*)d_in[7];

    char* ws = (char*)d_ws;
    int*    cursor = (int*)(ws + 0);                  // 40,000
    int*    elist  = (int*)(ws + 40000);              // -> 2,600,000
    ushort* W1T    = (ushort*)(ws + 2600000);         // -> 2,608,192 (mono tier)
    ushort* W2F    = (ushort*)(ws + 2608192);         // -> 2,812,992
    float*  tpbuf  = (float*)(ws + 2812992);          // -> 38,652,992
    ushort* Hbuf   = (ushort*)(ws + 38652992);        // -> 59,132,992
    const size_t WS_SPLIT = 59132992ull;
    const size_t WS_MONO  = 38652992ull;

    if (ws_size >= WS_SPLIT) {
        hipMemsetAsync(cursor, 0, 40000, stream);
        front_kernel<<<NBLK, 256, 0, stream>>>(
            edge_attr, fc_w1, fc_b1, fc_w2, edge_index, W2F, cursor, elist, Hbuf);
        edge_kernel_split<<<NBLK, 256, 0, stream>>>(
            node_attr, edge_sh, fc_b2, edge_index, W2F, Hbuf, tpbuf);
        gather_kernel<<<(NN + 3) / 4, 256, 0, stream>>>(
            tpbuf, cursor, elist, node_attr, (float*)d_out);
    } else if (ws_size >= WS_MONO) {
        hipMemsetAsync(cursor, 0, 40000, stream);
        prep_kernel<<<(64*64 + 100*1024 + NE + 255) / 256, 256, 0, stream>>>(
            fc_w1, fc_w2, edge_index, W1T, W2F, cursor, elist, 1);
        edge_kernel_mono<<<NBLK, 256, 0, stream>>>(
            node_attr, edge_attr, edge_sh, fc_b1, fc_b2, edge_index, W1T, W2F, tpbuf);
        gather_kernel<<<(NN + 3) / 4, 256, 0, stream>>>(
            tpbuf, cursor, elist, node_attr, (float*)d_out);
    } else {
        float* acc = (float*)ws;                      // 2,240,000
        float* cnt = (float*)(ws + 2240000);          // -> 2,280,000
        hipMemsetAsync(ws, 0, 2280000, stream);
        edge_fb_kernel<<<(NE + 255) / 256, 256, 0, stream>>>(
            node_attr, edge_attr, edge_sh, fc_w1, fc_b1, fc_w2, fc_b2, edge_index, acc, cnt);
        finalize_fb_kernel<<<(NN * IND + 255) / 256, 256, 0, stream>>>(
            acc, cnt, node_attr, (float*)d_out);
    }
}

// Round 17
// 104.623 us; speedup vs baseline: 1.2325x; 1.0047x over previous
//
#include <hip/hip_runtime.h>

#define NN 10000
#define NE 160000
#define IND 56          // 32 + 3*8
#define WN 1600
#define EPB 128         // edges per block (4 waves x 32)
#define NBLK (NE / EPB) // 1250
#define DCAP 64         // max edges per source node bucket

typedef __attribute__((ext_vector_type(8))) short bf16x8;
typedef __attribute__((ext_vector_type(4))) float f32x4;

static constexpr float PATH_NORM_C = 0.15811388300841897f; // 1/sqrt(40)
static constexpr float CG_C        = 0.57735026918962576f; // 1/sqrt(3)

__device__ __forceinline__ uint32_t f2bf(float f) {
    uint32_t x = __float_as_uint(f);
    return (x + 0x7fffu + ((x >> 16) & 1u)) >> 16;   // RNE
}
__device__ __forceinline__ uint32_t pack2(float a, float b) {
    return f2bf(a) | (f2bf(b) << 16);
}
__device__ __forceinline__ f32x4 ld_cf4(const ushort* p) {
    uint2 w = *reinterpret_cast<const uint2*>(p);
    f32x4 v;
    v[0] = __uint_as_float(w.x << 16);
    v[1] = __uint_as_float(w.x & 0xffff0000u);
    v[2] = __uint_as_float(w.y << 16);
    v[3] = __uint_as_float(w.y & 0xffff0000u);
    return v;
}

// ==== front kernel: GEMM1 (W1 via LDS) + W2F conversion + elist fill ========
__global__ __launch_bounds__(256) void front_kernel(
    const float* __restrict__ edge_attr,
    const float* __restrict__ fc_w1,
    const float* __restrict__ fc_b1,
    const float* __restrict__ fc_w2,
    const int*   __restrict__ edge_index,
    ushort* __restrict__ W2F,
    int* __restrict__ cursor, int* __restrict__ elist,
    ushort* __restrict__ Hbuf)
{
    __shared__ ushort w1lds[64 * 66];   // [k][j], pitch 66 (bank-conflict-free)

    const int tid  = threadIdx.x;
    const int wave = tid >> 6;
    const int lane = tid & 63;
    const int g    = lane >> 4;
    const int q    = lane & 15;
    const int E0   = blockIdx.x * EPB;

    #pragma unroll
    for (int it = 0; it < 16; ++it) {
        const int idx = it * 256 + tid;
        const int j = idx >> 6, k = idx & 63;
        w1lds[k * 66 + j] = (ushort)f2bf(fc_w1[idx]);
    }
    __syncthreads();

    f32x4 d1[2][4];
    #pragma unroll
    for (int mt = 0; mt < 4; ++mt) {
        const float4 b1v = *reinterpret_cast<const float4*>(fc_b1 + mt*16 + 4*g);
        #pragma unroll
        for (int ms = 0; ms < 2; ++ms)
            d1[ms][mt] = (f32x4){b1v.x, b1v.y, b1v.z, b1v.w};
    }

    #pragma unroll
    for (int kh = 0; kh < 2; ++kh) {
        bf16x8 bfr[2];
        #pragma unroll
        for (int ms = 0; ms < 2; ++ms) {
            const int e = E0 + wave*32 + ms*16 + q;
            const float* ap = edge_attr + (size_t)e * 64 + kh*32 + g*8;
            float4 f0 = *reinterpret_cast<const float4*>(ap);
            float4 f1 = *reinterpret_cast<const float4*>(ap + 4);
            union { uint32_t u[4]; bf16x8 v; } cv;
            cv.u[0] = pack2(f0.x, f0.y); cv.u[1] = pack2(f0.z, f0.w);
            cv.u[2] = pack2(f1.x, f1.y); cv.u[3] = pack2(f1.z, f1.w);
            bfr[ms] = cv.v;
        }
        #pragma unroll
        for (int mt = 0; mt < 4; ++mt) {
            bf16x8 afr = *reinterpret_cast<const bf16x8*>(
                &w1lds[(mt*16 + q) * 66 + kh*32 + g*8]);
            #pragma unroll
            for (int ms = 0; ms < 2; ++ms)
                d1[ms][mt] = __builtin_amdgcn_mfma_f32_16x16x32_bf16(afr, bfr[ms], d1[ms][mt], 0, 0, 0);
        }
    }
    #pragma unroll
    for (int mt = 0; mt < 4; ++mt) {
        const int kg = 2*mt + (g >> 1);
        #pragma unroll
        for (int ms = 0; ms < 2; ++ms) {
            const int group = blockIdx.x*8 + wave*2 + ms;
            float v0 = fmaxf(d1[ms][mt][0], 0.f);
            float v1 = fmaxf(d1[ms][mt][1], 0.f);
            float v2 = fmaxf(d1[ms][mt][2], 0.f);
            float v3 = fmaxf(d1[ms][mt][3], 0.f);
            uint2 w;
            w.x = pack2(v0, v1);
            w.y = pack2(v2, v3);
            *reinterpret_cast<uint2*>(Hbuf + (size_t)group*1024 + (kg*16 + q)*8 + 4*(g & 1)) = w;
        }
    }

    const int gid = blockIdx.x * 256 + tid;
    if (gid < 100 * 1024) {
        int t  = gid >> 10, r = gid & 1023;
        int kh = r >> 9,  rr = r & 511;
        int l  = rr >> 3, ii = rr & 7;
        int j  = t * 16 + (l & 15);
        int k  = kh * 32 + ((l >> 4) << 3) + ii;
        W2F[gid] = (ushort)f2bf(fc_w2[k * WN + j]);
    } else {
        const int i3 = gid - 100 * 1024;
        if (i3 < NE) {
            int s = edge_index[i3];
            int pos = atomicAdd(&cursor[s], 1);
            if (pos < DCAP) elist[s * DCAP + pos] = i3;
        }
    }
}

// ---- pre-pass for mono tier ------------------------------------------------
__global__ __launch_bounds__(256) void prep_kernel(
    const float* __restrict__ fc_w1, const float* __restrict__ fc_w2,
    const int* __restrict__ edge_index,
    ushort* __restrict__ W1T, ushort* __restrict__ W2F,
    int* __restrict__ cursor, int* __restrict__ elist, int do_fill)
{
    int i = blockIdx.x * 256 + threadIdx.x;
    if (i < 64 * 64) {
        int k = i >> 6, j = i & 63;
        W1T[k * 64 + j] = (ushort)f2bf(fc_w1[j * 64 + k]);
    }
    int i2 = i - 64 * 64;
    if (i2 >= 0 && i2 < 100 * 1024) {
        int t  = i2 >> 10, r = i2 & 1023;
        int kh = r >> 9,  rr = r & 511;
        int l  = rr >> 3, ii = rr & 7;
        int j  = t * 16 + (l & 15);
        int k  = kh * 32 + ((l >> 4) << 3) + ii;
        W2F[i2] = (ushort)f2bf(fc_w2[k * WN + j]);
    }
    int i3 = i2 - 100 * 1024;
    if (i3 >= 0 && i3 < NE && do_fill) {
        int s = edge_index[i3];
        int pos = atomicAdd(&cursor[s], 1);
        if (pos < DCAP) elist[s * DCAP + pos] = i3;
    }
}

// ===== split edge kernel (R15 loop, bf16 tpbuf stores) ======================
__global__ __launch_bounds__(256) void edge_kernel_split(
    const float* __restrict__ node_attr,
    const float* __restrict__ edge_sh,
    const float* __restrict__ fc_b2,
    const int*   __restrict__ edge_index,
    const ushort* __restrict__ W2F,
    const ushort* __restrict__ Hbuf,
    ushort* __restrict__ tpbuf)
{
    __shared__ ushort cfh[64][EPB];                               // 16 KB
    __shared__ float  shS[4][EPB];                                //  2 KB

    const int tid  = threadIdx.x;
    const int wave = tid >> 6;
    const int lane = tid & 63;
    const int g    = lane >> 4;
    const int q    = lane & 15;
    const int E0   = blockIdx.x * EPB;

    if (tid < EPB) {
        const int e    = tid;
        const int dstn = edge_index[NE + E0 + e];
        const float4 sh = reinterpret_cast<const float4*>(edge_sh)[E0 + e];
        const float4* xp = reinterpret_cast<const float4*>(node_attr + (size_t)dstn * IND);
        float xr[56];
        #pragma unroll
        for (int i = 0; i < 14; ++i) {
            float4 v = xp[i];
            xr[4*i] = v.x; xr[4*i+1] = v.y; xr[4*i+2] = v.z; xr[4*i+3] = v.w;
        }
        #pragma unroll
        for (int u = 0; u < 32; ++u) cfh[u][e] = (ushort)f2bf(xr[u]);
        #pragma unroll
        for (int u = 0; u < 8; ++u) {
            cfh[32 + 3*u + 0][e] = (ushort)f2bf(sh.x * xr[32 + 3*u + 0]);
            cfh[32 + 3*u + 1][e] = (ushort)f2bf(sh.x * xr[32 + 3*u + 1]);
            cfh[32 + 3*u + 2][e] = (ushort)f2bf(sh.x * xr[32 + 3*u + 2]);
            cfh[56 + u][e] = (ushort)f2bf(
                CG_C * (xr[32+3*u]*sh.y + xr[32+3*u+1]*sh.z + xr[32+3*u+2]*sh.w));
        }
        shS[0][e] = sh.x;
        shS[1][e] = sh.y;  shS[2][e] = sh.z;  shS[3][e] = sh.w;
    }

    bf16x8 af[2][2];
    #pragma unroll
    for (int ms = 0; ms < 2; ++ms)
        #pragma unroll
        for (int kh = 0; kh < 2; ++kh)
            af[ms][kh] = *reinterpret_cast<const bf16x8*>(
                Hbuf + (size_t)(blockIdx.x*8 + wave*2 + ms)*1024 + kh*512 + g*128 + q*8);

    bf16x8 A0, A1, B0, B1, C0, C1, D0, D1;
    float  Ab, Bb, Cb, Db;
    auto load_slot = [&](int t, bf16x8& b0, bf16x8& b1, float& bb) {
        const ushort* p = W2F + (size_t)t * 1024 + lane * 8;
        b0 = *reinterpret_cast<const bf16x8*>(p);
        b1 = *reinterpret_cast<const bf16x8*>(p + 512);
        bb = fc_b2[t * 16 + q];
    };
    load_slot(0, A0, A1, Ab);
    load_slot(1, B0, B1, Bb);
    load_slot(2, C0, C1, Cb);
    load_slot(3, D0, D1, Db);

    __syncthreads();

    const int ebase = wave*32 + 4*g;
    f32x4 s0v[2];
    s0v[0] = *reinterpret_cast<const f32x4*>(&shS[0][ebase]);
    s0v[1] = *reinterpret_cast<const f32x4*>(&shS[0][ebase + 16]);

    float o0[2][2][4];
    float ttv[2][4];
    float o1v[2][4][3];
    #pragma unroll
    for (int ms = 0; ms < 2; ++ms) {
        #pragma unroll
        for (int r = 0; r < 4; ++r) {
            o0[ms][0][r] = 0.f; o0[ms][1][r] = 0.f; ttv[ms][r] = 0.f;
            o1v[ms][r][0] = 0.f; o1v[ms][r][1] = 0.f; o1v[ms][r][2] = 0.f;
        }
    }

    auto mfma2 = [&](const bf16x8& b0, const bf16x8& b1, float b2v, f32x4* accv) {
        #pragma unroll
        for (int ms = 0; ms < 2; ++ms) {
            f32x4 a = (f32x4){b2v, b2v, b2v, b2v};
            a = __builtin_amdgcn_mfma_f32_16x16x32_bf16(af[ms][0], b0, a, 0, 0, 0);
            a = __builtin_amdgcn_mfma_f32_16x16x32_bf16(af[ms][1], b1, a, 0, 0, 0);
            accv[ms] = a;
        }
    };

    const int qh = q >> 3;

    #pragma unroll 1
    for (int c = 0; c < 16; ++c) {
        const int t4 = 4*c;
        const int u0 = 2*c, u1 = 2*c + 1;
        f32x4 c00 = ld_cf4(&cfh[u0][ebase]);
        f32x4 c01 = ld_cf4(&cfh[u0][ebase + 16]);
        f32x4 c10 = ld_cf4(&cfh[u1][ebase]);
        f32x4 c11 = ld_cf4(&cfh[u1][ebase + 16]);
        f32x4 w2[2];

        mfma2(A0, A1, Ab, w2);  load_slot(t4 + 4, A0, A1, Ab);
        #pragma unroll
        for (int r = 0; r < 4; ++r) {
            o0[0][0][r] = fmaf(s0v[0][r]*c00[r], w2[0][r], o0[0][0][r]);
            o0[1][0][r] = fmaf(s0v[1][r]*c01[r], w2[1][r], o0[1][0][r]);
        }
        mfma2(B0, B1, Bb, w2);  load_slot(t4 + 5, B0, B1, Bb);
        #pragma unroll
        for (int r = 0; r < 4; ++r) {
            o0[0][1][r] = fmaf(s0v[0][r]*c00[r], w2[0][r], o0[0][1][r]);
            o0[1][1][r] = fmaf(s0v[1][r]*c01[r], w2[1][r], o0[1][1][r]);
        }
        mfma2(C0, C1, Cb, w2);  load_slot(t4 + 6, C0, C1, Cb);
        #pragma unroll
        for (int r = 0; r < 4; ++r) {
            o0[0][0][r] = fmaf(s0v[0][r]*c10[r], w2[0][r], o0[0][0][r]);
            o0[1][0][r] = fmaf(s0v[1][r]*c11[r], w2[1][r], o0[1][0][r]);
        }
        mfma2(D0, D1, Db, w2);  load_slot(t4 + 7, D0, D1, Db);
        #pragma unroll
        for (int r = 0; r < 4; ++r) {
            o0[0][1][r] = fmaf(s0v[0][r]*c10[r], w2[0][r], o0[0][1][r]);
            o0[1][1][r] = fmaf(s0v[1][r]*c11[r], w2[1][r], o0[1][1][r]);
        }
    }

    #pragma unroll 1
    for (int d = 0; d < 4; ++d) {
        const int t4 = 64 + 4*d;
        f32x4 w2[2];

        mfma2(A0, A1, Ab, w2);  load_slot(t4 + 4, A0, A1, Ab);
        {
            const int u = 8*d + qh;
            #pragma unroll
            for (int ms = 0; ms < 2; ++ms) {
                f32x4 cfv = ld_cf4(&cfh[u][ebase + ms*16]);
                #pragma unroll
                for (int r = 0; r < 4; ++r) ttv[ms][r] = fmaf(cfv[r], w2[ms][r], ttv[ms][r]);
            }
        }
        mfma2(B0, B1, Bb, w2);  load_slot(t4 + 5, B0, B1, Bb);
        {
            const int u = 8*d + 2 + qh;
            #pragma unroll
            for (int ms = 0; ms < 2; ++ms) {
                f32x4 cfv = ld_cf4(&cfh[u][ebase + ms*16]);
                #pragma unroll
                for (int r = 0; r < 4; ++r) ttv[ms][r] = fmaf(cfv[r], w2[ms][r], ttv[ms][r]);
            }
        }
        mfma2(C0, C1, Cb, w2);  load_slot(t4 + 6, C0, C1, Cb);
        {
            const int u = 8*d + 4 + qh;
            #pragma unroll
            for (int ms = 0; ms < 2; ++ms) {
                f32x4 cfv = ld_cf4(&cfh[u][ebase + ms*16]);
                #pragma unroll
                for (int r = 0; r < 4; ++r) ttv[ms][r] = fmaf(cfv[r], w2[ms][r], ttv[ms][r]);
            }
        }
        mfma2(D0, D1, Db, w2);  load_slot(t4 + 7, D0, D1, Db);
        {
            const int u = 8*d + 6 + qh;
            #pragma unroll
            for (int ms = 0; ms < 2; ++ms) {
                f32x4 cfv = ld_cf4(&cfh[u][ebase + ms*16]);
                #pragma unroll
                for (int r = 0; r < 4; ++r) ttv[ms][r] = fmaf(cfv[r], w2[ms][r], ttv[ms][r]);
            }
        }
    }

    {
        f32x4 w2[2];
        #define R3_BODY(TC)                                                         \
            {                                                                       \
                const int u = 2*(TC) + qh;                                          \
                _Pragma("unroll")                                                   \
                for (int ms = 0; ms < 2; ++ms)                                      \
                    _Pragma("unroll")                                               \
                    for (int m = 0; m < 3; ++m) {                                   \
                        f32x4 cfv = ld_cf4(&cfh[32 + u*3 + m][ebase + ms*16]);      \
                        _Pragma("unroll")                                           \
                        for (int r = 0; r < 4; ++r)                                 \
                            o1v[ms][r][m] = fmaf(cfv[r], w2[ms][r], o1v[ms][r][m]); \
                    }                                                               \
            }
        mfma2(A0, A1, Ab, w2);  load_slot(84, A0, A1, Ab);  R3_BODY(0)
        mfma2(B0, B1, Bb, w2);  load_slot(85, B0, B1, Bb);  R3_BODY(1)
        mfma2(C0, C1, Cb, w2);  load_slot(86, C0, C1, Cb);  R3_BODY(2)
        mfma2(D0, D1, Db, w2);  load_slot(87, D0, D1, Db);  R3_BODY(3)
        #undef R3_BODY
    }

    #pragma unroll 1
    for (int d = 0; d < 4; ++d) {
        const int t4 = 84 + 4*d;
        const int u0 = 2*d, u1 = 2*d + 1;
        f32x4 c00 = ld_cf4(&cfh[56 + u0][ebase]);
        f32x4 c01 = ld_cf4(&cfh[56 + u0][ebase + 16]);
        f32x4 c10 = ld_cf4(&cfh[56 + u1][ebase]);
        f32x4 c11 = ld_cf4(&cfh[56 + u1][ebase + 16]);
        f32x4 w2[2];
        int tn;

        mfma2(A0, A1, Ab, w2);  tn = t4 + 4; load_slot(tn < 100 ? tn : 99, A0, A1, Ab);
        #pragma unroll
        for (int r = 0; r < 4; ++r) {
            o0[0][0][r] = fmaf(c00[r], w2[0][r], o0[0][0][r]);
            o0[1][0][r] = fmaf(c01[r], w2[1][r], o0[1][0][r]);
        }
        mfma2(B0, B1, Bb, w2);  tn = t4 + 5; load_slot(tn < 100 ? tn : 99, B0, B1, Bb);
        #pragma unroll
        for (int r = 0; r < 4; ++r) {
            o0[0][1][r] = fmaf(c00[r], w2[0][r], o0[0][1][r]);
            o0[1][1][r] = fmaf(c01[r], w2[1][r], o0[1][1][r]);
        }
        mfma2(C0, C1, Cb, w2);  tn = t4 + 6; load_slot(tn < 100 ? tn : 99, C0, C1, Cb);
        #pragma unroll
        for (int r = 0; r < 4; ++r) {
            o0[0][0][r] = fmaf(c10[r], w2[0][r], o0[0][0][r]);
            o0[1][0][r] = fmaf(c11[r], w2[1][r], o0[1][0][r]);
        }
        mfma2(D0, D1, Db, w2);  tn = t4 + 7; load_slot(tn < 100 ? tn : 99, D0, D1, Db);
        #pragma unroll
        for (int r = 0; r < 4; ++r) {
            o0[0][1][r] = fmaf(c10[r], w2[0][r], o0[0][1][r]);
            o0[1][1][r] = fmaf(c11[r], w2[1][r], o0[1][1][r]);
        }
    }

    #pragma unroll
    for (int ms = 0; ms < 2; ++ms)
        #pragma unroll
        for (int r = 0; r < 4; ++r) {
            ttv[ms][r] += __shfl_xor(ttv[ms][r], 8, 64);
            #pragma unroll
            for (int m = 0; m < 3; ++m)
                o1v[ms][r][m] += __shfl_xor(o1v[ms][r][m], 8, 64);
        }

    #pragma unroll
    for (int ms = 0; ms < 2; ++ms) {
        const int eb = ebase + ms*16;
        const f32x4 s1x = *reinterpret_cast<const f32x4*>(&shS[1][eb]);
        const f32x4 s1y = *reinterpret_cast<const f32x4*>(&shS[2][eb]);
        const f32x4 s1z = *reinterpret_cast<const f32x4*>(&shS[3][eb]);
        #pragma unroll
        for (int r = 0; r < 4; ++r) {
            ushort* tp = tpbuf + (size_t)(E0 + eb + r) * IND;
            tp[q]      = (ushort)f2bf(PATH_NORM_C * o0[ms][0][r]);
            tp[16 + q] = (ushort)f2bf(PATH_NORM_C * o0[ms][1][r]);
            if ((q & 8) == 0) {
                const int v = q & 7;
                tp[32 + 3*v + 0] = (ushort)f2bf(PATH_NORM_C * (o1v[ms][r][0] + s1x[r]*ttv[ms][r]));
                tp[32 + 3*v + 1] = (ushort)f2bf(PATH_NORM_C * (o1v[ms][r][1] + s1y[r]*ttv[ms][r]));
                tp[32 + 3*v + 2] = (ushort)f2bf(PATH_NORM_C * (o1v[ms][r][2] + s1z[r]*ttv[ms][r]));
            }
        }
    }
}

// ===== mono edge kernel (R11 loop, bf16 tpbuf stores): middle tier ==========
__global__ __launch_bounds__(256, 3) void edge_kernel_mono(
    const float* __restrict__ node_attr,
    const float* __restrict__ edge_attr,
    const float* __restrict__ edge_sh,
    const float* __restrict__ fc_b1,
    const float* __restrict__ fc_b2,
    const int*   __restrict__ edge_index,
    const ushort* __restrict__ W1T,
    const ushort* __restrict__ W2F,
    ushort* __restrict__ tpbuf)
{
    __shared__ ushort cfh[64][EPB];
    __shared__ float  shS[4][EPB];
    __shared__ __attribute__((aligned(16))) ushort pool[8192];

    const int tid  = threadIdx.x;
    const int wave = tid >> 6;
    const int lane = tid & 63;
    const int g    = lane >> 4;
    const int q    = lane & 15;
    const int E0   = blockIdx.x * EPB;

    if (tid < EPB) {
        const int e    = tid;
        const int dstn = edge_index[NE + E0 + e];
        const float4 sh = reinterpret_cast<const float4*>(edge_sh)[E0 + e];
        const float4* xp = reinterpret_cast<const float4*>(node_attr + (size_t)dstn * IND);
        float xr[56];
        #pragma unroll
        for (int i = 0; i < 14; ++i) {
            float4 v = xp[i];
            xr[4*i] = v.x; xr[4*i+1] = v.y; xr[4*i+2] = v.z; xr[4*i+3] = v.w;
        }
        #pragma unroll
        for (int u = 0; u < 32; ++u) cfh[u][e] = (ushort)f2bf(xr[u]);
        #pragma unroll
        for (int u = 0; u < 8; ++u) {
            cfh[32 + 3*u + 0][e] = (ushort)f2bf(sh.x * xr[32 + 3*u + 0]);
            cfh[32 + 3*u + 1][e] = (ushort)f2bf(sh.x * xr[32 + 3*u + 1]);
            cfh[32 + 3*u + 2][e] = (ushort)f2bf(sh.x * xr[32 + 3*u + 2]);
            cfh[56 + u][e] = (ushort)f2bf(
                CG_C * (xr[32+3*u]*sh.y + xr[32+3*u+1]*sh.z + xr[32+3*u+2]*sh.w));
        }
        shS[0][e] = sh.x;
        shS[1][e] = sh.y;  shS[2][e] = sh.z;  shS[3][e] = sh.w;
    }

    f32x4 d1[2][4];
    #pragma unroll
    for (int mt = 0; mt < 4; ++mt) {
        const float4 b1v = *reinterpret_cast<const float4*>(fc_b1 + mt*16 + 4*g);
        #pragma unroll
        for (int ms = 0; ms < 2; ++ms)
            d1[ms][mt] = (f32x4){b1v.x, b1v.y, b1v.z, b1v.w};
    }
    #pragma unroll
    for (int kh = 0; kh < 2; ++kh) {
        bf16x8 bfr[2];
        #pragma unroll
        for (int ms = 0; ms < 2; ++ms) {
            const int e = E0 + wave*32 + ms*16 + q;
            const float* ap = edge_attr + (size_t)e * 64 + kh*32 + g*8;
            float4 f0 = *reinterpret_cast<const float4*>(ap);
            float4 f1 = *reinterpret_cast<const float4*>(ap + 4);
            union { uint32_t u[4]; bf16x8 v; } cv;
            cv.u[0] = pack2(f0.x, f0.y); cv.u[1] = pack2(f0.z, f0.w);
            cv.u[2] = pack2(f1.x, f1.y); cv.u[3] = pack2(f1.z, f1.w);
            bfr[ms] = cv.v;
        }
        #pragma unroll
        for (int mt = 0; mt < 4; ++mt) {
            bf16x8 afr = *reinterpret_cast<const bf16x8*>(W1T + (mt*16 + q)*64 + kh*32 + g*8);
            #pragma unroll
            for (int ms = 0; ms < 2; ++ms)
                d1[ms][mt] = __builtin_amdgcn_mfma_f32_16x16x32_bf16(afr, bfr[ms], d1[ms][mt], 0, 0, 0);
        }
    }
    #pragma unroll
    for (int mt = 0; mt < 4; ++mt) {
        const int kg = 2*mt + (g >> 1);
        #pragma unroll
        for (int ms = 0; ms < 2; ++ms) {
            float v0 = fmaxf(d1[ms][mt][0], 0.f);
            float v1 = fmaxf(d1[ms][mt][1], 0.f);
            float v2 = fmaxf(d1[ms][mt][2], 0.f);
            float v3 = fmaxf(d1[ms][mt][3], 0.f);
            uint32_t* wp = reinterpret_cast<uint32_t*>(
                &pool[wave*2048 + ms*1024 + (kg*16 + q)*8 + 4*(g & 1)]);
            wp[0] = pack2(v0, v1);
            wp[1] = pack2(v2, v3);
        }
    }

    bf16x8 af[2][2];
    #pragma unroll
    for (int ms = 0; ms < 2; ++ms)
        #pragma unroll
        for (int kh = 0; kh < 2; ++kh)
            af[ms][kh] = *reinterpret_cast<const bf16x8*>(
                &pool[wave*2048 + ms*1024 + ((kh*4 + g)*16 + q)*8]);

    bf16x8 A0, A1, B0, B1, C0, C1, D0, D1;
    float  Ab, Bb, Cb, Db;
    auto load_slot = [&](int t, bf16x8& b0, bf16x8& b1, float& bb) {
        const ushort* p = W2F + (size_t)t * 1024 + lane * 8;
        b0 = *reinterpret_cast<const bf16x8*>(p);
        b1 = *reinterpret_cast<const bf16x8*>(p + 512);
        bb = fc_b2[t * 16 + q];
    };
    load_slot(0, A0, A1, Ab);
    load_slot(1, B0, B1, Bb);
    load_slot(2, C0, C1, Cb);
    load_slot(3, D0, D1, Db);

    __syncthreads();

    const int ebase = wave*32 + 4*g;
    f32x4 s0v[2];
    s0v[0] = *reinterpret_cast<const f32x4*>(&shS[0][ebase]);
    s0v[1] = *reinterpret_cast<const f32x4*>(&shS[0][ebase + 16]);

    float o0[2][2][4];
    float ttv[2][4];
    float o1v[2][4][3];
    #pragma unroll
    for (int ms = 0; ms < 2; ++ms) {
        #pragma unroll
        for (int r = 0; r < 4; ++r) {
            o0[ms][0][r] = 0.f; o0[ms][1][r] = 0.f; ttv[ms][r] = 0.f;
            o1v[ms][r][0] = 0.f; o1v[ms][r][1] = 0.f; o1v[ms][r][2] = 0.f;
        }
    }

    auto mfma2 = [&](const bf16x8& b0, const bf16x8& b1, float b2v, f32x4* accv) {
        #pragma unroll
        for (int ms = 0; ms < 2; ++ms) {
            f32x4 a = (f32x4){b2v, b2v, b2v, b2v};
            a = __builtin_amdgcn_mfma_f32_16x16x32_bf16(af[ms][0], b0, a, 0, 0, 0);
            a = __builtin_amdgcn_mfma_f32_16x16x32_bf16(af[ms][1], b1, a, 0, 0, 0);
            accv[ms] = a;
        }
    };

    const int qh = q >> 3;

    #pragma unroll 1
    for (int c = 0; c < 16; ++c) {
        const int t4 = 4*c;
        const int u0 = 2*c, u1 = 2*c + 1;
        f32x4 c00 = ld_cf4(&cfh[u0][ebase]);
        f32x4 c01 = ld_cf4(&cfh[u0][ebase + 16]);
        f32x4 c10 = ld_cf4(&cfh[u1][ebase]);
        f32x4 c11 = ld_cf4(&cfh[u1][ebase + 16]);
        f32x4 w2[2];

        mfma2(A0, A1, Ab, w2);  load_slot(t4 + 4, A0, A1, Ab);
        #pragma unroll
        for (int r = 0; r < 4; ++r) {
            o0[0][0][r] = fmaf(s0v[0][r]*c00[r], w2[0][r], o0[0][0][r]);
            o0[1][0][r] = fmaf(s0v[1][r]*c01[r], w2[1][r], o0[1][0][r]);
        }
        mfma2(B0, B1, Bb, w2);  load_slot(t4 + 5, B0, B1, Bb);
        #pragma unroll
        for (int r = 0; r < 4; ++r) {
            o0[0][1][r] = fmaf(s0v[0][r]*c00[r], w2[0][r], o0[0][1][r]);
            o0[1][1][r] = fmaf(s0v[1][r]*c01[r], w2[1][r], o0[1][1][r]);
        }
        mfma2(C0, C1, Cb, w2);  load_slot(t4 + 6, C0, C1, Cb);
        #pragma unroll
        for (int r = 0; r < 4; ++r) {
            o0[0][0][r] = fmaf(s0v[0][r]*c10[r], w2[0][r], o0[0][0][r]);
            o0[1][0][r] = fmaf(s0v[1][r]*c11[r], w2[1][r], o0[1][0][r]);
        }
        mfma2(D0, D1, Db, w2);  load_slot(t4 + 7, D0, D1, Db);
        #pragma unroll
        for (int r = 0; r < 4; ++r) {
            o0[0][1][r] = fmaf(s0v[0][r]*c10[r], w2[0][r], o0[0][1][r]);
            o0[1][1][r] = fmaf(s0v[1][r]*c11[r], w2[1][r], o0[1][1][r]);
        }
    }

    #pragma unroll 1
    for (int d = 0; d < 4; ++d) {
        const int t4 = 64 + 4*d;
        f32x4 w2[2];

        mfma2(A0, A1, Ab, w2);  load_slot(t4 + 4, A0, A1, Ab);
        {
            const int u = 8*d + qh;
            #pragma unroll
            for (int ms = 0; ms < 2; ++ms) {
                f32x4 cfv = ld_cf4(&cfh[u][ebase + ms*16]);
                #pragma unroll
                for (int r = 0; r < 4; ++r) ttv[ms][r] = fmaf(cfv[r], w2[ms][r], ttv[ms][r]);
            }
        }
        mfma2(B0, B1, Bb, w2);  load_slot(t4 + 5, B0, B1, Bb);
        {
            const int u = 8*d + 2 + qh;
            #pragma unroll
            for (int ms = 0; ms < 2; ++ms) {
                f32x4 cfv = ld_cf4(&cfh[u][ebase + ms*16]);
                #pragma unroll
                for (int r = 0; r < 4; ++r) ttv[ms][r] = fmaf(cfv[r], w2[ms][r], ttv[ms][r]);
            }
        }
        mfma2(C0, C1, Cb, w2);  load_slot(t4 + 6, C0, C1, Cb);
        {
            const int u = 8*d + 4 + qh;
            #pragma unroll
            for (int ms = 0; ms < 2; ++ms) {
                f32x4 cfv = ld_cf4(&cfh[u][ebase + ms*16]);
                #pragma unroll
                for (int r = 0; r < 4; ++r) ttv[ms][r] = fmaf(cfv[r], w2[ms][r], ttv[ms][r]);
            }
        }
        mfma2(D0, D1, Db, w2);  load_slot(t4 + 7, D0, D1, Db);
        {
            const int u = 8*d + 6 + qh;
            #pragma unroll
            for (int ms = 0; ms < 2; ++ms) {
                f32x4 cfv = ld_cf4(&cfh[u][ebase + ms*16]);
                #pragma unroll
                for (int r = 0; r < 4; ++r) ttv[ms][r] = fmaf(cfv[r], w2[ms][r], ttv[ms][r]);
            }
        }
    }

    {
        f32x4 w2[2];
        #define R3_BODY(TC)                                                         \
            {                                                                       \
                const int u = 2*(TC) + qh;                                          \
                _Pragma("unroll")                                                   \
                for (int ms = 0; ms < 2; ++ms)                                      \
                    _Pragma("unroll")                                               \
                    for (int m = 0; m < 3; ++m) {                                   \
                        f32x4 cfv = ld_cf4(&cfh[32 + u*3 + m][ebase + ms*16]);      \
                        _Pragma("unroll")                                           \
                        for (int r = 0; r < 4; ++r)                                 \
                            o1v[ms][r][m] = fmaf(cfv[r], w2[ms][r], o1v[ms][r][m]); \
                    }                                                               \
            }
        mfma2(A0, A1, Ab, w2);  load_slot(84, A0, A1, Ab);  R3_BODY(0)
        mfma2(B0, B1, Bb, w2);  load_slot(85, B0, B1, Bb);  R3_BODY(1)
        mfma2(C0, C1, Cb, w2);  load_slot(86, C0, C1, Cb);  R3_BODY(2)
        mfma2(D0, D1, Db, w2);  load_slot(87, D0, D1, Db);  R3_BODY(3)
        #undef R3_BODY
    }

    #pragma unroll 1
    for (int d = 0; d < 4; ++d) {
        const int t4 = 84 + 4*d;
        const int u0 = 2*d, u1 = 2*d + 1;
        f32x4 c00 = ld_cf4(&cfh[56 + u0][ebase]);
        f32x4 c01 = ld_cf4(&cfh[56 + u0][ebase + 16]);
        f32x4 c10 = ld_cf4(&cfh[56 + u1][ebase]);
        f32x4 c11 = ld_cf4(&cfh[56 + u1][ebase + 16]);
        f32x4 w2[2];
        int tn;

        mfma2(A0, A1, Ab, w2);  tn = t4 + 4; load_slot(tn < 100 ? tn : 99, A0, A1, Ab);
        #pragma unroll
        for (int r = 0; r < 4; ++r) {
            o0[0][0][r] = fmaf(c00[r], w2[0][r], o0[0][0][r]);
            o0[1][0][r] = fmaf(c01[r], w2[1][r], o0[1][0][r]);
        }
        mfma2(B0, B1, Bb, w2);  tn = t4 + 5; load_slot(tn < 100 ? tn : 99, B0, B1, Bb);
        #pragma unroll
        for (int r = 0; r < 4; ++r) {
            o0[0][1][r] = fmaf(c00[r], w2[0][r], o0[0][1][r]);
            o0[1][1][r] = fmaf(c01[r], w2[1][r], o0[1][1][r]);
        }
        mfma2(C0, C1, Cb, w2);  tn = t4 + 6; load_slot(tn < 100 ? tn : 99, C0, C1, Cb);
        #pragma unroll
        for (int r = 0; r < 4; ++r) {
            o0[0][0][r] = fmaf(c10[r], w2[0][r], o0[0][0][r]);
            o0[1][0][r] = fmaf(c11[r], w2[1][r], o0[1][0][r]);
        }
        mfma2(D0, D1, Db, w2);  tn = t4 + 7; load_slot(tn < 100 ? tn : 99, D0, D1, Db);
        #pragma unroll
        for (int r = 0; r < 4; ++r) {
            o0[0][1][r] = fmaf(c10[r], w2[0][r], o0[0][1][r]);
            o0[1][1][r] = fmaf(c11[r], w2[1][r], o0[1][1][r]);
        }
    }

    #pragma unroll
    for (int ms = 0; ms < 2; ++ms)
        #pragma unroll
        for (int r = 0; r < 4; ++r) {
            ttv[ms][r] += __shfl_xor(ttv[ms][r], 8, 64);
            #pragma unroll
            for (int m = 0; m < 3; ++m)
                o1v[ms][r][m] += __shfl_xor(o1v[ms][r][m], 8, 64);
        }

    #pragma unroll
    for (int ms = 0; ms < 2; ++ms) {
        const int eb = ebase + ms*16;
        const f32x4 s1x = *reinterpret_cast<const f32x4*>(&shS[1][eb]);
        const f32x4 s1y = *reinterpret_cast<const f32x4*>(&shS[2][eb]);
        const f32x4 s1z = *reinterpret_cast<const f32x4*>(&shS[3][eb]);
        #pragma unroll
        for (int r = 0; r < 4; ++r) {
            ushort* tp = tpbuf + (size_t)(E0 + eb + r) * IND;
            tp[q]      = (ushort)f2bf(PATH_NORM_C * o0[ms][0][r]);
            tp[16 + q] = (ushort)f2bf(PATH_NORM_C * o0[ms][1][r]);
            if ((q & 8) == 0) {
                const int v = q & 7;
                tp[32 + 3*v + 0] = (ushort)f2bf(PATH_NORM_C * (o1v[ms][r][0] + s1x[r]*ttv[ms][r]));
                tp[32 + 3*v + 1] = (ushort)f2bf(PATH_NORM_C * (o1v[ms][r][1] + s1y[r]*ttv[ms][r]));
                tp[32 + 3*v + 2] = (ushort)f2bf(PATH_NORM_C * (o1v[ms][r][2] + s1z[r]*ttv[ms][r]));
            }
        }
    }
}

// ---- gather: one wave per node, mean + residual (bf16 tpbuf) ---------------
__global__ __launch_bounds__(256) void gather_kernel(
    const ushort* __restrict__ tpbuf, const int* __restrict__ cursor,
    const int* __restrict__ elist, const float* __restrict__ node_attr,
    float* __restrict__ out)
{
    const int node = blockIdx.x * 4 + (threadIdx.x >> 6);
    const int j = threadIdx.x & 63;
    if (node >= NN) return;
    const int degt = cursor[node];
    const int deg = (degt < DCAP) ? degt : DCAP;
    float sum = 0.f;
    #pragma unroll 4
    for (int i = 0; i < deg; ++i) {
        const int e = elist[node * DCAP + i];
        if (j < 56) sum += __uint_as_float((uint32_t)tpbuf[(size_t)e * IND + j] << 16);
    }
    if (j < 56) {
        const float c = (degt > 0) ? (float)degt : 1.f;
        out[node * IND + j] = sum / c + node_attr[node * IND + j];
    }
}

// ---- last-resort fallback: naive per-edge atomic kernel (fp32) -------------
__global__ __launch_bounds__(256) void finalize_fb_kernel(
    const float* __restrict__ acc, const float* __restrict__ cnt,
    const float* __restrict__ node_attr, float* __restrict__ out)
{
    const int i = blockIdx.x * 256 + threadIdx.x;
    if (i >= NN * IND) return;
    const int n = i / IND;
    const float c = fmaxf(cnt[n], 1.0f);
    out[i] = acc[i] / c + node_attr[i];
}

__global__ __launch_bounds__(256) void edge_fb_kernel(
    const float* __restrict__ node_attr, const float* __restrict__ edge_attr,
    const float* __restrict__ edge_sh, const float* __restrict__ fc_w1,
    const float* __restrict__ fc_b1, const float* __restrict__ fc_w2,
    const float* __restrict__ fc_b2, const int* __restrict__ edge_index,
    float* __restrict__ acc, float* __restrict__ cnt)
{
    const int idx = blockIdx.x * 256 + threadIdx.x;
    if (idx >= NE) return;
    const int e = idx;
    const int src = edge_index[e];
    const int dst = edge_index[NE + e];
    float h[64];
    #pragma unroll 1
    for (int k = 0; k < 64; ++k) {
        float s = fc_b1[k];
        for (int j = 0; j < 64; ++j) s += edge_attr[(size_t)e*64 + j] * fc_w1[j*64 + k];
        h[k] = fmaxf(s, 0.f);
    }
    const float4 sh = reinterpret_cast<const float4*>(edge_sh)[e];
    const float* x = node_attr + (size_t)dst * IND;
    float out0[32];
    #pragma unroll 1
    for (int v = 0; v < 32; ++v) out0[v] = 0.f;
    float tt[8], o1[24];
    #pragma unroll 1
    for (int v = 0; v < 8; ++v) tt[v] = 0.f;
    #pragma unroll 1
    for (int i = 0; i < 24; ++i) o1[i] = 0.f;
    #pragma unroll 1
    for (int u = 0; u < 32; ++u) {
        const float c1 = sh.x * x[u];
        for (int v = 0; v < 32; ++v) {
            float w = fc_b2[u*32 + v];
            for (int k = 0; k < 64; ++k) w += h[k] * fc_w2[k*WN + u*32 + v];
            out0[v] += c1 * w;
        }
        for (int v = 0; v < 8; ++v) {
            float w = fc_b2[1024 + u*8 + v];
            for (int k = 0; k < 64; ++k) w += h[k] * fc_w2[k*WN + 1024 + u*8 + v];
            tt[v] += x[u] * w;
        }
    }
    #pragma unroll 1
    for (int u = 0; u < 8; ++u) {
        const float y1 = CG_C * (x[32+3*u]*sh.y + x[32+3*u+1]*sh.z + x[32+3*u+2]*sh.w);
        for (int v = 0; v < 8; ++v) {
            float w = fc_b2[1280 + u*8 + v];
            for (int k = 0; k < 64; ++k) w += h[k] * fc_w2[k*WN + 1280 + u*8 + v];
            o1[3*v+0] += sh.x * w * x[32+3*u+0];
            o1[3*v+1] += sh.x * w * x[32+3*u+1];
            o1[3*v+2] += sh.x * w * x[32+3*u+2];
        }
        for (int v = 0; v < 32; ++v) {
            float w = fc_b2[1344 + u*32 + v];
            for (int k = 0; k < 64; ++k) w += h[k] * fc_w2[k*WN + 1344 + u*32 + v];
            out0[v] += y1 * w;
        }
    }
    float* ap = acc + (size_t)src * IND;
    for (int v = 0; v < 32; ++v) atomicAdd(ap + v, PATH_NORM_C * out0[v]);
    for (int v = 0; v < 8; ++v) {
        atomicAdd(ap + 32 + 3*v + 0, PATH_NORM_C * (o1[3*v+0] + sh.y * tt[v]));
        atomicAdd(ap + 32 + 3*v + 1, PATH_NORM_C * (o1[3*v+1] + sh.z * tt[v]));
        atomicAdd(ap + 32 + 3*v + 2, PATH_NORM_C * (o1[3*v+2] + sh.w * tt[v]));
    }
    atomicAdd(cnt + src, 1.0f);
}

extern "C" void kernel_launch(void* const* d_in, const int* in_sizes, int n_in,
                              void* d_out, int out_size, void* d_ws, size_t ws_size,
                              hipStream_t stream) {
    const float* node_attr = (const float*)d_in[0];
    const float* edge_attr = (const float*)d_in[1];
    const float* edge_sh   = (const float*)d_in[2];
    const float* fc_w1     = (const float*)d_in[3];
    const float* fc_b1     = (const float*)d_in[4];
    const float* fc_w2     = (const float*)d_in[5];
    const float* fc_b2     = (const float*)d_in[6];
    const int*   edge_index = (const int*)d_in[7];

    char* ws = (char*)d_ws;
    int*    cursor = (int*)(ws + 0);                  // 40,000
    int*    elist  = (int*)(ws + 40000);              // -> 2,600,000
    ushort* W1T    = (ushort*)(ws + 2600000);         // -> 2,608,192 (mono tier)
    ushort* W2F    = (ushort*)(ws + 2608192);         // -> 2,812,992
    ushort* tpbuf  = (ushort*)(ws + 2812992);         // 17,920,000 -> 20,732,992
    ushort* Hbuf   = (ushort*)(ws + 20732992);        // 20,480,000 -> 41,212,992
    const size_t WS_SPLIT = 41212992ull;
    const size_t WS_MONO  = 20732992ull;

    if (ws_size >= WS_SPLIT) {
        hipMemsetAsync(cursor, 0, 40000, stream);
        front_kernel<<<NBLK, 256, 0, stream>>>(
            edge_attr, fc_w1, fc_b1, fc_w2, edge_index, W2F, cursor, elist, Hbuf);
        edge_kernel_split<<<NBLK, 256, 0, stream>>>(
            node_attr, edge_sh, fc_b2, edge_index, W2F, Hbuf, tpbuf);
        gather_kernel<<<(NN + 3) / 4, 256, 0, stream>>>(
            tpbuf, cursor, elist, node_attr, (float*)d_out);
    } else if (ws_size >= WS_MONO) {
        hipMemsetAsync(cursor, 0, 40000, stream);
        prep_kernel<<<(64*64 + 100*1024 + NE + 255) / 256, 256, 0, stream>>>(
            fc_w1, fc_w2, edge_index, W1T, W2F, cursor, elist, 1);
        edge_kernel_mono<<<NBLK, 256, 0, stream>>>(
            node_attr, edge_attr, edge_sh, fc_b1, fc_b2, edge_index, W1T, W2F, tpbuf);
        gather_kernel<<<(NN + 3) / 4, 256, 0, stream>>>(
            tpbuf, cursor, elist, node_attr, (float*)d_out);
    } else {
        float* acc = (float*)ws;                      // 2,240,000
        float* cnt = (float*)(ws + 2240000);          // -> 2,280,000
        hipMemsetAsync(ws, 0, 2280000, stream);
        edge_fb_kernel<<<(NE + 255) / 256, 256, 0, stream>>>(
            node_attr, edge_attr, edge_sh, fc_w1, fc_b1, fc_w2, fc_b2, edge_index, acc, cnt);
        finalize_fb_kernel<<<(NN * IND + 255) / 256, 256, 0, stream>>>(
            acc, cnt, node_attr, (float*)d_out);
    }
}

// Round 19
// 103.632 us; speedup vs baseline: 1.2443x; 1.0096x over previous
//
#include <hip/hip_runtime.h>

#define NN 10000
#define NE 160000
#define IND 56          // 32 + 3*8
#define WN 1600
#define EPB 128         // edges per block (4 waves x 32)
#define NBLK (NE / EPB) // 1250
#define DCAP 64         // max edges per source node bucket

typedef __attribute__((ext_vector_type(8))) short bf16x8;
typedef __attribute__((ext_vector_type(4))) float f32x4;

static constexpr float PATH_NORM_C = 0.15811388300841897f; // 1/sqrt(40)
static constexpr float CG_C        = 0.57735026918962576f; // 1/sqrt(3)

__device__ __forceinline__ uint32_t f2bf(float f) {
    uint32_t x = __float_as_uint(f);
    return (x + 0x7fffu + ((x >> 16) & 1u)) >> 16;   // RNE
}
__device__ __forceinline__ uint32_t pack2(float a, float b) {
    return f2bf(a) | (f2bf(b) << 16);
}
__device__ __forceinline__ f32x4 ld_cf4(const ushort* p) {
    uint2 w = *reinterpret_cast<const uint2*>(p);
    f32x4 v;
    v[0] = __uint_as_float(w.x << 16);
    v[1] = __uint_as_float(w.x & 0xffff0000u);
    v[2] = __uint_as_float(w.y << 16);
    v[3] = __uint_as_float(w.y & 0xffff0000u);
    return v;
}

// ==== front kernel: GEMM1 (W1 via LDS) + W2F conversion + elist fill ========
__global__ __launch_bounds__(256) void front_kernel(
    const float* __restrict__ edge_attr,
    const float* __restrict__ fc_w1,
    const float* __restrict__ fc_b1,
    const float* __restrict__ fc_w2,
    const int*   __restrict__ edge_index,
    ushort* __restrict__ W2F,
    int* __restrict__ cursor, int* __restrict__ elist,
    ushort* __restrict__ Hbuf)
{
    __shared__ ushort w1lds[64 * 66];

    const int tid  = threadIdx.x;
    const int wave = tid >> 6;
    const int lane = tid & 63;
    const int g    = lane >> 4;
    const int q    = lane & 15;
    const int E0   = blockIdx.x * EPB;

    #pragma unroll
    for (int it = 0; it < 16; ++it) {
        const int idx = it * 256 + tid;
        const int j = idx >> 6, k = idx & 63;
        w1lds[k * 66 + j] = (ushort)f2bf(fc_w1[idx]);
    }
    __syncthreads();

    f32x4 d1[2][4];
    #pragma unroll
    for (int mt = 0; mt < 4; ++mt) {
        const float4 b1v = *reinterpret_cast<const float4*>(fc_b1 + mt*16 + 4*g);
        #pragma unroll
        for (int ms = 0; ms < 2; ++ms)
            d1[ms][mt] = (f32x4){b1v.x, b1v.y, b1v.z, b1v.w};
    }

    #pragma unroll
    for (int kh = 0; kh < 2; ++kh) {
        bf16x8 bfr[2];
        #pragma unroll
        for (int ms = 0; ms < 2; ++ms) {
            const int e = E0 + wave*32 + ms*16 + q;
            const float* ap = edge_attr + (size_t)e * 64 + kh*32 + g*8;
            float4 f0 = *reinterpret_cast<const float4*>(ap);
            float4 f1 = *reinterpret_cast<const float4*>(ap + 4);
            union { uint32_t u[4]; bf16x8 v; } cv;
            cv.u[0] = pack2(f0.x, f0.y); cv.u[1] = pack2(f0.z, f0.w);
            cv.u[2] = pack2(f1.x, f1.y); cv.u[3] = pack2(f1.z, f1.w);
            bfr[ms] = cv.v;
        }
        #pragma unroll
        for (int mt = 0; mt < 4; ++mt) {
            bf16x8 afr = *reinterpret_cast<const bf16x8*>(
                &w1lds[(mt*16 + q) * 66 + kh*32 + g*8]);
            #pragma unroll
            for (int ms = 0; ms < 2; ++ms)
                d1[ms][mt] = __builtin_amdgcn_mfma_f32_16x16x32_bf16(afr, bfr[ms], d1[ms][mt], 0, 0, 0);
        }
    }
    #pragma unroll
    for (int mt = 0; mt < 4; ++mt) {
        const int kg = 2*mt + (g >> 1);
        #pragma unroll
        for (int ms = 0; ms < 2; ++ms) {
            const int group = blockIdx.x*8 + wave*2 + ms;
            float v0 = fmaxf(d1[ms][mt][0], 0.f);
            float v1 = fmaxf(d1[ms][mt][1], 0.f);
            float v2 = fmaxf(d1[ms][mt][2], 0.f);
            float v3 = fmaxf(d1[ms][mt][3], 0.f);
            uint2 w;
            w.x = pack2(v0, v1);
            w.y = pack2(v2, v3);
            *reinterpret_cast<uint2*>(Hbuf + (size_t)group*1024 + (kg*16 + q)*8 + 4*(g & 1)) = w;
        }
    }

    const int gid = blockIdx.x * 256 + tid;
    if (gid < 100 * 1024) {
        int t  = gid >> 10, r = gid & 1023;
        int kh = r >> 9,  rr = r & 511;
        int l  = rr >> 3, ii = rr & 7;
        int j  = t * 16 + (l & 15);
        int k  = kh * 32 + ((l >> 4) << 3) + ii;
        W2F[gid] = (ushort)f2bf(fc_w2[k * WN + j]);
    } else {
        const int i3 = gid - 100 * 1024;
        if (i3 < NE) {
            int s = edge_index[i3];
            int pos = atomicAdd(&cursor[s], 1);
            if (pos < DCAP) elist[s * DCAP + pos] = i3;
        }
    }
}

// ---- pre-pass for mono tier ------------------------------------------------
__global__ __launch_bounds__(256) void prep_kernel(
    const float* __restrict__ fc_w1, const float* __restrict__ fc_w2,
    const int* __restrict__ edge_index,
    ushort* __restrict__ W1T, ushort* __restrict__ W2F,
    int* __restrict__ cursor, int* __restrict__ elist, int do_fill)
{
    int i = blockIdx.x * 256 + threadIdx.x;
    if (i < 64 * 64) {
        int k = i >> 6, j = i & 63;
        W1T[k * 64 + j] = (ushort)f2bf(fc_w1[j * 64 + k]);
    }
    int i2 = i - 64 * 64;
    if (i2 >= 0 && i2 < 100 * 1024) {
        int t  = i2 >> 10, r = i2 & 1023;
        int kh = r >> 9,  rr = r & 511;
        int l  = rr >> 3, ii = rr & 7;
        int j  = t * 16 + (l & 15);
        int k  = kh * 32 + ((l >> 4) << 3) + ii;
        W2F[i2] = (ushort)f2bf(fc_w2[k * WN + j]);
    }
    int i3 = i2 - 100 * 1024;
    if (i3 >= 0 && i3 < NE && do_fill) {
        int s = edge_index[i3];
        int pos = atomicAdd(&cursor[s], 1);
        if (pos < DCAP) elist[s * DCAP + pos] = i3;
    }
}

// ===== split edge kernel (R17 math, fc_b2 in LDS) ===========================
__global__ __launch_bounds__(256) void edge_kernel_split(
    const float* __restrict__ node_attr,
    const float* __restrict__ edge_sh,
    const float* __restrict__ fc_b2,
    const int*   __restrict__ edge_index,
    const ushort* __restrict__ W2F,
    const ushort* __restrict__ Hbuf,
    ushort* __restrict__ tpbuf)
{
    __shared__ ushort cfh[64][EPB];                               // 16 KB
    __shared__ float  shS[4][EPB];                                //  2 KB
    __shared__ float  b2lds[WN];                                  // 6.4 KB

    const int tid  = threadIdx.x;
    const int wave = tid >> 6;
    const int lane = tid & 63;
    const int g    = lane >> 4;
    const int q    = lane & 15;
    const int E0   = blockIdx.x * EPB;

    // coop fc_b2 -> LDS (exact copy)
    #pragma unroll
    for (int it = 0; it < 7; ++it) {
        const int idx = it * 256 + tid;
        if (idx < WN) b2lds[idx] = fc_b2[idx];
    }

    if (tid < EPB) {
        const int e    = tid;
        const int dstn = edge_index[NE + E0 + e];
        const float4 sh = reinterpret_cast<const float4*>(edge_sh)[E0 + e];
        const float4* xp = reinterpret_cast<const float4*>(node_attr + (size_t)dstn * IND);
        float xr[56];
        #pragma unroll
        for (int i = 0; i < 14; ++i) {
            float4 v = xp[i];
            xr[4*i] = v.x; xr[4*i+1] = v.y; xr[4*i+2] = v.z; xr[4*i+3] = v.w;
        }
        #pragma unroll
        for (int u = 0; u < 32; ++u) cfh[u][e] = (ushort)f2bf(xr[u]);
        #pragma unroll
        for (int u = 0; u < 8; ++u) {
            cfh[32 + 3*u + 0][e] = (ushort)f2bf(sh.x * xr[32 + 3*u + 0]);
            cfh[32 + 3*u + 1][e] = (ushort)f2bf(sh.x * xr[32 + 3*u + 1]);
            cfh[32 + 3*u + 2][e] = (ushort)f2bf(sh.x * xr[32 + 3*u + 2]);
            cfh[56 + u][e] = (ushort)f2bf(
                CG_C * (xr[32+3*u]*sh.y + xr[32+3*u+1]*sh.z + xr[32+3*u+2]*sh.w));
        }
        shS[0][e] = sh.x;
        shS[1][e] = sh.y;  shS[2][e] = sh.z;  shS[3][e] = sh.w;
    }

    __syncthreads();   // cfh/shS/b2lds visible

    bf16x8 af[2][2];
    #pragma unroll
    for (int ms = 0; ms < 2; ++ms)
        #pragma unroll
        for (int kh = 0; kh < 2; ++kh)
            af[ms][kh] = *reinterpret_cast<const bf16x8*>(
                Hbuf + (size_t)(blockIdx.x*8 + wave*2 + ms)*1024 + kh*512 + g*128 + q*8);

    bf16x8 A0, A1, B0, B1, C0, C1, D0, D1;
    float  Ab, Bb, Cb, Db;
    auto load_slot = [&](int t, bf16x8& b0, bf16x8& b1, float& bb) {
        const ushort* p = W2F + (size_t)t * 1024 + lane * 8;
        b0 = *reinterpret_cast<const bf16x8*>(p);
        b1 = *reinterpret_cast<const bf16x8*>(p + 512);
        bb = b2lds[t * 16 + q];
    };
    load_slot(0, A0, A1, Ab);
    load_slot(1, B0, B1, Bb);
    load_slot(2, C0, C1, Cb);
    load_slot(3, D0, D1, Db);

    const int ebase = wave*32 + 4*g;
    f32x4 s0v[2];
    s0v[0] = *reinterpret_cast<const f32x4*>(&shS[0][ebase]);
    s0v[1] = *reinterpret_cast<const f32x4*>(&shS[0][ebase + 16]);

    float o0[2][2][4];
    float ttv[2][4];
    float o1v[2][4][3];
    #pragma unroll
    for (int ms = 0; ms < 2; ++ms) {
        #pragma unroll
        for (int r = 0; r < 4; ++r) {
            o0[ms][0][r] = 0.f; o0[ms][1][r] = 0.f; ttv[ms][r] = 0.f;
            o1v[ms][r][0] = 0.f; o1v[ms][r][1] = 0.f; o1v[ms][r][2] = 0.f;
        }
    }

    auto mfma2 = [&](const bf16x8& b0, const bf16x8& b1, float b2v, f32x4* accv) {
        #pragma unroll
        for (int ms = 0; ms < 2; ++ms) {
            f32x4 a = (f32x4){b2v, b2v, b2v, b2v};
            a = __builtin_amdgcn_mfma_f32_16x16x32_bf16(af[ms][0], b0, a, 0, 0, 0);
            a = __builtin_amdgcn_mfma_f32_16x16x32_bf16(af[ms][1], b1, a, 0, 0, 0);
            accv[ms] = a;
        }
    };

    const int qh = q >> 3;

    // ---- region 1: tiles 0..63, coef s0*x0[u] (fp32 s0 multiply) ------------
    #pragma unroll 1
    for (int c = 0; c < 16; ++c) {
        const int t4 = 4*c;
        const int u0 = 2*c, u1 = 2*c + 1;
        f32x4 c00 = ld_cf4(&cfh[u0][ebase]);
        f32x4 c01 = ld_cf4(&cfh[u0][ebase + 16]);
        f32x4 c10 = ld_cf4(&cfh[u1][ebase]);
        f32x4 c11 = ld_cf4(&cfh[u1][ebase + 16]);
        f32x4 w2[2];

        mfma2(A0, A1, Ab, w2);  load_slot(t4 + 4, A0, A1, Ab);
        #pragma unroll
        for (int r = 0; r < 4; ++r) {
            o0[0][0][r] = fmaf(s0v[0][r]*c00[r], w2[0][r], o0[0][0][r]);
            o0[1][0][r] = fmaf(s0v[1][r]*c01[r], w2[1][r], o0[1][0][r]);
        }
        mfma2(B0, B1, Bb, w2);  load_slot(t4 + 5, B0, B1, Bb);
        #pragma unroll
        for (int r = 0; r < 4; ++r) {
            o0[0][1][r] = fmaf(s0v[0][r]*c00[r], w2[0][r], o0[0][1][r]);
            o0[1][1][r] = fmaf(s0v[1][r]*c01[r], w2[1][r], o0[1][1][r]);
        }
        mfma2(C0, C1, Cb, w2);  load_slot(t4 + 6, C0, C1, Cb);
        #pragma unroll
        for (int r = 0; r < 4; ++r) {
            o0[0][0][r] = fmaf(s0v[0][r]*c10[r], w2[0][r], o0[0][0][r]);
            o0[1][0][r] = fmaf(s0v[1][r]*c11[r], w2[1][r], o0[1][0][r]);
        }
        mfma2(D0, D1, Db, w2);  load_slot(t4 + 7, D0, D1, Db);
        #pragma unroll
        for (int r = 0; r < 4; ++r) {
            o0[0][1][r] = fmaf(s0v[0][r]*c10[r], w2[0][r], o0[0][1][r]);
            o0[1][1][r] = fmaf(s0v[1][r]*c11[r], w2[1][r], o0[1][1][r]);
        }
    }

    // ---- region 2: tiles 64..79, u = 8d+2*tc+qh, coef x0[u] -----------------
    #pragma unroll 1
    for (int d = 0; d < 4; ++d) {
        const int t4 = 64 + 4*d;
        f32x4 w2[2];

        mfma2(A0, A1, Ab, w2);  load_slot(t4 + 4, A0, A1, Ab);
        {
            const int u = 8*d + qh;
            #pragma unroll
            for (int ms = 0; ms < 2; ++ms) {
                f32x4 cfv = ld_cf4(&cfh[u][ebase + ms*16]);
                #pragma unroll
                for (int r = 0; r < 4; ++r) ttv[ms][r] = fmaf(cfv[r], w2[ms][r], ttv[ms][r]);
            }
        }
        mfma2(B0, B1, Bb, w2);  load_slot(t4 + 5, B0, B1, Bb);
        {
            const int u = 8*d + 2 + qh;
            #pragma unroll
            for (int ms = 0; ms < 2; ++ms) {
                f32x4 cfv = ld_cf4(&cfh[u][ebase + ms*16]);
                #pragma unroll
                for (int r = 0; r < 4; ++r) ttv[ms][r] = fmaf(cfv[r], w2[ms][r], ttv[ms][r]);
            }
        }
        mfma2(C0, C1, Cb, w2);  load_slot(t4 + 6, C0, C1, Cb);
        {
            const int u = 8*d + 4 + qh;
            #pragma unroll
            for (int ms = 0; ms < 2; ++ms) {
                f32x4 cfv = ld_cf4(&cfh[u][ebase + ms*16]);
                #pragma unroll
                for (int r = 0; r < 4; ++r) ttv[ms][r] = fmaf(cfv[r], w2[ms][r], ttv[ms][r]);
            }
        }
        mfma2(D0, D1, Db, w2);  load_slot(t4 + 7, D0, D1, Db);
        {
            const int u = 8*d + 6 + qh;
            #pragma unroll
            for (int ms = 0; ms < 2; ++ms) {
                f32x4 cfv = ld_cf4(&cfh[u][ebase + ms*16]);
                #pragma unroll
                for (int r = 0; r < 4; ++r) ttv[ms][r] = fmaf(cfv[r], w2[ms][r], ttv[ms][r]);
            }
        }
    }

    // ---- region 3: tiles 80..83, u = 2*tc+qh, coef s0*x1[u][m] --------------
    {
        f32x4 w2[2];
        #define R3_BODY(TC)                                                         \
            {                                                                       \
                const int u = 2*(TC) + qh;                                          \
                _Pragma("unroll")                                                   \
                for (int ms = 0; ms < 2; ++ms)                                      \
                    _Pragma("unroll")                                               \
                    for (int m = 0; m < 3; ++m) {                                   \
                        f32x4 cfv = ld_cf4(&cfh[32 + u*3 + m][ebase + ms*16]);      \
                        _Pragma("unroll")                                           \
                        for (int r = 0; r < 4; ++r)                                 \
                            o1v[ms][r][m] = fmaf(cfv[r], w2[ms][r], o1v[ms][r][m]); \
                    }                                                               \
            }
        mfma2(A0, A1, Ab, w2);  load_slot(84, A0, A1, Ab);  R3_BODY(0)
        mfma2(B0, B1, Bb, w2);  load_slot(85, B0, B1, Bb);  R3_BODY(1)
        mfma2(C0, C1, Cb, w2);  load_slot(86, C0, C1, Cb);  R3_BODY(2)
        mfma2(D0, D1, Db, w2);  load_slot(87, D0, D1, Db);  R3_BODY(3)
        #undef R3_BODY
    }

    // ---- region 4: tiles 84..99, coef y1[u4] --------------------------------
    #pragma unroll 1
    for (int d = 0; d < 4; ++d) {
        const int t4 = 84 + 4*d;
        const int u0 = 2*d, u1 = 2*d + 1;
        f32x4 c00 = ld_cf4(&cfh[56 + u0][ebase]);
        f32x4 c01 = ld_cf4(&cfh[56 + u0][ebase + 16]);
        f32x4 c10 = ld_cf4(&cfh[56 + u1][ebase]);
        f32x4 c11 = ld_cf4(&cfh[56 + u1][ebase + 16]);
        f32x4 w2[2];
        int tn;

        mfma2(A0, A1, Ab, w2);  tn = t4 + 4; load_slot(tn < 100 ? tn : 99, A0, A1, Ab);
        #pragma unroll
        for (int r = 0; r < 4; ++r) {
            o0[0][0][r] = fmaf(c00[r], w2[0][r], o0[0][0][r]);
            o0[1][0][r] = fmaf(c01[r], w2[1][r], o0[1][0][r]);
        }
        mfma2(B0, B1, Bb, w2);  tn = t4 + 5; load_slot(tn < 100 ? tn : 99, B0, B1, Bb);
        #pragma unroll
        for (int r = 0; r < 4; ++r) {
            o0[0][1][r] = fmaf(c00[r], w2[0][r], o0[0][1][r]);
            o0[1][1][r] = fmaf(c01[r], w2[1][r], o0[1][1][r]);
        }
        mfma2(C0, C1, Cb, w2);  tn = t4 + 6; load_slot(tn < 100 ? tn : 99, C0, C1, Cb);
        #pragma unroll
        for (int r = 0; r < 4; ++r) {
            o0[0][0][r] = fmaf(c10[r], w2[0][r], o0[0][0][r]);
            o0[1][0][r] = fmaf(c11[r], w2[1][r], o0[1][0][r]);
        }
        mfma2(D0, D1, Db, w2);  tn = t4 + 7; load_slot(tn < 100 ? tn : 99, D0, D1, Db);
        #pragma unroll
        for (int r = 0; r < 4; ++r) {
            o0[0][1][r] = fmaf(c10[r], w2[0][r], o0[0][1][r]);
            o0[1][1][r] = fmaf(c11[r], w2[1][r], o0[1][1][r]);
        }
    }

    // ---- finish: reduce u-halves (lane ^ 8), bf16 coalesced stores ----------
    #pragma unroll
    for (int ms = 0; ms < 2; ++ms)
        #pragma unroll
        for (int r = 0; r < 4; ++r) {
            ttv[ms][r] += __shfl_xor(ttv[ms][r], 8, 64);
            #pragma unroll
            for (int m = 0; m < 3; ++m)
                o1v[ms][r][m] += __shfl_xor(o1v[ms][r][m], 8, 64);
        }

    #pragma unroll
    for (int ms = 0; ms < 2; ++ms) {
        const int eb = ebase + ms*16;
        const f32x4 s1x = *reinterpret_cast<const f32x4*>(&shS[1][eb]);
        const f32x4 s1y = *reinterpret_cast<const f32x4*>(&shS[2][eb]);
        const f32x4 s1z = *reinterpret_cast<const f32x4*>(&shS[3][eb]);
        #pragma unroll
        for (int r = 0; r < 4; ++r) {
            ushort* tp = tpbuf + (size_t)(E0 + eb + r) * IND;
            tp[q]      = (ushort)f2bf(PATH_NORM_C * o0[ms][0][r]);
            tp[16 + q] = (ushort)f2bf(PATH_NORM_C * o0[ms][1][r]);
            if ((q & 8) == 0) {
                const int v = q & 7;
                tp[32 + 3*v + 0] = (ushort)f2bf(PATH_NORM_C * (o1v[ms][r][0] + s1x[r]*ttv[ms][r]));
                tp[32 + 3*v + 1] = (ushort)f2bf(PATH_NORM_C * (o1v[ms][r][1] + s1y[r]*ttv[ms][r]));
                tp[32 + 3*v + 2] = (ushort)f2bf(PATH_NORM_C * (o1v[ms][r][2] + s1z[r]*ttv[ms][r]));
            }
        }
    }
}

// ===== mono edge kernel (R17 verbatim): middle tier =========================
__global__ __launch_bounds__(256, 3) void edge_kernel_mono(
    const float* __restrict__ node_attr,
    const float* __restrict__ edge_attr,
    const float* __restrict__ edge_sh,
    const float* __restrict__ fc_b1,
    const float* __restrict__ fc_b2,
    const int*   __restrict__ edge_index,
    const ushort* __restrict__ W1T,
    const ushort* __restrict__ W2F,
    ushort* __restrict__ tpbuf)
{
    __shared__ ushort cfh[64][EPB];
    __shared__ float  shS[4][EPB];
    __shared__ __attribute__((aligned(16))) ushort pool[8192];

    const int tid  = threadIdx.x;
    const int wave = tid >> 6;
    const int lane = tid & 63;
    const int g    = lane >> 4;
    const int q    = lane & 15;
    const int E0   = blockIdx.x * EPB;

    if (tid < EPB) {
        const int e    = tid;
        const int dstn = edge_index[NE + E0 + e];
        const float4 sh = reinterpret_cast<const float4*>(edge_sh)[E0 + e];
        const float4* xp = reinterpret_cast<const float4*>(node_attr + (size_t)dstn * IND);
        float xr[56];
        #pragma unroll
        for (int i = 0; i < 14; ++i) {
            float4 v = xp[i];
            xr[4*i] = v.x; xr[4*i+1] = v.y; xr[4*i+2] = v.z; xr[4*i+3] = v.w;
        }
        #pragma unroll
        for (int u = 0; u < 32; ++u) cfh[u][e] = (ushort)f2bf(xr[u]);
        #pragma unroll
        for (int u = 0; u < 8; ++u) {
            cfh[32 + 3*u + 0][e] = (ushort)f2bf(sh.x * xr[32 + 3*u + 0]);
            cfh[32 + 3*u + 1][e] = (ushort)f2bf(sh.x * xr[32 + 3*u + 1]);
            cfh[32 + 3*u + 2][e] = (ushort)f2bf(sh.x * xr[32 + 3*u + 2]);
            cfh[56 + u][e] = (ushort)f2bf(
                CG_C * (xr[32+3*u]*sh.y + xr[32+3*u+1]*sh.z + xr[32+3*u+2]*sh.w));
        }
        shS[0][e] = sh.x;
        shS[1][e] = sh.y;  shS[2][e] = sh.z;  shS[3][e] = sh.w;
    }

    f32x4 d1[2][4];
    #pragma unroll
    for (int mt = 0; mt < 4; ++mt) {
        const float4 b1v = *reinterpret_cast<const float4*>(fc_b1 + mt*16 + 4*g);
        #pragma unroll
        for (int ms = 0; ms < 2; ++ms)
            d1[ms][mt] = (f32x4){b1v.x, b1v.y, b1v.z, b1v.w};
    }
    #pragma unroll
    for (int kh = 0; kh < 2; ++kh) {
        bf16x8 bfr[2];
        #pragma unroll
        for (int ms = 0; ms < 2; ++ms) {
            const int e = E0 + wave*32 + ms*16 + q;
            const float* ap = edge_attr + (size_t)e * 64 + kh*32 + g*8;
            float4 f0 = *reinterpret_cast<const float4*>(ap);
            float4 f1 = *reinterpret_cast<const float4*>(ap + 4);
            union { uint32_t u[4]; bf16x8 v; } cv;
            cv.u[0] = pack2(f0.x, f0.y); cv.u[1] = pack2(f0.z, f0.w);
            cv.u[2] = pack2(f1.x, f1.y); cv.u[3] = pack2(f1.z, f1.w);
            bfr[ms] = cv.v;
        }
        #pragma unroll
        for (int mt = 0; mt < 4; ++mt) {
            bf16x8 afr = *reinterpret_cast<const bf16x8*>(W1T + (mt*16 + q)*64 + kh*32 + g*8);
            #pragma unroll
            for (int ms = 0; ms < 2; ++ms)
                d1[ms][mt] = __builtin_amdgcn_mfma_f32_16x16x32_bf16(afr, bfr[ms], d1[ms][mt], 0, 0, 0);
        }
    }
    #pragma unroll
    for (int mt = 0; mt < 4; ++mt) {
        const int kg = 2*mt + (g >> 1);
        #pragma unroll
        for (int ms = 0; ms < 2; ++ms) {
            float v0 = fmaxf(d1[ms][mt][0], 0.f);
            float v1 = fmaxf(d1[ms][mt][1], 0.f);
            float v2 = fmaxf(d1[ms][mt][2], 0.f);
            float v3 = fmaxf(d1[ms][mt][3], 0.f);
            uint32_t* wp = reinterpret_cast<uint32_t*>(
                &pool[wave*2048 + ms*1024 + (kg*16 + q)*8 + 4*(g & 1)]);
            wp[0] = pack2(v0, v1);
            wp[1] = pack2(v2, v3);
        }
    }

    bf16x8 af[2][2];
    #pragma unroll
    for (int ms = 0; ms < 2; ++ms)
        #pragma unroll
        for (int kh = 0; kh < 2; ++kh)
            af[ms][kh] = *reinterpret_cast<const bf16x8*>(
                &pool[wave*2048 + ms*1024 + ((kh*4 + g)*16 + q)*8]);

    bf16x8 A0, A1, B0, B1, C0, C1, D0, D1;
    float  Ab, Bb, Cb, Db;
    auto load_slot = [&](int t, bf16x8& b0, bf16x8& b1, float& bb) {
        const ushort* p = W2F + (size_t)t * 1024 + lane * 8;
        b0 = *reinterpret_cast<const bf16x8*>(p);
        b1 = *reinterpret_cast<const bf16x8*>(p + 512);
        bb = fc_b2[t * 16 + q];
    };
    load_slot(0, A0, A1, Ab);
    load_slot(1, B0, B1, Bb);
    load_slot(2, C0, C1, Cb);
    load_slot(3, D0, D1, Db);

    __syncthreads();

    const int ebase = wave*32 + 4*g;
    f32x4 s0v[2];
    s0v[0] = *reinterpret_cast<const f32x4*>(&shS[0][ebase]);
    s0v[1] = *reinterpret_cast<const f32x4*>(&shS[0][ebase + 16]);

    float o0[2][2][4];
    float ttv[2][4];
    float o1v[2][4][3];
    #pragma unroll
    for (int ms = 0; ms < 2; ++ms) {
        #pragma unroll
        for (int r = 0; r < 4; ++r) {
            o0[ms][0][r] = 0.f; o0[ms][1][r] = 0.f; ttv[ms][r] = 0.f;
            o1v[ms][r][0] = 0.f; o1v[ms][r][1] = 0.f; o1v[ms][r][2] = 0.f;
        }
    }

    auto mfma2 = [&](const bf16x8& b0, const bf16x8& b1, float b2v, f32x4* accv) {
        #pragma unroll
        for (int ms = 0; ms < 2; ++ms) {
            f32x4 a = (f32x4){b2v, b2v, b2v, b2v};
            a = __builtin_amdgcn_mfma_f32_16x16x32_bf16(af[ms][0], b0, a, 0, 0, 0);
            a = __builtin_amdgcn_mfma_f32_16x16x32_bf16(af[ms][1], b1, a, 0, 0, 0);
            accv[ms] = a;
        }
    };

    const int qh = q >> 3;

    #pragma unroll 1
    for (int c = 0; c < 16; ++c) {
        const int t4 = 4*c;
        const int u0 = 2*c, u1 = 2*c + 1;
        f32x4 c00 = ld_cf4(&cfh[u0][ebase]);
        f32x4 c01 = ld_cf4(&cfh[u0][ebase + 16]);
        f32x4 c10 = ld_cf4(&cfh[u1][ebase]);
        f32x4 c11 = ld_cf4(&cfh[u1][ebase + 16]);
        f32x4 w2[2];

        mfma2(A0, A1, Ab, w2);  load_slot(t4 + 4, A0, A1, Ab);
        #pragma unroll
        for (int r = 0; r < 4; ++r) {
            o0[0][0][r] = fmaf(s0v[0][r]*c00[r], w2[0][r], o0[0][0][r]);
            o0[1][0][r] = fmaf(s0v[1][r]*c01[r], w2[1][r], o0[1][0][r]);
        }
        mfma2(B0, B1, Bb, w2);  load_slot(t4 + 5, B0, B1, Bb);
        #pragma unroll
        for (int r = 0; r < 4; ++r) {
            o0[0][1][r] = fmaf(s0v[0][r]*c00[r], w2[0][r], o0[0][1][r]);
            o0[1][1][r] = fmaf(s0v[1][r]*c01[r], w2[1][r], o0[1][1][r]);
        }
        mfma2(C0, C1, Cb, w2);  load_slot(t4 + 6, C0, C1, Cb);
        #pragma unroll
        for (int r = 0; r < 4; ++r) {
            o0[0][0][r] = fmaf(s0v[0][r]*c10[r], w2[0][r], o0[0][0][r]);
            o0[1][0][r] = fmaf(s0v[1][r]*c11[r], w2[1][r], o0[1][0][r]);
        }
        mfma2(D0, D1, Db, w2);  load_slot(t4 + 7, D0, D1, Db);
        #pragma unroll
        for (int r = 0; r < 4; ++r) {
            o0[0][1][r] = fmaf(s0v[0][r]*c10[r], w2[0][r], o0[0][1][r]);
            o0[1][1][r] = fmaf(s0v[1][r]*c11[r], w2[1][r], o0[1][1][r]);
        }
    }

    #pragma unroll 1
    for (int d = 0; d < 4; ++d) {
        const int t4 = 64 + 4*d;
        f32x4 w2[2];

        mfma2(A0, A1, Ab, w2);  load_slot(t4 + 4, A0, A1, Ab);
        {
            const int u = 8*d + qh;
            #pragma unroll
            for (int ms = 0; ms < 2; ++ms) {
                f32x4 cfv = ld_cf4(&cfh[u][ebase + ms*16]);
                #pragma unroll
                for (int r = 0; r < 4; ++r) ttv[ms][r] = fmaf(cfv[r], w2[ms][r], ttv[ms][r]);
            }
        }
        mfma2(B0, B1, Bb, w2);  load_slot(t4 + 5, B0, B1, Bb);
        {
            const int u = 8*d + 2 + qh;
            #pragma unroll
            for (int ms = 0; ms < 2; ++ms) {
                f32x4 cfv = ld_cf4(&cfh[u][ebase + ms*16]);
                #pragma unroll
                for (int r = 0; r < 4; ++r) ttv[ms][r] = fmaf(cfv[r], w2[ms][r], ttv[ms][r]);
            }
        }
        mfma2(C0, C1, Cb, w2);  load_slot(t4 + 6, C0, C1, Cb);
        {
            const int u = 8*d + 4 + qh;
            #pragma unroll
            for (int ms = 0; ms < 2; ++ms) {
                f32x4 cfv = ld_cf4(&cfh[u][ebase + ms*16]);
                #pragma unroll
                for (int r = 0; r < 4; ++r) ttv[ms][r] = fmaf(cfv[r], w2[ms][r], ttv[ms][r]);
            }
        }
        mfma2(D0, D1, Db, w2);  load_slot(t4 + 7, D0, D1, Db);
        {
            const int u = 8*d + 6 + qh;
            #pragma unroll
            for (int ms = 0; ms < 2; ++ms) {
                f32x4 cfv = ld_cf4(&cfh[u][ebase + ms*16]);
                #pragma unroll
                for (int r = 0; r < 4; ++r) ttv[ms][r] = fmaf(cfv[r], w2[ms][r], ttv[ms][r]);
            }
        }
    }

    {
        f32x4 w2[2];
        #define R3_BODY(TC)                                                         \
            {                                                                       \
                const int u = 2*(TC) + qh;                                          \
                _Pragma("unroll")                                                   \
                for (int ms = 0; ms < 2; ++ms)                                      \
                    _Pragma("unroll")                                               \
                    for (int m = 0; m < 3; ++m) {                                   \
                        f32x4 cfv = ld_cf4(&cfh[32 + u*3 + m][ebase + ms*16]);      \
                        _Pragma("unroll")                                           \
                        for (int r = 0; r < 4; ++r)                                 \
                            o1v[ms][r][m] = fmaf(cfv[r], w2[ms][r], o1v[ms][r][m]); \
                    }                                                               \
            }
        mfma2(A0, A1, Ab, w2);  load_slot(84, A0, A1, Ab);  R3_BODY(0)
        mfma2(B0, B1, Bb, w2);  load_slot(85, B0, B1, Bb);  R3_BODY(1)
        mfma2(C0, C1, Cb, w2);  load_slot(86, C0, C1, Cb);  R3_BODY(2)
        mfma2(D0, D1, Db, w2);  load_slot(87, D0, D1, Db);  R3_BODY(3)
        #undef R3_BODY
    }

    #pragma unroll 1
    for (int d = 0; d < 4; ++d) {
        const int t4 = 84 + 4*d;
        const int u0 = 2*d, u1 = 2*d + 1;
        f32x4 c00 = ld_cf4(&cfh[56 + u0][ebase]);
        f32x4 c01 = ld_cf4(&cfh[56 + u0][ebase + 16]);
        f32x4 c10 = ld_cf4(&cfh[56 + u1][ebase]);
        f32x4 c11 = ld_cf4(&cfh[56 + u1][ebase + 16]);
        f32x4 w2[2];
        int tn;

        mfma2(A0, A1, Ab, w2);  tn = t4 + 4; load_slot(tn < 100 ? tn : 99, A0, A1, Ab);
        #pragma unroll
        for (int r = 0; r < 4; ++r) {
            o0[0][0][r] = fmaf(c00[r], w2[0][r], o0[0][0][r]);
            o0[1][0][r] = fmaf(c01[r], w2[1][r], o0[1][0][r]);
        }
        mfma2(B0, B1, Bb, w2);  tn = t4 + 5; load_slot(tn < 100 ? tn : 99, B0, B1, Bb);
        #pragma unroll
        for (int r = 0; r < 4; ++r) {
            o0[0][1][r] = fmaf(c00[r], w2[0][r], o0[0][1][r]);
            o0[1][1][r] = fmaf(c01[r], w2[1][r], o0[1][1][r]);
        }
        mfma2(C0, C1, Cb, w2);  tn = t4 + 6; load_slot(tn < 100 ? tn : 99, C0, C1, Cb);
        #pragma unroll
        for (int r = 0; r < 4; ++r) {
            o0[0][0][r] = fmaf(c10[r], w2[0][r], o0[0][0][r]);
            o0[1][0][r] = fmaf(c11[r], w2[1][r], o0[1][0][r]);
        }
        mfma2(D0, D1, Db, w2);  tn = t4 + 7; load_slot(tn < 100 ? tn : 99, D0, D1, Db);
        #pragma unroll
        for (int r = 0; r < 4; ++r) {
            o0[0][1][r] = fmaf(c10[r], w2[0][r], o0[0][1][r]);
            o0[1][1][r] = fmaf(c11[r], w2[1][r], o0[1][1][r]);
        }
    }

    #pragma unroll
    for (int ms = 0; ms < 2; ++ms)
        #pragma unroll
        for (int r = 0; r < 4; ++r) {
            ttv[ms][r] += __shfl_xor(ttv[ms][r], 8, 64);
            #pragma unroll
            for (int m = 0; m < 3; ++m)
                o1v[ms][r][m] += __shfl_xor(o1v[ms][r][m], 8, 64);
        }

    #pragma unroll
    for (int ms = 0; ms < 2; ++ms) {
        const int eb = ebase + ms*16;
        const f32x4 s1x = *reinterpret_cast<const f32x4*>(&shS[1][eb]);
        const f32x4 s1y = *reinterpret_cast<const f32x4*>(&shS[2][eb]);
        const f32x4 s1z = *reinterpret_cast<const f32x4*>(&shS[3][eb]);
        #pragma unroll
        for (int r = 0; r < 4; ++r) {
            ushort* tp = tpbuf + (size_t)(E0 + eb + r) * IND;
            tp[q]      = (ushort)f2bf(PATH_NORM_C * o0[ms][0][r]);
            tp[16 + q] = (ushort)f2bf(PATH_NORM_C * o0[ms][1][r]);
            if ((q & 8) == 0) {
                const int v = q & 7;
                tp[32 + 3*v + 0] = (ushort)f2bf(PATH_NORM_C * (o1v[ms][r][0] + s1x[r]*ttv[ms][r]));
                tp[32 + 3*v + 1] = (ushort)f2bf(PATH_NORM_C * (o1v[ms][r][1] + s1y[r]*ttv[ms][r]));
                tp[32 + 3*v + 2] = (ushort)f2bf(PATH_NORM_C * (o1v[ms][r][2] + s1z[r]*ttv[ms][r]));
            }
        }
    }
}

// ---- gather: one wave per node, mean + residual (bf16 tpbuf) ---------------
__global__ __launch_bounds__(256) void gather_kernel(
    const ushort* __restrict__ tpbuf, const int* __restrict__ cursor,
    const int* __restrict__ elist, const float* __restrict__ node_attr,
    float* __restrict__ out)
{
    const int node = blockIdx.x * 4 + (threadIdx.x >> 6);
    const int j = threadIdx.x & 63;
    if (node >= NN) return;
    const int degt = cursor[node];
    const int deg = (degt < DCAP) ? degt : DCAP;
    float sum = 0.f;
    #pragma unroll 4
    for (int i = 0; i < deg; ++i) {
        const int e = elist[node * DCAP + i];
        if (j < 56) sum += __uint_as_float((uint32_t)tpbuf[(size_t)e * IND + j] << 16);
    }
    if (j < 56) {
        const float c = (degt > 0) ? (float)degt : 1.f;
        out[node * IND + j] = sum / c + node_attr[node * IND + j];
    }
}

// ---- last-resort fallback: naive per-edge atomic kernel (fp32) -------------
__global__ __launch_bounds__(256) void finalize_fb_kernel(
    const float* __restrict__ acc, const float* __restrict__ cnt,
    const float* __restrict__ node_attr, float* __restrict__ out)
{
    const int i = blockIdx.x * 256 + threadIdx.x;
    if (i >= NN * IND) return;
    const int n = i / IND;
    const float c = fmaxf(cnt[n], 1.0f);
    out[i] = acc[i] / c + node_attr[i];
}

__global__ __launch_bounds__(256) void edge_fb_kernel(
    const float* __restrict__ node_attr, const float* __restrict__ edge_attr,
    const float* __restrict__ edge_sh, const float* __restrict__ fc_w1,
    const float* __restrict__ fc_b1, const float* __restrict__ fc_w2,
    const float* __restrict__ fc_b2, const int* __restrict__ edge_index,
    float* __restrict__ acc, float* __restrict__ cnt)
{
    const int idx = blockIdx.x * 256 + threadIdx.x;
    if (idx >= NE) return;
    const int e = idx;
    const int src = edge_index[e];
    const int dst = edge_index[NE + e];
    float h[64];
    #pragma unroll 1
    for (int k = 0; k < 64; ++k) {
        float s = fc_b1[k];
        for (int j = 0; j < 64; ++j) s += edge_attr[(size_t)e*64 + j] * fc_w1[j*64 + k];
        h[k] = fmaxf(s, 0.f);
    }
    const float4 sh = reinterpret_cast<const float4*>(edge_sh)[e];
    const float* x = node_attr + (size_t)dst * IND;
    float out0[32];
    #pragma unroll 1
    for (int v = 0; v < 32; ++v) out0[v] = 0.f;
    float tt[8], o1[24];
    #pragma unroll 1
    for (int v = 0; v < 8; ++v) tt[v] = 0.f;
    #pragma unroll 1
    for (int i = 0; i < 24; ++i) o1[i] = 0.f;
    #pragma unroll 1
    for (int u = 0; u < 32; ++u) {
        const float c1 = sh.x * x[u];
        for (int v = 0; v < 32; ++v) {
            float w = fc_b2[u*32 + v];
            for (int k = 0; k < 64; ++k) w += h[k] * fc_w2[k*WN + u*32 + v];
            out0[v] += c1 * w;
        }
        for (int v = 0; v < 8; ++v) {
            float w = fc_b2[1024 + u*8 + v];
            for (int k = 0; k < 64; ++k) w += h[k] * fc_w2[k*WN + 1024 + u*8 + v];
            tt[v] += x[u] * w;
        }
    }
    #pragma unroll 1
    for (int u = 0; u < 8; ++u) {
        const float y1 = CG_C * (x[32+3*u]*sh.y + x[32+3*u+1]*sh.z + x[32+3*u+2]*sh.w);
        for (int v = 0; v < 8; ++v) {
            float w = fc_b2[1280 + u*8 + v];
            for (int k = 0; k < 64; ++k) w += h[k] * fc_w2[k*WN + 1280 + u*8 + v];
            o1[3*v+0] += sh.x * w * x[32+3*u+0];
            o1[3*v+1] += sh.x * w * x[32+3*u+1];
            o1[3*v+2] += sh.x * w * x[32+3*u+2];
        }
        for (int v = 0; v < 32; ++v) {
            float w = fc_b2[1344 + u*32 + v];
            for (int k = 0; k < 64; ++k) w += h[k] * fc_w2[k*WN + 1344 + u*32 + v];
            out0[v] += y1 * w;
        }
    }
    float* ap = acc + (size_t)src * IND;
    for (int v = 0; v < 32; ++v) atomicAdd(ap + v, PATH_NORM_C * out0[v]);
    for (int v = 0; v < 8; ++v) {
        atomicAdd(ap + 32 + 3*v + 0, PATH_NORM_C * (o1[3*v+0] + sh.y * tt[v]));
        atomicAdd(ap + 32 + 3*v + 1, PATH_NORM_C * (o1[3*v+1] + sh.z * tt[v]));
        atomicAdd(ap + 32 + 3*v + 2, PATH_NORM_C * (o1[3*v+2] + sh.w * tt[v]));
    }
    atomicAdd(cnt + src, 1.0f);
}

extern "C" void kernel_launch(void* const* d_in, const int* in_sizes, int n_in,
                              void* d_out, int out_size, void* d_ws, size_t ws_size,
                              hipStream_t stream) {
    const float* node_attr = (const float*)d_in[0];
    const float* edge_attr = (const float*)d_in[1];
    const float* edge_sh   = (const float*)d_in[2];
    const float* fc_w1     = (const float*)d_in[3];
    const float* fc_b1     = (const float*)d_in[4];
    const float* fc_w2     = (const float*)d_in[5];
    const float* fc_b2     = (const float*)d_in[6];
    const int*   edge_index = (const int*)d_in[7];

    char* ws = (char*)d_ws;
    int*    cursor = (int*)(ws + 0);                  // 40,000
    int*    elist  = (int*)(ws + 40000);              // -> 2,600,000
    ushort* W1T    = (ushort*)(ws + 2600000);         // -> 2,608,192 (mono tier)
    ushort* W2F    = (ushort*)(ws + 2608192);         // -> 2,812,992
    ushort* tpbuf  = (ushort*)(ws + 2812992);         // 17,920,000 -> 20,732,992
    ushort* Hbuf   = (ushort*)(ws + 20732992);        // 20,480,000 -> 41,212,992
    const size_t WS_SPLIT = 41212992ull;
    const size_t WS_MONO  = 20732992ull;

    if (ws_size >= WS_SPLIT) {
        hipMemsetAsync(cursor, 0, 40000, stream);
        front_kernel<<<NBLK, 256, 0, stream>>>(
            edge_attr, fc_w1, fc_b1, fc_w2, edge_index, W2F, cursor, elist, Hbuf);
        edge_kernel_split<<<NBLK, 256, 0, stream>>>(
            node_attr, edge_sh, fc_b2, edge_index, W2F, Hbuf, tpbuf);
        gather_kernel<<<(NN + 3) / 4, 256, 0, stream>>>(
            tpbuf, cursor, elist, node_attr, (float*)d_out);
    } else if (ws_size >= WS_MONO) {
        hipMemsetAsync(cursor, 0, 40000, stream);
        prep_kernel<<<(64*64 + 100*1024 + NE + 255) / 256, 256, 0, stream>>>(
            fc_w1, fc_w2, edge_index, W1T, W2F, cursor, elist, 1);
        edge_kernel_mono<<<NBLK, 256, 0, stream>>>(
            node_attr, edge_attr, edge_sh, fc_b1, fc_b2, edge_index, W1T, W2F, tpbuf);
        gather_kernel<<<(NN + 3) / 4, 256, 0, stream>>>(
            tpbuf, cursor, elist, node_attr, (float*)d_out);
    } else {
        float* acc = (float*)ws;                      // 2,240,000
        float* cnt = (float*)(ws + 2240000);          // -> 2,280,000
        hipMemsetAsync(ws, 0, 2280000, stream);
        edge_fb_kernel<<<(NE + 255) / 256, 256, 0, stream>>>(
            node_attr, edge_attr, edge_sh, fc_w1, fc_b1, fc_w2, fc_b2, edge_index, acc, cnt);
        finalize_fb_kernel<<<(NN * IND + 255) / 256, 256, 0, stream>>>(
            acc, cnt, node_attr, (float*)d_out);
    }
}